// Round 1
// baseline (318.019 us; speedup 1.0000x reference)
//
#include <hip/hip_runtime.h>
#include <math.h>

#define NB 4
#define NP 2048
#define NC 192
#define KNN 12
#define NEG_SLOPE 0.2f

__device__ __forceinline__ float lrelu(float x) { return x >= 0.0f ? x : NEG_SLOPE * x; }

// ---------------- kernel 1: L2-normalize rows (4 points/block, 1 wave each) ----
__global__ void __launch_bounds__(256) k_normalize(const float* __restrict__ nodes,
                                                   float* __restrict__ xn) {
    int wave = threadIdx.x >> 6;
    int lane = threadIdx.x & 63;
    size_t pt = (size_t)blockIdx.x * 4 + wave;
    const float* x = nodes + pt * NC;
    float v0 = x[lane], v1 = x[lane + 64], v2 = x[lane + 128];
    float s = v0 * v0 + v1 * v1 + v2 * v2;
    #pragma unroll
    for (int off = 32; off; off >>= 1) s += __shfl_xor(s, off, 64);
    float inv = 1.0f / fmaxf(sqrtf(s), 1e-12f);
    float* o = xn + pt * NC;
    o[lane] = v0 * inv; o[lane + 64] = v1 * inv; o[lane + 128] = v2 * inv;
}

// ---------------- kernel 2: sim = Xn_b * Xn_b^T  (128x128 tile, f32) ----------
#define LDST 132
__global__ void __launch_bounds__(256) k_sim(const float* __restrict__ xn,
                                             float* __restrict__ sim,
                                             size_t xstride, size_t simstride) {
    __shared__ float As[16][LDST];
    __shared__ float Bs[16][LDST];
    const float* xb = xn + (size_t)blockIdx.z * xstride;
    float* sb = sim + (size_t)blockIdx.z * simstride;
    int t = threadIdx.x;
    int tx = t & 15, ty = t >> 4;
    int m0 = blockIdx.y * 128, n0 = blockIdx.x * 128;
    int lr = t >> 2;           // 0..63
    int kq = (t & 3) * 4;      // 0,4,8,12
    float c[2][2][4][4] = {};
    for (int kb = 0; kb < NC; kb += 16) {
        #pragma unroll
        for (int s = 0; s < 2; ++s) {
            int r = lr + 64 * s;
            float4 va = *reinterpret_cast<const float4*>(xb + (size_t)(m0 + r) * NC + kb + kq);
            As[kq + 0][r] = va.x; As[kq + 1][r] = va.y; As[kq + 2][r] = va.z; As[kq + 3][r] = va.w;
            float4 vb = *reinterpret_cast<const float4*>(xb + (size_t)(n0 + r) * NC + kb + kq);
            Bs[kq + 0][r] = vb.x; Bs[kq + 1][r] = vb.y; Bs[kq + 2][r] = vb.z; Bs[kq + 3][r] = vb.w;
        }
        __syncthreads();
        #pragma unroll
        for (int k = 0; k < 16; ++k) {
            float4 a0 = *reinterpret_cast<const float4*>(&As[k][ty * 4]);
            float4 a1 = *reinterpret_cast<const float4*>(&As[k][ty * 4 + 64]);
            float4 b0 = *reinterpret_cast<const float4*>(&Bs[k][tx * 4]);
            float4 b1 = *reinterpret_cast<const float4*>(&Bs[k][tx * 4 + 64]);
            float av[2][4] = {{a0.x, a0.y, a0.z, a0.w}, {a1.x, a1.y, a1.z, a1.w}};
            float bv[2][4] = {{b0.x, b0.y, b0.z, b0.w}, {b1.x, b1.y, b1.z, b1.w}};
            #pragma unroll
            for (int ih = 0; ih < 2; ++ih)
                #pragma unroll
                for (int jh = 0; jh < 2; ++jh)
                    #pragma unroll
                    for (int i = 0; i < 4; ++i)
                        #pragma unroll
                        for (int j = 0; j < 4; ++j)
                            c[ih][jh][i][j] += av[ih][i] * bv[jh][j];
        }
        __syncthreads();
    }
    #pragma unroll
    for (int ih = 0; ih < 2; ++ih)
        #pragma unroll
        for (int i = 0; i < 4; ++i) {
            int row = m0 + ih * 64 + ty * 4 + i;
            #pragma unroll
            for (int jh = 0; jh < 2; ++jh) {
                float4 w = {c[ih][jh][i][0], c[ih][jh][i][1], c[ih][jh][i][2], c[ih][jh][i][3]};
                *reinterpret_cast<float4*>(sb + (size_t)row * NP + n0 + jh * 64 + tx * 4) = w;
            }
        }
}

// ---------------- kernel 3: iterative top-12 per row (tie -> lowest index) ----
__global__ void __launch_bounds__(256) k_topk(const float* __restrict__ sim,
                                              int* __restrict__ knn, size_t simstride) {
    __shared__ float row[NP];
    __shared__ float bval[4];
    __shared__ int bidx[4];
    int p = blockIdx.x;
    int batch = blockIdx.y;
    int t = threadIdx.x;
    const float* sr = sim + (size_t)batch * simstride + (size_t)p * NP;
    for (int j = t; j < NP; j += 256) row[j] = sr[j];
    __syncthreads();
    if (t == 0) row[p] = -INFINITY;   // exclude self
    __syncthreads();
    int* ko = knn + ((size_t)batch * NP + p) * KNN;
    for (int r = 0; r < KNN; ++r) {
        float bv = -INFINITY; int bi = NP;
        for (int j = t; j < NP; j += 256) {
            float v = row[j];
            if (v > bv) { bv = v; bi = j; }   // ascending j => strict '>' keeps lowest idx
        }
        #pragma unroll
        for (int off = 32; off; off >>= 1) {
            float ov = __shfl_xor(bv, off, 64);
            int oi = __shfl_xor(bi, off, 64);
            if (ov > bv || (ov == bv && oi < bi)) { bv = ov; bi = oi; }
        }
        if ((t & 63) == 0) { bval[t >> 6] = bv; bidx[t >> 6] = bi; }
        __syncthreads();
        if (t == 0) {
            float fv = bval[0]; int fi = bidx[0];
            #pragma unroll
            for (int w = 1; w < 4; ++w)
                if (bval[w] > fv || (bval[w] == fv && bidx[w] < fi)) { fv = bval[w]; fi = bidx[w]; }
            ko[r] = fi;
            row[fi] = -INFINITY;
        }
        __syncthreads();
    }
}

// ---------------- kernel 4: U' = X@W1a - X@W1b + b1, V = X@W1b ----------------
#define PTS 16
__global__ void __launch_bounds__(192) k_uv(const float* __restrict__ nodes,
                                            const float* __restrict__ W1,
                                            const float* __restrict__ b1,
                                            float* __restrict__ up, float* __restrict__ vv) {
    __shared__ float xs[PTS][NC];   // 12 KB
    int t = threadIdx.x;            // 0..191 = output channel
    int p0 = blockIdx.x * PTS;      // global point base over B*P
    for (int i = t; i < PTS * NC; i += 192) {
        int pt = i / NC, cc = i % NC;
        xs[pt][cc] = nodes[(size_t)(p0 + pt) * NC + cc];
    }
    __syncthreads();
    float accU[PTS] = {}, accV[PTS] = {};
    for (int c4 = 0; c4 < NC; c4 += 4) {
        float wa[4], wb[4];
        #pragma unroll
        for (int i = 0; i < 4; ++i) {
            wa[i] = W1[(size_t)(c4 + i) * NC + t];
            wb[i] = W1[(size_t)(c4 + i + NC) * NC + t];
        }
        #pragma unroll
        for (int pt = 0; pt < PTS; ++pt) {
            float4 xv = *reinterpret_cast<const float4*>(&xs[pt][c4]);
            accU[pt] += xv.x * wa[0] + xv.y * wa[1] + xv.z * wa[2] + xv.w * wa[3];
            accV[pt] += xv.x * wb[0] + xv.y * wb[1] + xv.z * wb[2] + xv.w * wb[3];
        }
    }
    float bb = b1[t];
    #pragma unroll
    for (int pt = 0; pt < PTS; ++pt) {
        up[(size_t)(p0 + pt) * NC + t] = accU[pt] - accV[pt] + bb;
        vv[(size_t)(p0 + pt) * NC + t] = accV[pt];
    }
}

// ---------------- kernel 5: fused edge MLP + mean_k + LayerNorm (1 wave/pt) ---
__global__ void __launch_bounds__(64) k_edge(const float* __restrict__ up,
                                             const float* __restrict__ vv,
                                             const int* __restrict__ knn,
                                             const float* __restrict__ W2,
                                             const float* __restrict__ b2,
                                             const float* __restrict__ gamma,
                                             const float* __restrict__ beta,
                                             float* __restrict__ out) {
    __shared__ float hs[KNN][NC];   // 9216 B
    __shared__ int qs[KNN];
    int lane = threadIdx.x;
    int pt = blockIdx.x;            // global over B*P
    int b = pt / NP;
    if (lane < KNN) qs[lane] = knn[(size_t)pt * KNN + lane];
    __syncthreads();
    float u0 = up[(size_t)pt * NC + lane];
    float u1 = up[(size_t)pt * NC + lane + 64];
    float u2 = up[(size_t)pt * NC + lane + 128];
    for (int e = 0; e < KNN; ++e) {
        const float* vq = vv + ((size_t)b * NP + qs[e]) * NC;
        hs[e][lane]       = lrelu(u0 + vq[lane]);
        hs[e][lane + 64]  = lrelu(u1 + vq[lane + 64]);
        hs[e][lane + 128] = lrelu(u2 + vq[lane + 128]);
    }
    __syncthreads();
    float acc[KNN][3] = {};
    for (int c4 = 0; c4 < NC; c4 += 4) {
        float w[4][3];
        #pragma unroll
        for (int i = 0; i < 4; ++i) {
            w[i][0] = W2[(size_t)(c4 + i) * NC + lane];
            w[i][1] = W2[(size_t)(c4 + i) * NC + lane + 64];
            w[i][2] = W2[(size_t)(c4 + i) * NC + lane + 128];
        }
        #pragma unroll
        for (int e = 0; e < KNN; ++e) {
            float4 hv = *reinterpret_cast<const float4*>(&hs[e][c4]);
            float hh[4] = {hv.x, hv.y, hv.z, hv.w};
            #pragma unroll
            for (int i = 0; i < 4; ++i) {
                acc[e][0] += hh[i] * w[i][0];
                acc[e][1] += hh[i] * w[i][1];
                acc[e][2] += hh[i] * w[i][2];
            }
        }
    }
    float bb0 = b2[lane], bb1 = b2[lane + 64], bb2 = b2[lane + 128];
    float agg0 = 0.f, agg1 = 0.f, agg2 = 0.f;
    #pragma unroll
    for (int e = 0; e < KNN; ++e) {
        agg0 += lrelu(acc[e][0] + bb0);
        agg1 += lrelu(acc[e][1] + bb1);
        agg2 += lrelu(acc[e][2] + bb2);
    }
    agg0 /= (float)KNN; agg1 /= (float)KNN; agg2 /= (float)KNN;
    float s = agg0 + agg1 + agg2;
    #pragma unroll
    for (int off = 32; off; off >>= 1) s += __shfl_xor(s, off, 64);
    float mu = s / (float)NC;
    float d0 = agg0 - mu, d1 = agg1 - mu, d2 = agg2 - mu;
    float vs = d0 * d0 + d1 * d1 + d2 * d2;
    #pragma unroll
    for (int off = 32; off; off >>= 1) vs += __shfl_xor(vs, off, 64);
    float rstd = 1.0f / sqrtf(vs / (float)NC + 1e-5f);
    float* o = out + (size_t)pt * NC;
    o[lane]       = d0 * rstd * gamma[lane]       + beta[lane];
    o[lane + 64]  = d1 * rstd * gamma[lane + 64]  + beta[lane + 64];
    o[lane + 128] = d2 * rstd * gamma[lane + 128] + beta[lane + 128];
}

extern "C" void kernel_launch(void* const* d_in, const int* in_sizes, int n_in,
                              void* d_out, int out_size, void* d_ws, size_t ws_size,
                              hipStream_t stream) {
    const float* nodes = (const float*)d_in[0];
    const float* W1    = (const float*)d_in[1];
    const float* b1    = (const float*)d_in[2];
    const float* W2    = (const float*)d_in[3];
    const float* b2    = (const float*)d_in[4];
    const float* gamma = (const float*)d_in[5];
    const float* beta  = (const float*)d_in[6];
    float* out = (float*)d_out;

    float* xn  = (float*)d_ws;                       // B*P*C
    float* up  = xn + (size_t)NB * NP * NC;          // B*P*C
    float* vv  = up + (size_t)NB * NP * NC;          // B*P*C
    int*   knn = (int*)(vv + (size_t)NB * NP * NC);  // B*P*K
    float* sim = (float*)(knn + (size_t)NB * NP * KNN);

    size_t fixed_bytes = ((size_t)3 * NB * NP * NC + (size_t)NB * NP * KNN) * 4;
    bool full = ws_size >= fixed_bytes + (size_t)NB * NP * NP * 4;

    k_normalize<<<NB * NP / 4, 256, 0, stream>>>(nodes, xn);
    k_uv<<<NB * NP / PTS, 192, 0, stream>>>(nodes, W1, b1, up, vv);
    if (full) {
        // all batches at once: better occupancy for the GEMM (1024 blocks)
        k_sim<<<dim3(NP / 128, NP / 128, NB), 256, 0, stream>>>(xn, sim,
                                                                (size_t)NP * NC, (size_t)NP * NP);
        k_topk<<<dim3(NP, NB), 256, 0, stream>>>(sim, knn, (size_t)NP * NP);
    } else {
        // ws-frugal fallback: one batch's sim at a time (16.8 MB)
        for (int b = 0; b < NB; ++b) {
            k_sim<<<dim3(NP / 128, NP / 128, 1), 256, 0, stream>>>(xn + (size_t)b * NP * NC, sim, 0, 0);
            k_topk<<<dim3(NP, 1), 256, 0, stream>>>(sim, knn + (size_t)b * NP * KNN, 0);
        }
    }
    k_edge<<<NB * NP, 64, 0, stream>>>(up, vv, knn, W2, b2, gamma, beta, out);
}

// Round 2
// 267.688 us; speedup vs baseline: 1.1880x; 1.1880x over previous
//
#include <hip/hip_runtime.h>
#include <math.h>

#define NB 4
#define NP 2048
#define NC 192
#define KNN 12
#define NEG_SLOPE 0.2f

typedef __attribute__((ext_vector_type(8))) short bf16x8;
typedef __attribute__((ext_vector_type(4))) float f32x4;

__device__ __forceinline__ float lrelu(float x) { return x >= 0.0f ? x : NEG_SLOPE * x; }

__device__ __forceinline__ ushort f2bf(float x) {
    unsigned u = __float_as_uint(x);
    unsigned r = (u + 0x7FFFu + ((u >> 16) & 1u)) >> 16;   // RNE
    return (ushort)r;
}

// ---------------- kernel 1: L2-normalize rows (4 points/block, 1 wave each) ----
__global__ void __launch_bounds__(256) k_normalize(const float* __restrict__ nodes,
                                                   float* __restrict__ xn) {
    int wave = threadIdx.x >> 6;
    int lane = threadIdx.x & 63;
    size_t pt = (size_t)blockIdx.x * 4 + wave;
    const float* x = nodes + pt * NC;
    float v0 = x[lane], v1 = x[lane + 64], v2 = x[lane + 128];
    float s = v0 * v0 + v1 * v1 + v2 * v2;
    #pragma unroll
    for (int off = 32; off; off >>= 1) s += __shfl_xor(s, off, 64);
    float inv = 1.0f / fmaxf(sqrtf(s), 1e-12f);
    float* o = xn + pt * NC;
    o[lane] = v0 * inv; o[lane + 64] = v1 * inv; o[lane + 128] = v2 * inv;
}

// ---------------- kernel 2: sim = Xn_b * Xn_b^T  (128x128 tile, f32) ----------
#define LDST 132
__global__ void __launch_bounds__(256) k_sim(const float* __restrict__ xn,
                                             float* __restrict__ sim,
                                             size_t xstride, size_t simstride) {
    __shared__ float As[16][LDST];
    __shared__ float Bs[16][LDST];
    const float* xb = xn + (size_t)blockIdx.z * xstride;
    float* sb = sim + (size_t)blockIdx.z * simstride;
    int t = threadIdx.x;
    int tx = t & 15, ty = t >> 4;
    int m0 = blockIdx.y * 128, n0 = blockIdx.x * 128;
    int lr = t >> 2;           // 0..63
    int kq = (t & 3) * 4;      // 0,4,8,12
    float c[2][2][4][4] = {};
    for (int kb = 0; kb < NC; kb += 16) {
        #pragma unroll
        for (int s = 0; s < 2; ++s) {
            int r = lr + 64 * s;
            float4 va = *reinterpret_cast<const float4*>(xb + (size_t)(m0 + r) * NC + kb + kq);
            As[kq + 0][r] = va.x; As[kq + 1][r] = va.y; As[kq + 2][r] = va.z; As[kq + 3][r] = va.w;
            float4 vb = *reinterpret_cast<const float4*>(xb + (size_t)(n0 + r) * NC + kb + kq);
            Bs[kq + 0][r] = vb.x; Bs[kq + 1][r] = vb.y; Bs[kq + 2][r] = vb.z; Bs[kq + 3][r] = vb.w;
        }
        __syncthreads();
        #pragma unroll
        for (int k = 0; k < 16; ++k) {
            float4 a0 = *reinterpret_cast<const float4*>(&As[k][ty * 4]);
            float4 a1 = *reinterpret_cast<const float4*>(&As[k][ty * 4 + 64]);
            float4 b0 = *reinterpret_cast<const float4*>(&Bs[k][tx * 4]);
            float4 b1 = *reinterpret_cast<const float4*>(&Bs[k][tx * 4 + 64]);
            float av[2][4] = {{a0.x, a0.y, a0.z, a0.w}, {a1.x, a1.y, a1.z, a1.w}};
            float bv[2][4] = {{b0.x, b0.y, b0.z, b0.w}, {b1.x, b1.y, b1.z, b1.w}};
            #pragma unroll
            for (int ih = 0; ih < 2; ++ih)
                #pragma unroll
                for (int jh = 0; jh < 2; ++jh)
                    #pragma unroll
                    for (int i = 0; i < 4; ++i)
                        #pragma unroll
                        for (int j = 0; j < 4; ++j)
                            c[ih][jh][i][j] += av[ih][i] * bv[jh][j];
        }
        __syncthreads();
    }
    #pragma unroll
    for (int ih = 0; ih < 2; ++ih)
        #pragma unroll
        for (int i = 0; i < 4; ++i) {
            int row = m0 + ih * 64 + ty * 4 + i;
            #pragma unroll
            for (int jh = 0; jh < 2; ++jh) {
                float4 w = {c[ih][jh][i][0], c[ih][jh][i][1], c[ih][jh][i][2], c[ih][jh][i][3]};
                *reinterpret_cast<float4*>(sb + (size_t)row * NP + n0 + jh * 64 + tx * 4) = w;
            }
        }
}

// ---------------- kernel 3: iterative top-12 per row (tie -> lowest index) ----
__global__ void __launch_bounds__(256) k_topk(const float* __restrict__ sim,
                                              int* __restrict__ knn, size_t simstride) {
    __shared__ float row[NP];
    __shared__ float bval[4];
    __shared__ int bidx[4];
    int p = blockIdx.x;
    int batch = blockIdx.y;
    int t = threadIdx.x;
    const float* sr = sim + (size_t)batch * simstride + (size_t)p * NP;
    for (int j = t; j < NP; j += 256) row[j] = sr[j];
    __syncthreads();
    if (t == 0) row[p] = -INFINITY;   // exclude self
    __syncthreads();
    int* ko = knn + ((size_t)batch * NP + p) * KNN;
    for (int r = 0; r < KNN; ++r) {
        float bv = -INFINITY; int bi = NP;
        for (int j = t; j < NP; j += 256) {
            float v = row[j];
            if (v > bv) { bv = v; bi = j; }
        }
        #pragma unroll
        for (int off = 32; off; off >>= 1) {
            float ov = __shfl_xor(bv, off, 64);
            int oi = __shfl_xor(bi, off, 64);
            if (ov > bv || (ov == bv && oi < bi)) { bv = ov; bi = oi; }
        }
        if ((t & 63) == 0) { bval[t >> 6] = bv; bidx[t >> 6] = bi; }
        __syncthreads();
        if (t == 0) {
            float fv = bval[0]; int fi = bidx[0];
            #pragma unroll
            for (int w = 1; w < 4; ++w)
                if (bval[w] > fv || (bval[w] == fv && bidx[w] < fi)) { fv = bval[w]; fi = bidx[w]; }
            ko[r] = fi;
            row[fi] = -INFINITY;
        }
        __syncthreads();
    }
}

// ---------------- kernel 4: U' = X@W1a - X@W1b + b1, V = X@W1b ----------------
#define PTS 16
__global__ void __launch_bounds__(192) k_uv(const float* __restrict__ nodes,
                                            const float* __restrict__ W1,
                                            const float* __restrict__ b1,
                                            float* __restrict__ up, float* __restrict__ vv) {
    __shared__ float xs[PTS][NC];
    int t = threadIdx.x;
    int p0 = blockIdx.x * PTS;
    for (int i = t; i < PTS * NC; i += 192) {
        int pt = i / NC, cc = i % NC;
        xs[pt][cc] = nodes[(size_t)(p0 + pt) * NC + cc];
    }
    __syncthreads();
    float accU[PTS] = {}, accV[PTS] = {};
    for (int c4 = 0; c4 < NC; c4 += 4) {
        float wa[4], wb[4];
        #pragma unroll
        for (int i = 0; i < 4; ++i) {
            wa[i] = W1[(size_t)(c4 + i) * NC + t];
            wb[i] = W1[(size_t)(c4 + i + NC) * NC + t];
        }
        #pragma unroll
        for (int pt = 0; pt < PTS; ++pt) {
            float4 xv = *reinterpret_cast<const float4*>(&xs[pt][c4]);
            accU[pt] += xv.x * wa[0] + xv.y * wa[1] + xv.z * wa[2] + xv.w * wa[3];
            accV[pt] += xv.x * wb[0] + xv.y * wb[1] + xv.z * wb[2] + xv.w * wb[3];
        }
    }
    float bb = b1[t];
    #pragma unroll
    for (int pt = 0; pt < PTS; ++pt) {
        up[(size_t)(p0 + pt) * NC + t] = accU[pt] - accV[pt] + bb;
        vv[(size_t)(p0 + pt) * NC + t] = accV[pt];
    }
}

// ---------------- prep: W2T bf16 [n][k] from W2 f32 [k][n] --------------------
__global__ void __launch_bounds__(256) k_w2t(const float* __restrict__ W2,
                                             ushort* __restrict__ w2t) {
    int idx = blockIdx.x * 256 + threadIdx.x;
    if (idx >= NC * NC) return;
    int n = idx / NC, k = idx % NC;
    w2t[(size_t)n * NC + k] = f2bf(W2[(size_t)k * NC + n]);
}

// ---------------- kernel 5: MFMA edge MLP + mean_k + LayerNorm ----------------
// 8 points/block, 256 threads (4 waves). Each point = one 16-row M-tile
// (12 real edges + 4 dummy rows). Wave w owns N-slice [48w, 48w+48).
#define PT 8
#define HSTR 200   // bf16 row stride: 400 B -> uniform bank spread for b128 reads
__global__ void __launch_bounds__(256) k_edge2(const float* __restrict__ up,
                                               const float* __restrict__ vv,
                                               const int* __restrict__ knn,
                                               const ushort* __restrict__ w2t,
                                               const float* __restrict__ b2,
                                               const float* __restrict__ gamma,
                                               const float* __restrict__ beta,
                                               float* __restrict__ out) {
    __shared__ ushort hs[PT * 16][HSTR];   // 51200 B; aliased as f32 agg later
    __shared__ int qsh[PT * KNN];
    int t = threadIdx.x;
    int w = t >> 6, l = t & 63;
    int lg = l >> 4, lr = l & 15;
    int pt0 = blockIdx.x * PT;
    int b = pt0 / NP;
    if (t < PT * KNN) qsh[t] = knn[(size_t)pt0 * KNN + t];
    __syncthreads();

    // ---- stage h (bf16) : wave w stages points 2w, 2w+1 ----
    #pragma unroll
    for (int pi = 0; pi < 2; ++pi) {
        int p = 2 * w + pi;
        const float* uP = up + (size_t)(pt0 + p) * NC;
        float u0 = uP[l], u1 = uP[l + 64], u2 = uP[l + 128];
        for (int e = 0; e < KNN; ++e) {
            int q = qsh[p * KNN + e];
            const float* vq = vv + ((size_t)b * NP + q) * NC;
            int row = p * 16 + e;
            hs[row][l]       = f2bf(lrelu(u0 + vq[l]));
            hs[row][l + 64]  = f2bf(lrelu(u1 + vq[l + 64]));
            hs[row][l + 128] = f2bf(lrelu(u2 + vq[l + 128]));
        }
        #pragma unroll
        for (int e = KNN; e < 16; ++e) {
            int row = p * 16 + e;
            hs[row][l] = 0; hs[row][l + 64] = 0; hs[row][l + 128] = 0;
        }
    }
    __syncthreads();

    // ---- MFMA: M = 128 edge-rows, N = 48 per wave, K = 192 ----
    int n0 = w * 48;
    f32x4 acc[PT][3];
    #pragma unroll
    for (int mt = 0; mt < PT; ++mt)
        #pragma unroll
        for (int nt = 0; nt < 3; ++nt)
            acc[mt][nt] = (f32x4){0.f, 0.f, 0.f, 0.f};
    for (int kb = 0; kb < NC; kb += 32) {
        bf16x8 bf[3];
        #pragma unroll
        for (int nt = 0; nt < 3; ++nt)
            bf[nt] = *reinterpret_cast<const bf16x8*>(&w2t[(size_t)(n0 + nt * 16 + lr) * NC + kb + 8 * lg]);
        #pragma unroll
        for (int mt = 0; mt < PT; ++mt) {
            bf16x8 af = *reinterpret_cast<const bf16x8*>(&hs[mt * 16 + lr][kb + 8 * lg]);
            #pragma unroll
            for (int nt = 0; nt < 3; ++nt)
                acc[mt][nt] = __builtin_amdgcn_mfma_f32_16x16x32_bf16(af, bf[nt], acc[mt][nt], 0, 0, 0);
        }
    }
    __syncthreads();   // all waves done reading hs; safe to alias

    // ---- epilogue: lrelu(+b2), mean over 12 edges via 2 shuffles ----
    float* aggf = (float*)&hs[0][0];   // [PT][NC]
    float bb[3];
    #pragma unroll
    for (int nt = 0; nt < 3; ++nt) bb[nt] = b2[n0 + nt * 16 + lr];
    #pragma unroll
    for (int mt = 0; mt < PT; ++mt) {
        #pragma unroll
        for (int nt = 0; nt < 3; ++nt) {
            float s = 0.f;
            if (lg < 3) {   // rows 0..11 real, group 3 = dummy rows 12..15
                #pragma unroll
                for (int j = 0; j < 4; ++j) s += lrelu(acc[mt][nt][j] + bb[nt]);
            }
            s += __shfl_xor(s, 16, 64);
            s += __shfl_xor(s, 32, 64);
            if (lg == 0) aggf[mt * NC + n0 + nt * 16 + lr] = s * (1.0f / KNN);
        }
    }
    __syncthreads();

    // ---- LayerNorm: wave w handles points w, w+4 ----
    #pragma unroll
    for (int pi = 0; pi < 2; ++pi) {
        int p = w + 4 * pi;
        float a0 = aggf[p * NC + l], a1 = aggf[p * NC + l + 64], a2 = aggf[p * NC + l + 128];
        float s = a0 + a1 + a2;
        #pragma unroll
        for (int off = 32; off; off >>= 1) s += __shfl_xor(s, off, 64);
        float mu = s / (float)NC;
        float d0 = a0 - mu, d1 = a1 - mu, d2 = a2 - mu;
        float vs = d0 * d0 + d1 * d1 + d2 * d2;
        #pragma unroll
        for (int off = 32; off; off >>= 1) vs += __shfl_xor(vs, off, 64);
        float rstd = 1.0f / sqrtf(vs / (float)NC + 1e-5f);
        float* o = out + (size_t)(pt0 + p) * NC;
        o[l]       = d0 * rstd * gamma[l]       + beta[l];
        o[l + 64]  = d1 * rstd * gamma[l + 64]  + beta[l + 64];
        o[l + 128] = d2 * rstd * gamma[l + 128] + beta[l + 128];
    }
}

extern "C" void kernel_launch(void* const* d_in, const int* in_sizes, int n_in,
                              void* d_out, int out_size, void* d_ws, size_t ws_size,
                              hipStream_t stream) {
    const float* nodes = (const float*)d_in[0];
    const float* W1    = (const float*)d_in[1];
    const float* b1    = (const float*)d_in[2];
    const float* W2    = (const float*)d_in[3];
    const float* b2    = (const float*)d_in[4];
    const float* gamma = (const float*)d_in[5];
    const float* beta  = (const float*)d_in[6];
    float* out = (float*)d_out;

    float*  xn  = (float*)d_ws;                        // B*P*C
    float*  up  = xn + (size_t)NB * NP * NC;           // B*P*C
    float*  vv  = up + (size_t)NB * NP * NC;           // B*P*C
    int*    knn = (int*)(vv + (size_t)NB * NP * NC);   // B*P*K
    ushort* w2t = (ushort*)(knn + (size_t)NB * NP * KNN); // C*C bf16
    float*  sim = (float*)(w2t + (size_t)NC * NC);

    size_t fixed_bytes = ((size_t)3 * NB * NP * NC + (size_t)NB * NP * KNN) * 4
                       + (size_t)NC * NC * 2;
    bool full = ws_size >= fixed_bytes + (size_t)NB * NP * NP * 4;

    k_normalize<<<NB * NP / 4, 256, 0, stream>>>(nodes, xn);
    k_uv<<<NB * NP / PTS, 192, 0, stream>>>(nodes, W1, b1, up, vv);
    k_w2t<<<(NC * NC + 255) / 256, 256, 0, stream>>>(W2, w2t);
    if (full) {
        k_sim<<<dim3(NP / 128, NP / 128, NB), 256, 0, stream>>>(xn, sim,
                                                                (size_t)NP * NC, (size_t)NP * NP);
        k_topk<<<dim3(NP, NB), 256, 0, stream>>>(sim, knn, (size_t)NP * NP);
    } else {
        for (int b = 0; b < NB; ++b) {
            k_sim<<<dim3(NP / 128, NP / 128, 1), 256, 0, stream>>>(xn + (size_t)b * NP * NC, sim, 0, 0);
            k_topk<<<dim3(NP, 1), 256, 0, stream>>>(sim, knn + (size_t)b * NP * KNN, 0);
        }
    }
    k_edge2<<<NB * NP / PT, 256, 0, stream>>>(up, vv, knn, w2t, b2, gamma, beta, out);
}

// Round 3
// 222.111 us; speedup vs baseline: 1.4318x; 1.2052x over previous
//
#include <hip/hip_runtime.h>
#include <math.h>

#define NB 4
#define NP 2048
#define NC 192
#define KNN 12
#define NEG_SLOPE 0.2f

typedef __attribute__((ext_vector_type(8))) short bf16x8;
typedef __attribute__((ext_vector_type(4))) float f32x4;

__device__ __forceinline__ float lrelu(float x) { return x >= 0.0f ? x : NEG_SLOPE * x; }

__device__ __forceinline__ ushort f2bf(float x) {
    unsigned u = __float_as_uint(x);
    unsigned r = (u + 0x7FFFu + ((u >> 16) & 1u)) >> 16;   // RNE
    return (ushort)r;
}

// ---------------- kernel 1: L2-normalize rows (4 points/block, 1 wave each) ----
__global__ void __launch_bounds__(256) k_normalize(const float* __restrict__ nodes,
                                                   float* __restrict__ xn) {
    int wave = threadIdx.x >> 6;
    int lane = threadIdx.x & 63;
    size_t pt = (size_t)blockIdx.x * 4 + wave;
    const float* x = nodes + pt * NC;
    float v0 = x[lane], v1 = x[lane + 64], v2 = x[lane + 128];
    float s = v0 * v0 + v1 * v1 + v2 * v2;
    #pragma unroll
    for (int off = 32; off; off >>= 1) s += __shfl_xor(s, off, 64);
    float inv = 1.0f / fmaxf(sqrtf(s), 1e-12f);
    float* o = xn + pt * NC;
    o[lane] = v0 * inv; o[lane + 64] = v1 * inv; o[lane + 128] = v2 * inv;
}

// ---------------- kernel 2: sim = Xn_b * Xn_b^T  (128x128 tile, f32) ----------
#define LDST 132
__global__ void __launch_bounds__(256) k_sim(const float* __restrict__ xn,
                                             float* __restrict__ sim,
                                             size_t xstride, size_t simstride) {
    __shared__ float As[16][LDST];
    __shared__ float Bs[16][LDST];
    const float* xb = xn + (size_t)blockIdx.z * xstride;
    float* sb = sim + (size_t)blockIdx.z * simstride;
    int t = threadIdx.x;
    int tx = t & 15, ty = t >> 4;
    int m0 = blockIdx.y * 128, n0 = blockIdx.x * 128;
    int lr = t >> 2;           // 0..63
    int kq = (t & 3) * 4;      // 0,4,8,12
    float c[2][2][4][4] = {};
    for (int kb = 0; kb < NC; kb += 16) {
        #pragma unroll
        for (int s = 0; s < 2; ++s) {
            int r = lr + 64 * s;
            float4 va = *reinterpret_cast<const float4*>(xb + (size_t)(m0 + r) * NC + kb + kq);
            As[kq + 0][r] = va.x; As[kq + 1][r] = va.y; As[kq + 2][r] = va.z; As[kq + 3][r] = va.w;
            float4 vb = *reinterpret_cast<const float4*>(xb + (size_t)(n0 + r) * NC + kb + kq);
            Bs[kq + 0][r] = vb.x; Bs[kq + 1][r] = vb.y; Bs[kq + 2][r] = vb.z; Bs[kq + 3][r] = vb.w;
        }
        __syncthreads();
        #pragma unroll
        for (int k = 0; k < 16; ++k) {
            float4 a0 = *reinterpret_cast<const float4*>(&As[k][ty * 4]);
            float4 a1 = *reinterpret_cast<const float4*>(&As[k][ty * 4 + 64]);
            float4 b0 = *reinterpret_cast<const float4*>(&Bs[k][tx * 4]);
            float4 b1 = *reinterpret_cast<const float4*>(&Bs[k][tx * 4 + 64]);
            float av[2][4] = {{a0.x, a0.y, a0.z, a0.w}, {a1.x, a1.y, a1.z, a1.w}};
            float bv[2][4] = {{b0.x, b0.y, b0.z, b0.w}, {b1.x, b1.y, b1.z, b1.w}};
            #pragma unroll
            for (int ih = 0; ih < 2; ++ih)
                #pragma unroll
                for (int jh = 0; jh < 2; ++jh)
                    #pragma unroll
                    for (int i = 0; i < 4; ++i)
                        #pragma unroll
                        for (int j = 0; j < 4; ++j)
                            c[ih][jh][i][j] += av[ih][i] * bv[jh][j];
        }
        __syncthreads();
    }
    #pragma unroll
    for (int ih = 0; ih < 2; ++ih)
        #pragma unroll
        for (int i = 0; i < 4; ++i) {
            int row = m0 + ih * 64 + ty * 4 + i;
            #pragma unroll
            for (int jh = 0; jh < 2; ++jh) {
                float4 w = {c[ih][jh][i][0], c[ih][jh][i][1], c[ih][jh][i][2], c[ih][jh][i][3]};
                *reinterpret_cast<float4*>(sb + (size_t)row * NP + n0 + jh * 64 + tx * 4) = w;
            }
        }
}

// -------- kernel 3: register-resident wave-per-row top-12 (no LDS/barriers) ---
// One wave per row. Lane owns 32 elements; maintains sorted-ascending top-12
// in registers (branchless shift-insert). Merge: 12x wave-butterfly argmax
// with (value desc, index asc) tie-break; winner pops its list.
__global__ void __launch_bounds__(256) k_topk2(const float* __restrict__ sim,
                                               int* __restrict__ knn,
                                               size_t simstride) {
    int wv = threadIdx.x >> 6, lane = threadIdx.x & 63;
    int row = blockIdx.x * 4 + wv;           // row over this launch
    int batch = row / NP, p = row % NP;
    const float* sr = sim + (size_t)batch * simstride + (size_t)p * NP;

    // preload all 32 elements (8 coalesced float4 per lane)
    float4 v4[8];
    #pragma unroll
    for (int i = 0; i < 8; ++i)
        v4[i] = *reinterpret_cast<const float4*>(sr + lane * 4 + i * 256);

    float tv[KNN]; int ti[KNN];
    #pragma unroll
    for (int r = 0; r < KNN; ++r) { tv[r] = -INFINITY; ti[r] = 0x7FFFFFFF; }

    #pragma unroll
    for (int i = 0; i < 8; ++i) {
        int base = lane * 4 + i * 256;
        float vs[4] = {v4[i].x, v4[i].y, v4[i].z, v4[i].w};
        #pragma unroll
        for (int j = 0; j < 4; ++j) {
            int idx = base + j;
            float v = (idx == p) ? -INFINITY : vs[j];   // exclude self
            if (v > tv[0]) {
                bool c[KNN];
                #pragma unroll
                for (int r = 0; r < KNN; ++r) c[r] = v > tv[r];
                #pragma unroll
                for (int r = 0; r < KNN - 1; ++r) {
                    tv[r] = c[r + 1] ? tv[r + 1] : (c[r] ? v : tv[r]);
                    ti[r] = c[r + 1] ? ti[r + 1] : (c[r] ? idx : ti[r]);
                }
                tv[KNN - 1] = c[KNN - 1] ? v : tv[KNN - 1];
                ti[KNN - 1] = c[KNN - 1] ? idx : ti[KNN - 1];
            }
        }
    }

    int* ko = knn + (size_t)row * KNN;
    for (int r = 0; r < KNN; ++r) {
        float bv = tv[KNN - 1]; int bi = ti[KNN - 1];
        #pragma unroll
        for (int off = 1; off < 64; off <<= 1) {
            float ov = __shfl_xor(bv, off, 64);
            int   oi = __shfl_xor(bi, off, 64);
            if (ov > bv || (ov == bv && oi < bi)) { bv = ov; bi = oi; }
        }
        if (bv == tv[KNN - 1] && bi == ti[KNN - 1]) {   // unique winner (idx unique)
            ko[r] = bi;
            #pragma unroll
            for (int s = KNN - 1; s > 0; --s) { tv[s] = tv[s - 1]; ti[s] = ti[s - 1]; }
            tv[0] = -INFINITY; ti[0] = 0x7FFFFFFF;
        }
    }
}

// ---------------- kernel 4: U' = X@W1a - X@W1b + b1, V = X@W1b ----------------
#define PTS 16
__global__ void __launch_bounds__(192) k_uv(const float* __restrict__ nodes,
                                            const float* __restrict__ W1,
                                            const float* __restrict__ b1,
                                            float* __restrict__ up, float* __restrict__ vv) {
    __shared__ float xs[PTS][NC];
    int t = threadIdx.x;
    int p0 = blockIdx.x * PTS;
    for (int i = t; i < PTS * NC; i += 192) {
        int pt = i / NC, cc = i % NC;
        xs[pt][cc] = nodes[(size_t)(p0 + pt) * NC + cc];
    }
    __syncthreads();
    float accU[PTS] = {}, accV[PTS] = {};
    for (int c4 = 0; c4 < NC; c4 += 4) {
        float wa[4], wb[4];
        #pragma unroll
        for (int i = 0; i < 4; ++i) {
            wa[i] = W1[(size_t)(c4 + i) * NC + t];
            wb[i] = W1[(size_t)(c4 + i + NC) * NC + t];
        }
        #pragma unroll
        for (int pt = 0; pt < PTS; ++pt) {
            float4 xv = *reinterpret_cast<const float4*>(&xs[pt][c4]);
            accU[pt] += xv.x * wa[0] + xv.y * wa[1] + xv.z * wa[2] + xv.w * wa[3];
            accV[pt] += xv.x * wb[0] + xv.y * wb[1] + xv.z * wb[2] + xv.w * wb[3];
        }
    }
    float bb = b1[t];
    #pragma unroll
    for (int pt = 0; pt < PTS; ++pt) {
        up[(size_t)(p0 + pt) * NC + t] = accU[pt] - accV[pt] + bb;
        vv[(size_t)(p0 + pt) * NC + t] = accV[pt];
    }
}

// ---------------- prep: W2T bf16 [n][k] from W2 f32 [k][n] --------------------
__global__ void __launch_bounds__(256) k_w2t(const float* __restrict__ W2,
                                             ushort* __restrict__ w2t) {
    int idx = blockIdx.x * 256 + threadIdx.x;
    if (idx >= NC * NC) return;
    int n = idx / NC, k = idx % NC;
    w2t[(size_t)n * NC + k] = f2bf(W2[(size_t)k * NC + n]);
}

// ---------------- kernel 5: MFMA edge MLP + mean_k + LayerNorm ----------------
#define PT 8
#define HSTR 200
__global__ void __launch_bounds__(256) k_edge2(const float* __restrict__ up,
                                               const float* __restrict__ vv,
                                               const int* __restrict__ knn,
                                               const ushort* __restrict__ w2t,
                                               const float* __restrict__ b2,
                                               const float* __restrict__ gamma,
                                               const float* __restrict__ beta,
                                               float* __restrict__ out) {
    __shared__ ushort hs[PT * 16][HSTR];
    __shared__ int qsh[PT * KNN];
    int t = threadIdx.x;
    int w = t >> 6, l = t & 63;
    int lg = l >> 4, lr = l & 15;
    int pt0 = blockIdx.x * PT;
    int b = pt0 / NP;
    if (t < PT * KNN) qsh[t] = knn[(size_t)pt0 * KNN + t];
    __syncthreads();

    #pragma unroll
    for (int pi = 0; pi < 2; ++pi) {
        int p = 2 * w + pi;
        const float* uP = up + (size_t)(pt0 + p) * NC;
        float u0 = uP[l], u1 = uP[l + 64], u2 = uP[l + 128];
        for (int e = 0; e < KNN; ++e) {
            int q = qsh[p * KNN + e];
            const float* vq = vv + ((size_t)b * NP + q) * NC;
            int row = p * 16 + e;
            hs[row][l]       = f2bf(lrelu(u0 + vq[l]));
            hs[row][l + 64]  = f2bf(lrelu(u1 + vq[l + 64]));
            hs[row][l + 128] = f2bf(lrelu(u2 + vq[l + 128]));
        }
        #pragma unroll
        for (int e = KNN; e < 16; ++e) {
            int row = p * 16 + e;
            hs[row][l] = 0; hs[row][l + 64] = 0; hs[row][l + 128] = 0;
        }
    }
    __syncthreads();

    int n0 = w * 48;
    f32x4 acc[PT][3];
    #pragma unroll
    for (int mt = 0; mt < PT; ++mt)
        #pragma unroll
        for (int nt = 0; nt < 3; ++nt)
            acc[mt][nt] = (f32x4){0.f, 0.f, 0.f, 0.f};
    for (int kb = 0; kb < NC; kb += 32) {
        bf16x8 bf[3];
        #pragma unroll
        for (int nt = 0; nt < 3; ++nt)
            bf[nt] = *reinterpret_cast<const bf16x8*>(&w2t[(size_t)(n0 + nt * 16 + lr) * NC + kb + 8 * lg]);
        #pragma unroll
        for (int mt = 0; mt < PT; ++mt) {
            bf16x8 af = *reinterpret_cast<const bf16x8*>(&hs[mt * 16 + lr][kb + 8 * lg]);
            #pragma unroll
            for (int nt = 0; nt < 3; ++nt)
                acc[mt][nt] = __builtin_amdgcn_mfma_f32_16x16x32_bf16(af, bf[nt], acc[mt][nt], 0, 0, 0);
        }
    }
    __syncthreads();

    float* aggf = (float*)&hs[0][0];
    float bb[3];
    #pragma unroll
    for (int nt = 0; nt < 3; ++nt) bb[nt] = b2[n0 + nt * 16 + lr];
    #pragma unroll
    for (int mt = 0; mt < PT; ++mt) {
        #pragma unroll
        for (int nt = 0; nt < 3; ++nt) {
            float s = 0.f;
            if (lg < 3) {
                #pragma unroll
                for (int j = 0; j < 4; ++j) s += lrelu(acc[mt][nt][j] + bb[nt]);
            }
            s += __shfl_xor(s, 16, 64);
            s += __shfl_xor(s, 32, 64);
            if (lg == 0) aggf[mt * NC + n0 + nt * 16 + lr] = s * (1.0f / KNN);
        }
    }
    __syncthreads();

    #pragma unroll
    for (int pi = 0; pi < 2; ++pi) {
        int p = w + 4 * pi;
        float a0 = aggf[p * NC + l], a1 = aggf[p * NC + l + 64], a2 = aggf[p * NC + l + 128];
        float s = a0 + a1 + a2;
        #pragma unroll
        for (int off = 32; off; off >>= 1) s += __shfl_xor(s, off, 64);
        float mu = s / (float)NC;
        float d0 = a0 - mu, d1 = a1 - mu, d2 = a2 - mu;
        float vs = d0 * d0 + d1 * d1 + d2 * d2;
        #pragma unroll
        for (int off = 32; off; off >>= 1) vs += __shfl_xor(vs, off, 64);
        float rstd = 1.0f / sqrtf(vs / (float)NC + 1e-5f);
        float* o = out + (size_t)(pt0 + p) * NC;
        o[l]       = d0 * rstd * gamma[l]       + beta[l];
        o[l + 64]  = d1 * rstd * gamma[l + 64]  + beta[l + 64];
        o[l + 128] = d2 * rstd * gamma[l + 128] + beta[l + 128];
    }
}

extern "C" void kernel_launch(void* const* d_in, const int* in_sizes, int n_in,
                              void* d_out, int out_size, void* d_ws, size_t ws_size,
                              hipStream_t stream) {
    const float* nodes = (const float*)d_in[0];
    const float* W1    = (const float*)d_in[1];
    const float* b1    = (const float*)d_in[2];
    const float* W2    = (const float*)d_in[3];
    const float* b2    = (const float*)d_in[4];
    const float* gamma = (const float*)d_in[5];
    const float* beta  = (const float*)d_in[6];
    float* out = (float*)d_out;

    float*  xn  = (float*)d_ws;                        // B*P*C
    float*  up  = xn + (size_t)NB * NP * NC;           // B*P*C
    float*  vv  = up + (size_t)NB * NP * NC;           // B*P*C
    int*    knn = (int*)(vv + (size_t)NB * NP * NC);   // B*P*K
    ushort* w2t = (ushort*)(knn + (size_t)NB * NP * KNN); // C*C bf16
    float*  sim = (float*)(w2t + (size_t)NC * NC);

    size_t fixed_bytes = ((size_t)3 * NB * NP * NC + (size_t)NB * NP * KNN) * 4
                       + (size_t)NC * NC * 2;
    bool full = ws_size >= fixed_bytes + (size_t)NB * NP * NP * 4;

    k_normalize<<<NB * NP / 4, 256, 0, stream>>>(nodes, xn);
    k_uv<<<NB * NP / PTS, 192, 0, stream>>>(nodes, W1, b1, up, vv);
    k_w2t<<<(NC * NC + 255) / 256, 256, 0, stream>>>(W2, w2t);
    if (full) {
        k_sim<<<dim3(NP / 128, NP / 128, NB), 256, 0, stream>>>(xn, sim,
                                                                (size_t)NP * NC, (size_t)NP * NP);
        k_topk2<<<NB * NP / 4, 256, 0, stream>>>(sim, knn, (size_t)NP * NP);
    } else {
        for (int b = 0; b < NB; ++b) {
            k_sim<<<dim3(NP / 128, NP / 128, 1), 256, 0, stream>>>(xn + (size_t)b * NP * NC, sim, 0, 0);
            k_topk2<<<NP / 4, 256, 0, stream>>>(sim, knn + (size_t)b * NP * KNN, 0);
        }
    }
    k_edge2<<<NB * NP / PT, 256, 0, stream>>>(up, vv, knn, w2t, b2, gamma, beta, out);
}

// Round 4
// 191.045 us; speedup vs baseline: 1.6646x; 1.1626x over previous
//
#include <hip/hip_runtime.h>
#include <math.h>

#define NB 4
#define NP 2048
#define NC 192
#define KNN 12
#define KSEL 16
#define NEG_SLOPE 0.2f

typedef __attribute__((ext_vector_type(8))) short bf16x8;
typedef __attribute__((ext_vector_type(4))) float f32x4;

__device__ __forceinline__ float lrelu(float x) { return x >= 0.0f ? x : NEG_SLOPE * x; }

__device__ __forceinline__ ushort f2bf(float x) {
    unsigned u = __float_as_uint(x);
    unsigned r = (u + 0x7FFFu + ((u >> 16) & 1u)) >> 16;   // RNE
    return (ushort)r;
}

// ------- kernel 1: L2-normalize rows; write f32 xn (rescore) + bf16 xh (MFMA) -
__global__ void __launch_bounds__(256) k_normalize(const float* __restrict__ nodes,
                                                   float* __restrict__ xn,
                                                   ushort* __restrict__ xh) {
    int wave = threadIdx.x >> 6;
    int lane = threadIdx.x & 63;
    size_t pt = (size_t)blockIdx.x * 4 + wave;
    const float* x = nodes + pt * NC;
    float v0 = x[lane], v1 = x[lane + 64], v2 = x[lane + 128];
    float s = v0 * v0 + v1 * v1 + v2 * v2;
    #pragma unroll
    for (int off = 32; off; off >>= 1) s += __shfl_xor(s, off, 64);
    float inv = 1.0f / fmaxf(sqrtf(s), 1e-12f);
    float f0 = v0 * inv, f1 = v1 * inv, f2 = v2 * inv;
    float* o = xn + pt * NC;
    o[lane] = f0; o[lane + 64] = f1; o[lane + 128] = f2;
    ushort* oh = xh + pt * NC;
    oh[lane] = f2bf(f0); oh[lane + 64] = f2bf(f1); oh[lane + 128] = f2bf(f2);
}

// ------- kernel 2: sim = Xh * Xh^T via bf16 MFMA (approximate, f32 out) -------
// 128x128 tile, 4 waves in 2x2, each wave 64x64 (4x4 fragments of 16x16x32).
__global__ void __launch_bounds__(256) k_sim3(const ushort* __restrict__ xh,
                                              float* __restrict__ sim,
                                              size_t xstride, size_t simstride) {
    __shared__ ushort Ah[128][72];   // stride 72 bf16 = 144 B -> 2-way (free)
    __shared__ ushort Bh[128][72];
    const ushort* XbH = xh + (size_t)blockIdx.z * xstride;
    float* sb = sim + (size_t)blockIdx.z * simstride;
    int t = threadIdx.x;
    int w = t >> 6, l = t & 63;
    int wm = w >> 1, wn = w & 1;
    int lg = l >> 4, lr = l & 15;
    int m0 = blockIdx.y * 128, n0 = blockIdx.x * 128;

    f32x4 acc[4][4];
    #pragma unroll
    for (int mi = 0; mi < 4; ++mi)
        #pragma unroll
        for (int ni = 0; ni < 4; ++ni)
            acc[mi][ni] = (f32x4){0.f, 0.f, 0.f, 0.f};

    int r = t >> 3, c = (t & 7) * 8;
    for (int ks = 0; ks < 3; ++ks) {
        int kb = ks * 64;
        #pragma unroll
        for (int i = 0; i < 4; ++i) {
            int row = r + 32 * i;
            *reinterpret_cast<bf16x8*>(&Ah[row][c]) =
                *reinterpret_cast<const bf16x8*>(&XbH[(size_t)(m0 + row) * NC + kb + c]);
            *reinterpret_cast<bf16x8*>(&Bh[row][c]) =
                *reinterpret_cast<const bf16x8*>(&XbH[(size_t)(n0 + row) * NC + kb + c]);
        }
        __syncthreads();
        #pragma unroll
        for (int ksub = 0; ksub < 2; ++ksub) {
            int ko = ksub * 32 + 8 * lg;
            bf16x8 af[4], bf[4];
            #pragma unroll
            for (int f = 0; f < 4; ++f) {
                af[f] = *reinterpret_cast<const bf16x8*>(&Ah[wm * 64 + f * 16 + lr][ko]);
                bf[f] = *reinterpret_cast<const bf16x8*>(&Bh[wn * 64 + f * 16 + lr][ko]);
            }
            #pragma unroll
            for (int mi = 0; mi < 4; ++mi)
                #pragma unroll
                for (int ni = 0; ni < 4; ++ni)
                    acc[mi][ni] = __builtin_amdgcn_mfma_f32_16x16x32_bf16(af[mi], bf[ni], acc[mi][ni], 0, 0, 0);
        }
        __syncthreads();
    }
    #pragma unroll
    for (int mi = 0; mi < 4; ++mi)
        #pragma unroll
        for (int j = 0; j < 4; ++j) {
            int row = m0 + wm * 64 + mi * 16 + lg * 4 + j;
            #pragma unroll
            for (int ni = 0; ni < 4; ++ni)
                sb[(size_t)row * NP + n0 + wn * 64 + ni * 16 + lr] = acc[mi][ni][j];
        }
}

// ------- kernel 3: top-16 approx select + exact f32 rescore -> exact 12-set ---
// One wave per row. Phase 1: register top-16 stream insert. Phase 2: 16x
// butterfly-argmax merge (candidate g -> lanes 4g..4g+3). Phase 3: exact dot
// on xn (4-lane split), rank, ballot-compact the top-12 set.
__global__ void __launch_bounds__(256) k_topk3(const float* __restrict__ sim,
                                               const float* __restrict__ xn,
                                               int* __restrict__ knn,
                                               size_t simstride, size_t xstride) {
    int wv = threadIdx.x >> 6, lane = threadIdx.x & 63;
    int row = blockIdx.x * 4 + wv;
    int batch = row / NP, p = row % NP;
    const float* sr = sim + (size_t)batch * simstride + (size_t)p * NP;

    float4 v4[8];
    #pragma unroll
    for (int i = 0; i < 8; ++i)
        v4[i] = *reinterpret_cast<const float4*>(sr + lane * 4 + i * 256);

    float tv[KSEL]; int ti[KSEL];
    #pragma unroll
    for (int q = 0; q < KSEL; ++q) { tv[q] = -INFINITY; ti[q] = 0x7FFFFFFF; }

    #pragma unroll
    for (int i = 0; i < 8; ++i) {
        int base = lane * 4 + i * 256;
        float vs[4] = {v4[i].x, v4[i].y, v4[i].z, v4[i].w};
        #pragma unroll
        for (int j = 0; j < 4; ++j) {
            int idx = base + j;
            float v = (idx == p) ? -INFINITY : vs[j];   // exclude self
            if (v > tv[0]) {
                bool cg[KSEL];
                #pragma unroll
                for (int q = 0; q < KSEL; ++q) cg[q] = v > tv[q];
                #pragma unroll
                for (int q = 0; q < KSEL - 1; ++q) {
                    tv[q] = cg[q + 1] ? tv[q + 1] : (cg[q] ? v : tv[q]);
                    ti[q] = cg[q + 1] ? ti[q + 1] : (cg[q] ? idx : ti[q]);
                }
                tv[KSEL - 1] = cg[KSEL - 1] ? v : tv[KSEL - 1];
                ti[KSEL - 1] = cg[KSEL - 1] ? idx : ti[KSEL - 1];
            }
        }
    }

    int my_q = 0;
    #pragma unroll
    for (int rr = 0; rr < KSEL; ++rr) {
        float bv = tv[KSEL - 1]; int bi = ti[KSEL - 1];
        #pragma unroll
        for (int off = 1; off < 64; off <<= 1) {
            float ov = __shfl_xor(bv, off, 64);
            int   oi = __shfl_xor(bi, off, 64);
            if (ov > bv || (ov == bv && oi < bi)) { bv = ov; bi = oi; }
        }
        if ((lane >> 2) == rr) my_q = bi;
        if (bv == tv[KSEL - 1] && bi == ti[KSEL - 1]) {   // unique winner pops
            #pragma unroll
            for (int s = KSEL - 1; s > 0; --s) { tv[s] = tv[s - 1]; ti[s] = ti[s - 1]; }
            tv[0] = -INFINITY; ti[0] = 0x7FFFFFFF;
        }
    }

    // exact rescore: group g = lane>>2 handles candidate my_q, slice = lane&3
    const float* xb = xn + (size_t)batch * xstride;
    const float* cp = xb + (size_t)p * NC + (lane & 3) * 48;
    const float* cq = xb + (size_t)my_q * NC + (lane & 3) * 48;
    float dot = 0.f;
    #pragma unroll
    for (int i = 0; i < 12; ++i) {
        float4 a = *reinterpret_cast<const float4*>(cp + i * 4);
        float4 bq = *reinterpret_cast<const float4*>(cq + i * 4);
        dot += a.x * bq.x + a.y * bq.y + a.z * bq.z + a.w * bq.w;
    }
    dot += __shfl_xor(dot, 1, 64);
    dot += __shfl_xor(dot, 2, 64);
    int g = lane >> 2;
    int rank = 0;
    #pragma unroll
    for (int j = 0; j < KSEL; ++j) {
        float vj = __shfl(dot, j * 4, 64);
        int   qj = __shfl(my_q, j * 4, 64);
        if (j != g && (vj > dot || (vj == dot && qj < my_q))) ++rank;
    }
    bool keep = ((lane & 3) == 0) && (rank < KNN);
    unsigned long long mask = __ballot(keep);
    int pos = __popcll(mask & ((1ull << lane) - 1));
    if (keep) knn[(size_t)row * KNN + pos] = my_q;
}

// ---------------- kernel 4: U' = X@W1a - X@W1b + b1, V = X@W1b ----------------
#define PTS 16
__global__ void __launch_bounds__(192) k_uv(const float* __restrict__ nodes,
                                            const float* __restrict__ W1,
                                            const float* __restrict__ b1,
                                            float* __restrict__ up, float* __restrict__ vv) {
    __shared__ float xs[PTS][NC];
    int t = threadIdx.x;
    int p0 = blockIdx.x * PTS;
    for (int i = t; i < PTS * NC; i += 192) {
        int pt = i / NC, cc = i % NC;
        xs[pt][cc] = nodes[(size_t)(p0 + pt) * NC + cc];
    }
    __syncthreads();
    float accU[PTS] = {}, accV[PTS] = {};
    for (int c4 = 0; c4 < NC; c4 += 4) {
        float wa[4], wb[4];
        #pragma unroll
        for (int i = 0; i < 4; ++i) {
            wa[i] = W1[(size_t)(c4 + i) * NC + t];
            wb[i] = W1[(size_t)(c4 + i + NC) * NC + t];
        }
        #pragma unroll
        for (int pt = 0; pt < PTS; ++pt) {
            float4 xv = *reinterpret_cast<const float4*>(&xs[pt][c4]);
            accU[pt] += xv.x * wa[0] + xv.y * wa[1] + xv.z * wa[2] + xv.w * wa[3];
            accV[pt] += xv.x * wb[0] + xv.y * wb[1] + xv.z * wb[2] + xv.w * wb[3];
        }
    }
    float bb = b1[t];
    #pragma unroll
    for (int pt = 0; pt < PTS; ++pt) {
        up[(size_t)(p0 + pt) * NC + t] = accU[pt] - accV[pt] + bb;
        vv[(size_t)(p0 + pt) * NC + t] = accV[pt];
    }
}

// ---------------- prep: W2T bf16 [n][k] from W2 f32 [k][n] --------------------
__global__ void __launch_bounds__(256) k_w2t(const float* __restrict__ W2,
                                             ushort* __restrict__ w2t) {
    int idx = blockIdx.x * 256 + threadIdx.x;
    if (idx >= NC * NC) return;
    int n = idx / NC, k = idx % NC;
    w2t[(size_t)n * NC + k] = f2bf(W2[(size_t)k * NC + n]);
}

// ---------------- kernel 5: MFMA edge MLP + mean_k + LayerNorm ----------------
#define PT 8
#define HSTR 200
__global__ void __launch_bounds__(256) k_edge2(const float* __restrict__ up,
                                               const float* __restrict__ vv,
                                               const int* __restrict__ knn,
                                               const ushort* __restrict__ w2t,
                                               const float* __restrict__ b2,
                                               const float* __restrict__ gamma,
                                               const float* __restrict__ beta,
                                               float* __restrict__ out) {
    __shared__ ushort hs[PT * 16][HSTR];
    __shared__ int qsh[PT * KNN];
    int t = threadIdx.x;
    int w = t >> 6, l = t & 63;
    int lg = l >> 4, lr = l & 15;
    int pt0 = blockIdx.x * PT;
    int b = pt0 / NP;
    if (t < PT * KNN) qsh[t] = knn[(size_t)pt0 * KNN + t];
    __syncthreads();

    #pragma unroll
    for (int pi = 0; pi < 2; ++pi) {
        int p = 2 * w + pi;
        const float* uP = up + (size_t)(pt0 + p) * NC;
        float u0 = uP[l], u1 = uP[l + 64], u2 = uP[l + 128];
        for (int e = 0; e < KNN; ++e) {
            int q = qsh[p * KNN + e];
            const float* vq = vv + ((size_t)b * NP + q) * NC;
            int row = p * 16 + e;
            hs[row][l]       = f2bf(lrelu(u0 + vq[l]));
            hs[row][l + 64]  = f2bf(lrelu(u1 + vq[l + 64]));
            hs[row][l + 128] = f2bf(lrelu(u2 + vq[l + 128]));
        }
        #pragma unroll
        for (int e = KNN; e < 16; ++e) {
            int row = p * 16 + e;
            hs[row][l] = 0; hs[row][l + 64] = 0; hs[row][l + 128] = 0;
        }
    }
    __syncthreads();

    int n0 = w * 48;
    f32x4 acc[PT][3];
    #pragma unroll
    for (int mt = 0; mt < PT; ++mt)
        #pragma unroll
        for (int nt = 0; nt < 3; ++nt)
            acc[mt][nt] = (f32x4){0.f, 0.f, 0.f, 0.f};
    for (int kb = 0; kb < NC; kb += 32) {
        bf16x8 bf[3];
        #pragma unroll
        for (int nt = 0; nt < 3; ++nt)
            bf[nt] = *reinterpret_cast<const bf16x8*>(&w2t[(size_t)(n0 + nt * 16 + lr) * NC + kb + 8 * lg]);
        #pragma unroll
        for (int mt = 0; mt < PT; ++mt) {
            bf16x8 af = *reinterpret_cast<const bf16x8*>(&hs[mt * 16 + lr][kb + 8 * lg]);
            #pragma unroll
            for (int nt = 0; nt < 3; ++nt)
                acc[mt][nt] = __builtin_amdgcn_mfma_f32_16x16x32_bf16(af, bf[nt], acc[mt][nt], 0, 0, 0);
        }
    }
    __syncthreads();

    float* aggf = (float*)&hs[0][0];
    float bb[3];
    #pragma unroll
    for (int nt = 0; nt < 3; ++nt) bb[nt] = b2[n0 + nt * 16 + lr];
    #pragma unroll
    for (int mt = 0; mt < PT; ++mt) {
        #pragma unroll
        for (int nt = 0; nt < 3; ++nt) {
            float s = 0.f;
            if (lg < 3) {
                #pragma unroll
                for (int j = 0; j < 4; ++j) s += lrelu(acc[mt][nt][j] + bb[nt]);
            }
            s += __shfl_xor(s, 16, 64);
            s += __shfl_xor(s, 32, 64);
            if (lg == 0) aggf[mt * NC + n0 + nt * 16 + lr] = s * (1.0f / KNN);
        }
    }
    __syncthreads();

    #pragma unroll
    for (int pi = 0; pi < 2; ++pi) {
        int p = w + 4 * pi;
        float a0 = aggf[p * NC + l], a1 = aggf[p * NC + l + 64], a2 = aggf[p * NC + l + 128];
        float s = a0 + a1 + a2;
        #pragma unroll
        for (int off = 32; off; off >>= 1) s += __shfl_xor(s, off, 64);
        float mu = s / (float)NC;
        float d0 = a0 - mu, d1 = a1 - mu, d2 = a2 - mu;
        float vs = d0 * d0 + d1 * d1 + d2 * d2;
        #pragma unroll
        for (int off = 32; off; off >>= 1) vs += __shfl_xor(vs, off, 64);
        float rstd = 1.0f / sqrtf(vs / (float)NC + 1e-5f);
        float* o = out + (size_t)(pt0 + p) * NC;
        o[l]       = d0 * rstd * gamma[l]       + beta[l];
        o[l + 64]  = d1 * rstd * gamma[l + 64]  + beta[l + 64];
        o[l + 128] = d2 * rstd * gamma[l + 128] + beta[l + 128];
    }
}

extern "C" void kernel_launch(void* const* d_in, const int* in_sizes, int n_in,
                              void* d_out, int out_size, void* d_ws, size_t ws_size,
                              hipStream_t stream) {
    const float* nodes = (const float*)d_in[0];
    const float* W1    = (const float*)d_in[1];
    const float* b1    = (const float*)d_in[2];
    const float* W2    = (const float*)d_in[3];
    const float* b2    = (const float*)d_in[4];
    const float* gamma = (const float*)d_in[5];
    const float* beta  = (const float*)d_in[6];
    float* out = (float*)d_out;

    const size_t BPC = (size_t)NB * NP * NC;
    float*  xn  = (float*)d_ws;                        // B*P*C f32
    float*  up  = xn + BPC;                            // B*P*C f32
    float*  vv  = up + BPC;                            // B*P*C f32
    ushort* xh  = (ushort*)(vv + BPC);                 // B*P*C bf16
    int*    knn = (int*)(xh + BPC);                    // B*P*K
    ushort* w2t = (ushort*)(knn + (size_t)NB * NP * KNN); // C*C bf16
    float*  sim = (float*)((char*)(w2t + (size_t)NC * NC) + 8); // pad to 16B
    sim = (float*)(((uintptr_t)sim + 15) & ~(uintptr_t)15);

    size_t fixed_bytes = (size_t)((char*)sim - (char*)d_ws);
    bool full = ws_size >= fixed_bytes + (size_t)NB * NP * NP * 4;

    k_normalize<<<NB * NP / 4, 256, 0, stream>>>(nodes, xn, xh);
    k_uv<<<NB * NP / PTS, 192, 0, stream>>>(nodes, W1, b1, up, vv);
    k_w2t<<<(NC * NC + 255) / 256, 256, 0, stream>>>(W2, w2t);
    if (full) {
        k_sim3<<<dim3(NP / 128, NP / 128, NB), 256, 0, stream>>>(xh, sim,
                                                                 (size_t)NP * NC, (size_t)NP * NP);
        k_topk3<<<NB * NP / 4, 256, 0, stream>>>(sim, xn, knn,
                                                 (size_t)NP * NP, (size_t)NP * NC);
    } else {
        for (int b = 0; b < NB; ++b) {
            k_sim3<<<dim3(NP / 128, NP / 128, 1), 256, 0, stream>>>(xh + (size_t)b * NP * NC, sim, 0, 0);
            k_topk3<<<NP / 4, 256, 0, stream>>>(sim, xn + (size_t)b * NP * NC,
                                                knn + (size_t)b * NP * KNN, 0, 0);
        }
    }
    k_edge2<<<NB * NP / PT, 256, 0, stream>>>(up, vv, knn, w2t, b2, gamma, beta, out);
}

// Round 5
// 166.532 us; speedup vs baseline: 1.9097x; 1.1472x over previous
//
#include <hip/hip_runtime.h>
#include <math.h>

#define NB 4
#define NP 2048
#define NC 192
#define KNN 12
#define KSEL 16
#define NEG_SLOPE 0.2f

typedef __attribute__((ext_vector_type(8))) short bf16x8;
typedef __attribute__((ext_vector_type(4))) float f32x4;

__device__ __forceinline__ float lrelu(float x) { return x >= 0.0f ? x : NEG_SLOPE * x; }

__device__ __forceinline__ ushort f2bf(float x) {
    unsigned u = __float_as_uint(x);
    unsigned r = (u + 0x7FFFu + ((u >> 16) & 1u)) >> 16;   // RNE
    return (ushort)r;
}

// ------- kernel 1: L2-normalize rows; write f32 xn (rescore) + bf16 xh (MFMA) -
__global__ void __launch_bounds__(256) k_normalize(const float* __restrict__ nodes,
                                                   float* __restrict__ xn,
                                                   ushort* __restrict__ xh) {
    int wave = threadIdx.x >> 6;
    int lane = threadIdx.x & 63;
    size_t pt = (size_t)blockIdx.x * 4 + wave;
    const float* x = nodes + pt * NC;
    float v0 = x[lane], v1 = x[lane + 64], v2 = x[lane + 128];
    float s = v0 * v0 + v1 * v1 + v2 * v2;
    #pragma unroll
    for (int off = 32; off; off >>= 1) s += __shfl_xor(s, off, 64);
    float inv = 1.0f / fmaxf(sqrtf(s), 1e-12f);
    float f0 = v0 * inv, f1 = v1 * inv, f2 = v2 * inv;
    float* o = xn + pt * NC;
    o[lane] = f0; o[lane + 64] = f1; o[lane + 128] = f2;
    ushort* oh = xh + pt * NC;
    oh[lane] = f2bf(f0); oh[lane + 64] = f2bf(f1); oh[lane + 128] = f2bf(f2);
}

// ------- kernel 2: sim = Xh * Xh^T via bf16 MFMA (approximate, f32 out) -------
__global__ void __launch_bounds__(256) k_sim3(const ushort* __restrict__ xh,
                                              float* __restrict__ sim,
                                              size_t xstride, size_t simstride) {
    __shared__ ushort Ah[128][72];
    __shared__ ushort Bh[128][72];
    const ushort* XbH = xh + (size_t)blockIdx.z * xstride;
    float* sb = sim + (size_t)blockIdx.z * simstride;
    int t = threadIdx.x;
    int w = t >> 6, l = t & 63;
    int wm = w >> 1, wn = w & 1;
    int lg = l >> 4, lr = l & 15;
    int m0 = blockIdx.y * 128, n0 = blockIdx.x * 128;

    f32x4 acc[4][4];
    #pragma unroll
    for (int mi = 0; mi < 4; ++mi)
        #pragma unroll
        for (int ni = 0; ni < 4; ++ni)
            acc[mi][ni] = (f32x4){0.f, 0.f, 0.f, 0.f};

    int r = t >> 3, c = (t & 7) * 8;
    for (int ks = 0; ks < 3; ++ks) {
        int kb = ks * 64;
        #pragma unroll
        for (int i = 0; i < 4; ++i) {
            int row = r + 32 * i;
            *reinterpret_cast<bf16x8*>(&Ah[row][c]) =
                *reinterpret_cast<const bf16x8*>(&XbH[(size_t)(m0 + row) * NC + kb + c]);
            *reinterpret_cast<bf16x8*>(&Bh[row][c]) =
                *reinterpret_cast<const bf16x8*>(&XbH[(size_t)(n0 + row) * NC + kb + c]);
        }
        __syncthreads();
        #pragma unroll
        for (int ksub = 0; ksub < 2; ++ksub) {
            int ko = ksub * 32 + 8 * lg;
            bf16x8 af[4], bf[4];
            #pragma unroll
            for (int f = 0; f < 4; ++f) {
                af[f] = *reinterpret_cast<const bf16x8*>(&Ah[wm * 64 + f * 16 + lr][ko]);
                bf[f] = *reinterpret_cast<const bf16x8*>(&Bh[wn * 64 + f * 16 + lr][ko]);
            }
            #pragma unroll
            for (int mi = 0; mi < 4; ++mi)
                #pragma unroll
                for (int ni = 0; ni < 4; ++ni)
                    acc[mi][ni] = __builtin_amdgcn_mfma_f32_16x16x32_bf16(af[mi], bf[ni], acc[mi][ni], 0, 0, 0);
        }
        __syncthreads();
    }
    #pragma unroll
    for (int mi = 0; mi < 4; ++mi)
        #pragma unroll
        for (int j = 0; j < 4; ++j) {
            int row = m0 + wm * 64 + mi * 16 + lg * 4 + j;
            #pragma unroll
            for (int ni = 0; ni < 4; ++ni)
                sb[(size_t)row * NP + n0 + wn * 64 + ni * 16 + lr] = acc[mi][ni][j];
        }
}

// ------- kernel 3: threshold+compact+bitonic top-16, exact rescore -> 12-set --
__global__ void __launch_bounds__(256) k_topk4(const float* __restrict__ sim,
                                               const float* __restrict__ xn,
                                               int* __restrict__ knn,
                                               size_t simstride, size_t xstride) {
    __shared__ float cvs[4][64];
    __shared__ int   cis[4][64];
    int wv = threadIdx.x >> 6, lane = threadIdx.x & 63;
    int row = blockIdx.x * 4 + wv;
    int batch = row / NP, p = row % NP;
    const float* sr = sim + (size_t)batch * simstride + (size_t)p * NP;

    float4 v4[8];
    #pragma unroll
    for (int i = 0; i < 8; ++i)
        v4[i] = *reinterpret_cast<const float4*>(sr + lane * 4 + i * 256);

    // self-mask once
    #pragma unroll
    for (int i = 0; i < 8; ++i) {
        int base = lane * 4 + i * 256;
        v4[i].x = (base + 0 == p) ? -INFINITY : v4[i].x;
        v4[i].y = (base + 1 == p) ? -INFINITY : v4[i].y;
        v4[i].z = (base + 2 == p) ? -INFINITY : v4[i].z;
        v4[i].w = (base + 3 == p) ? -INFINITY : v4[i].w;
    }

    // per-lane max
    float lmax = -INFINITY;
    #pragma unroll
    for (int i = 0; i < 8; ++i) {
        lmax = fmaxf(lmax, fmaxf(fmaxf(v4[i].x, v4[i].y), fmaxf(v4[i].z, v4[i].w)));
    }

    // bitonic sort (descending) of 64 lane-maxes, value-only
    float sm = lmax;
    #pragma unroll
    for (int k = 2; k <= 64; k <<= 1) {
        #pragma unroll
        for (int j = k >> 1; j >= 1; j >>= 1) {
            float ov = __shfl_xor(sm, j, 64);
            bool lower = (lane & j) == 0;
            bool up = (lane & k) != 0;
            float lo = fminf(sm, ov), hi = fmaxf(sm, ov);
            sm = (up == lower) ? lo : hi;
        }
    }
    float theta = __shfl(sm, 16, 64);   // 17th-largest lane-max

    // count candidates (> theta)
    int cnt = 0;
    #pragma unroll
    for (int i = 0; i < 8; ++i) {
        cnt += (v4[i].x > theta) + (v4[i].y > theta) + (v4[i].z > theta) + (v4[i].w > theta);
    }
    int x = cnt;
    #pragma unroll
    for (int off = 1; off < 64; off <<= 1) {
        int y = __shfl_up(x, off, 64);
        if (lane >= off) x += y;
    }
    int excl = x - cnt;
    int total = __shfl(x, 63, 64);

    int my_q = 0;
    bool fb = (total < KSEL) || (total > 64);
    if (!fb) {
        cvs[wv][lane] = -INFINITY;
        cis[wv][lane] = 0;
        asm volatile("s_waitcnt lgkmcnt(0)" ::: "memory");
        int pos = excl;
        #pragma unroll
        for (int i = 0; i < 8; ++i) {
            int base = lane * 4 + i * 256;
            float vs[4] = {v4[i].x, v4[i].y, v4[i].z, v4[i].w};
            #pragma unroll
            for (int j = 0; j < 4; ++j) {
                if (vs[j] > theta) {
                    cvs[wv][pos] = vs[j];
                    cis[wv][pos] = base + j;
                    ++pos;
                }
            }
        }
        asm volatile("s_waitcnt lgkmcnt(0)" ::: "memory");
        float v = cvs[wv][lane];
        int   idx = cis[wv][lane];
        // bitonic sort (descending) of 64 (val,idx) pairs
        #pragma unroll
        for (int k = 2; k <= 64; k <<= 1) {
            #pragma unroll
            for (int j = k >> 1; j >= 1; j >>= 1) {
                float ov = __shfl_xor(v, j, 64);
                int   oi = __shfl_xor(idx, j, 64);
                bool lower = (lane & j) == 0;
                bool up = (lane & k) != 0;
                bool ogt = (ov > v);
                float hv = ogt ? ov : v;  int hid = ogt ? oi : idx;
                float lv = ogt ? v : ov;  int lid = ogt ? idx : oi;
                bool keep_lo = (up == lower);
                v   = keep_lo ? lv : hv;
                idx = keep_lo ? lid : hid;
            }
        }
        my_q = __shfl(idx, lane >> 2, 64);   // candidate g -> lanes 4g..4g+3
    } else {
        // exact fallback: R4 insert + merge (wave-uniform branch, ~never taken)
        float tv[KSEL]; int ti[KSEL];
        #pragma unroll
        for (int q = 0; q < KSEL; ++q) { tv[q] = -INFINITY; ti[q] = 0x7FFFFFFF; }
        #pragma unroll
        for (int i = 0; i < 8; ++i) {
            int base = lane * 4 + i * 256;
            float vs[4] = {v4[i].x, v4[i].y, v4[i].z, v4[i].w};
            #pragma unroll
            for (int j = 0; j < 4; ++j) {
                float v = vs[j];
                int idx = base + j;
                if (v > tv[0]) {
                    bool cg[KSEL];
                    #pragma unroll
                    for (int q = 0; q < KSEL; ++q) cg[q] = v > tv[q];
                    #pragma unroll
                    for (int q = 0; q < KSEL - 1; ++q) {
                        tv[q] = cg[q + 1] ? tv[q + 1] : (cg[q] ? v : tv[q]);
                        ti[q] = cg[q + 1] ? ti[q + 1] : (cg[q] ? idx : ti[q]);
                    }
                    tv[KSEL - 1] = cg[KSEL - 1] ? v : tv[KSEL - 1];
                    ti[KSEL - 1] = cg[KSEL - 1] ? idx : ti[KSEL - 1];
                }
            }
        }
        #pragma unroll
        for (int rr = 0; rr < KSEL; ++rr) {
            float bv = tv[KSEL - 1]; int bi = ti[KSEL - 1];
            #pragma unroll
            for (int off = 1; off < 64; off <<= 1) {
                float ov = __shfl_xor(bv, off, 64);
                int   oi = __shfl_xor(bi, off, 64);
                if (ov > bv || (ov == bv && oi < bi)) { bv = ov; bi = oi; }
            }
            if ((lane >> 2) == rr) my_q = bi;
            if (bv == tv[KSEL - 1] && bi == ti[KSEL - 1]) {
                #pragma unroll
                for (int s = KSEL - 1; s > 0; --s) { tv[s] = tv[s - 1]; ti[s] = ti[s - 1]; }
                tv[0] = -INFINITY; ti[0] = 0x7FFFFFFF;
            }
        }
    }

    // exact rescore: group g = lane>>2 handles candidate my_q, slice = lane&3
    const float* xb = xn + (size_t)batch * xstride;
    const float* cp = xb + (size_t)p * NC + (lane & 3) * 48;
    const float* cq = xb + (size_t)my_q * NC + (lane & 3) * 48;
    float dot = 0.f;
    #pragma unroll
    for (int i = 0; i < 12; ++i) {
        float4 a = *reinterpret_cast<const float4*>(cp + i * 4);
        float4 bq = *reinterpret_cast<const float4*>(cq + i * 4);
        dot += a.x * bq.x + a.y * bq.y + a.z * bq.z + a.w * bq.w;
    }
    dot += __shfl_xor(dot, 1, 64);
    dot += __shfl_xor(dot, 2, 64);
    int g = lane >> 2;
    int rank = 0;
    #pragma unroll
    for (int j = 0; j < KSEL; ++j) {
        float vj = __shfl(dot, j * 4, 64);
        int   qj = __shfl(my_q, j * 4, 64);
        if (j != g && (vj > dot || (vj == dot && qj < my_q))) ++rank;
    }
    bool keep = ((lane & 3) == 0) && (rank < KNN);
    unsigned long long mask = __ballot(keep);
    int pos = __popcll(mask & ((1ull << lane) - 1));
    if (keep) knn[(size_t)row * KNN + pos] = my_q;
}

// ---------------- kernel 4: U' = X@W1a - X@W1b + b1, V = X@W1b ----------------
#define PTS 16
__global__ void __launch_bounds__(192) k_uv(const float* __restrict__ nodes,
                                            const float* __restrict__ W1,
                                            const float* __restrict__ b1,
                                            float* __restrict__ up, float* __restrict__ vv) {
    __shared__ float xs[PTS][NC];
    int t = threadIdx.x;
    int p0 = blockIdx.x * PTS;
    for (int i = t; i < PTS * NC; i += 192) {
        int pt = i / NC, cc = i % NC;
        xs[pt][cc] = nodes[(size_t)(p0 + pt) * NC + cc];
    }
    __syncthreads();
    float accU[PTS] = {}, accV[PTS] = {};
    for (int c4 = 0; c4 < NC; c4 += 4) {
        float wa[4], wb[4];
        #pragma unroll
        for (int i = 0; i < 4; ++i) {
            wa[i] = W1[(size_t)(c4 + i) * NC + t];
            wb[i] = W1[(size_t)(c4 + i + NC) * NC + t];
        }
        #pragma unroll
        for (int pt = 0; pt < PTS; ++pt) {
            float4 xv = *reinterpret_cast<const float4*>(&xs[pt][c4]);
            accU[pt] += xv.x * wa[0] + xv.y * wa[1] + xv.z * wa[2] + xv.w * wa[3];
            accV[pt] += xv.x * wb[0] + xv.y * wb[1] + xv.z * wb[2] + xv.w * wb[3];
        }
    }
    float bb = b1[t];
    #pragma unroll
    for (int pt = 0; pt < PTS; ++pt) {
        up[(size_t)(p0 + pt) * NC + t] = accU[pt] - accV[pt] + bb;
        vv[(size_t)(p0 + pt) * NC + t] = accV[pt];
    }
}

// ---------------- prep: W2T bf16 [n][k] from W2 f32 [k][n] --------------------
__global__ void __launch_bounds__(256) k_w2t(const float* __restrict__ W2,
                                             ushort* __restrict__ w2t) {
    int idx = blockIdx.x * 256 + threadIdx.x;
    if (idx >= NC * NC) return;
    int n = idx / NC, k = idx % NC;
    w2t[(size_t)n * NC + k] = f2bf(W2[(size_t)k * NC + n]);
}

// ---------------- kernel 5: MFMA edge MLP + mean_k + LayerNorm ----------------
#define PT 8
#define HSTR 200
__global__ void __launch_bounds__(256) k_edge2(const float* __restrict__ up,
                                               const float* __restrict__ vv,
                                               const int* __restrict__ knn,
                                               const ushort* __restrict__ w2t,
                                               const float* __restrict__ b2,
                                               const float* __restrict__ gamma,
                                               const float* __restrict__ beta,
                                               float* __restrict__ out) {
    __shared__ ushort hs[PT * 16][HSTR];
    __shared__ int qsh[PT * KNN];
    int t = threadIdx.x;
    int w = t >> 6, l = t & 63;
    int lg = l >> 4, lr = l & 15;
    int pt0 = blockIdx.x * PT;
    int b = pt0 / NP;
    if (t < PT * KNN) qsh[t] = knn[(size_t)pt0 * KNN + t];
    __syncthreads();

    #pragma unroll
    for (int pi = 0; pi < 2; ++pi) {
        int p = 2 * w + pi;
        const float* uP = up + (size_t)(pt0 + p) * NC;
        float u0 = uP[l], u1 = uP[l + 64], u2 = uP[l + 128];
        for (int e = 0; e < KNN; ++e) {
            int q = qsh[p * KNN + e];
            const float* vq = vv + ((size_t)b * NP + q) * NC;
            int row = p * 16 + e;
            hs[row][l]       = f2bf(lrelu(u0 + vq[l]));
            hs[row][l + 64]  = f2bf(lrelu(u1 + vq[l + 64]));
            hs[row][l + 128] = f2bf(lrelu(u2 + vq[l + 128]));
        }
        #pragma unroll
        for (int e = KNN; e < 16; ++e) {
            int row = p * 16 + e;
            hs[row][l] = 0; hs[row][l + 64] = 0; hs[row][l + 128] = 0;
        }
    }
    __syncthreads();

    int n0 = w * 48;
    f32x4 acc[PT][3];
    #pragma unroll
    for (int mt = 0; mt < PT; ++mt)
        #pragma unroll
        for (int nt = 0; nt < 3; ++nt)
            acc[mt][nt] = (f32x4){0.f, 0.f, 0.f, 0.f};
    for (int kb = 0; kb < NC; kb += 32) {
        bf16x8 bf[3];
        #pragma unroll
        for (int nt = 0; nt < 3; ++nt)
            bf[nt] = *reinterpret_cast<const bf16x8*>(&w2t[(size_t)(n0 + nt * 16 + lr) * NC + kb + 8 * lg]);
        #pragma unroll
        for (int mt = 0; mt < PT; ++mt) {
            bf16x8 af = *reinterpret_cast<const bf16x8*>(&hs[mt * 16 + lr][kb + 8 * lg]);
            #pragma unroll
            for (int nt = 0; nt < 3; ++nt)
                acc[mt][nt] = __builtin_amdgcn_mfma_f32_16x16x32_bf16(af, bf[nt], acc[mt][nt], 0, 0, 0);
        }
    }
    __syncthreads();

    float* aggf = (float*)&hs[0][0];
    float bb[3];
    #pragma unroll
    for (int nt = 0; nt < 3; ++nt) bb[nt] = b2[n0 + nt * 16 + lr];
    #pragma unroll
    for (int mt = 0; mt < PT; ++mt) {
        #pragma unroll
        for (int nt = 0; nt < 3; ++nt) {
            float s = 0.f;
            if (lg < 3) {
                #pragma unroll
                for (int j = 0; j < 4; ++j) s += lrelu(acc[mt][nt][j] + bb[nt]);
            }
            s += __shfl_xor(s, 16, 64);
            s += __shfl_xor(s, 32, 64);
            if (lg == 0) aggf[mt * NC + n0 + nt * 16 + lr] = s * (1.0f / KNN);
        }
    }
    __syncthreads();

    #pragma unroll
    for (int pi = 0; pi < 2; ++pi) {
        int p = w + 4 * pi;
        float a0 = aggf[p * NC + l], a1 = aggf[p * NC + l + 64], a2 = aggf[p * NC + l + 128];
        float s = a0 + a1 + a2;
        #pragma unroll
        for (int off = 32; off; off >>= 1) s += __shfl_xor(s, off, 64);
        float mu = s / (float)NC;
        float d0 = a0 - mu, d1 = a1 - mu, d2 = a2 - mu;
        float vs = d0 * d0 + d1 * d1 + d2 * d2;
        #pragma unroll
        for (int off = 32; off; off >>= 1) vs += __shfl_xor(vs, off, 64);
        float rstd = 1.0f / sqrtf(vs / (float)NC + 1e-5f);
        float* o = out + (size_t)(pt0 + p) * NC;
        o[l]       = d0 * rstd * gamma[l]       + beta[l];
        o[l + 64]  = d1 * rstd * gamma[l + 64]  + beta[l + 64];
        o[l + 128] = d2 * rstd * gamma[l + 128] + beta[l + 128];
    }
}

extern "C" void kernel_launch(void* const* d_in, const int* in_sizes, int n_in,
                              void* d_out, int out_size, void* d_ws, size_t ws_size,
                              hipStream_t stream) {
    const float* nodes = (const float*)d_in[0];
    const float* W1    = (const float*)d_in[1];
    const float* b1    = (const float*)d_in[2];
    const float* W2    = (const float*)d_in[3];
    const float* b2    = (const float*)d_in[4];
    const float* gamma = (const float*)d_in[5];
    const float* beta  = (const float*)d_in[6];
    float* out = (float*)d_out;

    const size_t BPC = (size_t)NB * NP * NC;
    float*  xn  = (float*)d_ws;                        // B*P*C f32
    float*  up  = xn + BPC;                            // B*P*C f32
    float*  vv  = up + BPC;                            // B*P*C f32
    ushort* xh  = (ushort*)(vv + BPC);                 // B*P*C bf16
    int*    knn = (int*)(xh + BPC);                    // B*P*K
    ushort* w2t = (ushort*)(knn + (size_t)NB * NP * KNN); // C*C bf16
    float*  sim = (float*)((char*)(w2t + (size_t)NC * NC) + 8);
    sim = (float*)(((uintptr_t)sim + 15) & ~(uintptr_t)15);

    size_t fixed_bytes = (size_t)((char*)sim - (char*)d_ws);
    bool full = ws_size >= fixed_bytes + (size_t)NB * NP * NP * 4;

    k_normalize<<<NB * NP / 4, 256, 0, stream>>>(nodes, xn, xh);
    k_uv<<<NB * NP / PTS, 192, 0, stream>>>(nodes, W1, b1, up, vv);
    k_w2t<<<(NC * NC + 255) / 256, 256, 0, stream>>>(W2, w2t);
    if (full) {
        k_sim3<<<dim3(NP / 128, NP / 128, NB), 256, 0, stream>>>(xh, sim,
                                                                 (size_t)NP * NC, (size_t)NP * NP);
        k_topk4<<<NB * NP / 4, 256, 0, stream>>>(sim, xn, knn,
                                                 (size_t)NP * NP, (size_t)NP * NC);
    } else {
        for (int b = 0; b < NB; ++b) {
            k_sim3<<<dim3(NP / 128, NP / 128, 1), 256, 0, stream>>>(xh + (size_t)b * NP * NC, sim, 0, 0);
            k_topk4<<<NP / 4, 256, 0, stream>>>(sim, xn + (size_t)b * NP * NC,
                                                knn + (size_t)b * NP * KNN, 0, 0);
        }
    }
    k_edge2<<<NB * NP / PT, 256, 0, stream>>>(up, vv, knn, w2t, b2, gamma, beta, out);
}

// Round 6
// 137.494 us; speedup vs baseline: 2.3130x; 1.2112x over previous
//
#include <hip/hip_runtime.h>
#include <hip/hip_bf16.h>
#include <math.h>

#define NB 4
#define NP 2048
#define NC 192
#define KNN 12
#define KSEL 16
#define NEG_SLOPE 0.2f

typedef __attribute__((ext_vector_type(8))) short bf16x8;
typedef __attribute__((ext_vector_type(4))) float f32x4;

__device__ __forceinline__ float lrelu(float x) { return x >= 0.0f ? x : NEG_SLOPE * x; }

__device__ __forceinline__ ushort f2bf(float x) {
    unsigned u = __float_as_uint(x);
    unsigned r = (u + 0x7FFFu + ((u >> 16) & 1u)) >> 16;   // RNE
    return (ushort)r;
}

// ------- kernel 1: L2-normalize rows; write f32 xn (rescore) + bf16 xh (MFMA) -
__global__ void __launch_bounds__(256) k_normalize(const float* __restrict__ nodes,
                                                   float* __restrict__ xn,
                                                   ushort* __restrict__ xh) {
    int wave = threadIdx.x >> 6;
    int lane = threadIdx.x & 63;
    size_t pt = (size_t)blockIdx.x * 4 + wave;
    const float* x = nodes + pt * NC;
    float v0 = x[lane], v1 = x[lane + 64], v2 = x[lane + 128];
    float s = v0 * v0 + v1 * v1 + v2 * v2;
    #pragma unroll
    for (int off = 32; off; off >>= 1) s += __shfl_xor(s, off, 64);
    float inv = 1.0f / fmaxf(sqrtf(s), 1e-12f);
    float f0 = v0 * inv, f1 = v1 * inv, f2 = v2 * inv;
    float* o = xn + pt * NC;
    o[lane] = f0; o[lane + 64] = f1; o[lane + 128] = f2;
    ushort* oh = xh + pt * NC;
    oh[lane] = f2bf(f0); oh[lane + 64] = f2bf(f1); oh[lane + 128] = f2bf(f2);
}

// ------- kernel 2: sim = Xh * Xh^T via bf16 MFMA (approximate, f32 out) -------
__global__ void __launch_bounds__(256) k_sim3(const ushort* __restrict__ xh,
                                              float* __restrict__ sim,
                                              size_t xstride, size_t simstride) {
    __shared__ ushort Ah[128][72];
    __shared__ ushort Bh[128][72];
    const ushort* XbH = xh + (size_t)blockIdx.z * xstride;
    float* sb = sim + (size_t)blockIdx.z * simstride;
    int t = threadIdx.x;
    int w = t >> 6, l = t & 63;
    int wm = w >> 1, wn = w & 1;
    int lg = l >> 4, lr = l & 15;
    int m0 = blockIdx.y * 128, n0 = blockIdx.x * 128;

    f32x4 acc[4][4];
    #pragma unroll
    for (int mi = 0; mi < 4; ++mi)
        #pragma unroll
        for (int ni = 0; ni < 4; ++ni)
            acc[mi][ni] = (f32x4){0.f, 0.f, 0.f, 0.f};

    int r = t >> 3, c = (t & 7) * 8;
    for (int ks = 0; ks < 3; ++ks) {
        int kb = ks * 64;
        #pragma unroll
        for (int i = 0; i < 4; ++i) {
            int row = r + 32 * i;
            *reinterpret_cast<bf16x8*>(&Ah[row][c]) =
                *reinterpret_cast<const bf16x8*>(&XbH[(size_t)(m0 + row) * NC + kb + c]);
            *reinterpret_cast<bf16x8*>(&Bh[row][c]) =
                *reinterpret_cast<const bf16x8*>(&XbH[(size_t)(n0 + row) * NC + kb + c]);
        }
        __syncthreads();
        #pragma unroll
        for (int ksub = 0; ksub < 2; ++ksub) {
            int ko = ksub * 32 + 8 * lg;
            bf16x8 af[4], bf[4];
            #pragma unroll
            for (int f = 0; f < 4; ++f) {
                af[f] = *reinterpret_cast<const bf16x8*>(&Ah[wm * 64 + f * 16 + lr][ko]);
                bf[f] = *reinterpret_cast<const bf16x8*>(&Bh[wn * 64 + f * 16 + lr][ko]);
            }
            #pragma unroll
            for (int mi = 0; mi < 4; ++mi)
                #pragma unroll
                for (int ni = 0; ni < 4; ++ni)
                    acc[mi][ni] = __builtin_amdgcn_mfma_f32_16x16x32_bf16(af[mi], bf[ni], acc[mi][ni], 0, 0, 0);
        }
        __syncthreads();
    }
    #pragma unroll
    for (int mi = 0; mi < 4; ++mi)
        #pragma unroll
        for (int j = 0; j < 4; ++j) {
            int row = m0 + wm * 64 + mi * 16 + lg * 4 + j;
            #pragma unroll
            for (int ni = 0; ni < 4; ++ni)
                sb[(size_t)row * NP + n0 + wn * 64 + ni * 16 + lr] = acc[mi][ni][j];
        }
}

// ------- kernel 3: threshold+compact+bitonic top-16, exact rescore -> 12-set --
__global__ void __launch_bounds__(256) k_topk4(const float* __restrict__ sim,
                                               const float* __restrict__ xn,
                                               int* __restrict__ knn,
                                               size_t simstride, size_t xstride) {
    __shared__ float cvs[4][64];
    __shared__ int   cis[4][64];
    int wv = threadIdx.x >> 6, lane = threadIdx.x & 63;
    int row = blockIdx.x * 4 + wv;
    int batch = row / NP, p = row % NP;
    const float* sr = sim + (size_t)batch * simstride + (size_t)p * NP;

    float4 v4[8];
    #pragma unroll
    for (int i = 0; i < 8; ++i)
        v4[i] = *reinterpret_cast<const float4*>(sr + lane * 4 + i * 256);

    #pragma unroll
    for (int i = 0; i < 8; ++i) {
        int base = lane * 4 + i * 256;
        v4[i].x = (base + 0 == p) ? -INFINITY : v4[i].x;
        v4[i].y = (base + 1 == p) ? -INFINITY : v4[i].y;
        v4[i].z = (base + 2 == p) ? -INFINITY : v4[i].z;
        v4[i].w = (base + 3 == p) ? -INFINITY : v4[i].w;
    }

    float lmax = -INFINITY;
    #pragma unroll
    for (int i = 0; i < 8; ++i) {
        lmax = fmaxf(lmax, fmaxf(fmaxf(v4[i].x, v4[i].y), fmaxf(v4[i].z, v4[i].w)));
    }

    float sm = lmax;
    #pragma unroll
    for (int k = 2; k <= 64; k <<= 1) {
        #pragma unroll
        for (int j = k >> 1; j >= 1; j >>= 1) {
            float ov = __shfl_xor(sm, j, 64);
            bool lower = (lane & j) == 0;
            bool up = (lane & k) != 0;
            float lo = fminf(sm, ov), hi = fmaxf(sm, ov);
            sm = (up == lower) ? lo : hi;
        }
    }
    float theta = __shfl(sm, 16, 64);

    int cnt = 0;
    #pragma unroll
    for (int i = 0; i < 8; ++i) {
        cnt += (v4[i].x > theta) + (v4[i].y > theta) + (v4[i].z > theta) + (v4[i].w > theta);
    }
    int x = cnt;
    #pragma unroll
    for (int off = 1; off < 64; off <<= 1) {
        int y = __shfl_up(x, off, 64);
        if (lane >= off) x += y;
    }
    int excl = x - cnt;
    int total = __shfl(x, 63, 64);

    int my_q = 0;
    bool fb = (total < KSEL) || (total > 64);
    if (!fb) {
        cvs[wv][lane] = -INFINITY;
        cis[wv][lane] = 0;
        asm volatile("s_waitcnt lgkmcnt(0)" ::: "memory");
        int pos = excl;
        #pragma unroll
        for (int i = 0; i < 8; ++i) {
            int base = lane * 4 + i * 256;
            float vs[4] = {v4[i].x, v4[i].y, v4[i].z, v4[i].w};
            #pragma unroll
            for (int j = 0; j < 4; ++j) {
                if (vs[j] > theta) {
                    cvs[wv][pos] = vs[j];
                    cis[wv][pos] = base + j;
                    ++pos;
                }
            }
        }
        asm volatile("s_waitcnt lgkmcnt(0)" ::: "memory");
        float v = cvs[wv][lane];
        int   idx = cis[wv][lane];
        #pragma unroll
        for (int k = 2; k <= 64; k <<= 1) {
            #pragma unroll
            for (int j = k >> 1; j >= 1; j >>= 1) {
                float ov = __shfl_xor(v, j, 64);
                int   oi = __shfl_xor(idx, j, 64);
                bool lower = (lane & j) == 0;
                bool up = (lane & k) != 0;
                bool ogt = (ov > v);
                float hv = ogt ? ov : v;  int hid = ogt ? oi : idx;
                float lv = ogt ? v : ov;  int lid = ogt ? idx : oi;
                bool keep_lo = (up == lower);
                v   = keep_lo ? lv : hv;
                idx = keep_lo ? lid : hid;
            }
        }
        my_q = __shfl(idx, lane >> 2, 64);
    } else {
        float tv[KSEL]; int ti[KSEL];
        #pragma unroll
        for (int q = 0; q < KSEL; ++q) { tv[q] = -INFINITY; ti[q] = 0x7FFFFFFF; }
        #pragma unroll
        for (int i = 0; i < 8; ++i) {
            int base = lane * 4 + i * 256;
            float vs[4] = {v4[i].x, v4[i].y, v4[i].z, v4[i].w};
            #pragma unroll
            for (int j = 0; j < 4; ++j) {
                float v = vs[j];
                int idx = base + j;
                if (v > tv[0]) {
                    bool cg[KSEL];
                    #pragma unroll
                    for (int q = 0; q < KSEL; ++q) cg[q] = v > tv[q];
                    #pragma unroll
                    for (int q = 0; q < KSEL - 1; ++q) {
                        tv[q] = cg[q + 1] ? tv[q + 1] : (cg[q] ? v : tv[q]);
                        ti[q] = cg[q + 1] ? ti[q + 1] : (cg[q] ? idx : ti[q]);
                    }
                    tv[KSEL - 1] = cg[KSEL - 1] ? v : tv[KSEL - 1];
                    ti[KSEL - 1] = cg[KSEL - 1] ? idx : ti[KSEL - 1];
                }
            }
        }
        #pragma unroll
        for (int rr = 0; rr < KSEL; ++rr) {
            float bv = tv[KSEL - 1]; int bi = ti[KSEL - 1];
            #pragma unroll
            for (int off = 1; off < 64; off <<= 1) {
                float ov = __shfl_xor(bv, off, 64);
                int   oi = __shfl_xor(bi, off, 64);
                if (ov > bv || (ov == bv && oi < bi)) { bv = ov; bi = oi; }
            }
            if ((lane >> 2) == rr) my_q = bi;
            if (bv == tv[KSEL - 1] && bi == ti[KSEL - 1]) {
                #pragma unroll
                for (int s = KSEL - 1; s > 0; --s) { tv[s] = tv[s - 1]; ti[s] = ti[s - 1]; }
                tv[0] = -INFINITY; ti[0] = 0x7FFFFFFF;
            }
        }
    }

    const float* xb = xn + (size_t)batch * xstride;
    const float* cp = xb + (size_t)p * NC + (lane & 3) * 48;
    const float* cq = xb + (size_t)my_q * NC + (lane & 3) * 48;
    float dot = 0.f;
    #pragma unroll
    for (int i = 0; i < 12; ++i) {
        float4 a = *reinterpret_cast<const float4*>(cp + i * 4);
        float4 bq = *reinterpret_cast<const float4*>(cq + i * 4);
        dot += a.x * bq.x + a.y * bq.y + a.z * bq.z + a.w * bq.w;
    }
    dot += __shfl_xor(dot, 1, 64);
    dot += __shfl_xor(dot, 2, 64);
    int g = lane >> 2;
    int rank = 0;
    #pragma unroll
    for (int j = 0; j < KSEL; ++j) {
        float vj = __shfl(dot, j * 4, 64);
        int   qj = __shfl(my_q, j * 4, 64);
        if (j != g && (vj > dot || (vj == dot && qj < my_q))) ++rank;
    }
    bool keep = ((lane & 3) == 0) && (rank < KNN);
    unsigned long long mask = __ballot(keep);
    int pos = __popcll(mask & ((1ull << lane) - 1));
    if (keep) knn[(size_t)row * KNN + pos] = my_q;
}

// ---------------- kernel 4: U' = X@W1a - X@W1b + b1, V = X@W1b ----------------
#define PTS 16
__global__ void __launch_bounds__(192) k_uv(const float* __restrict__ nodes,
                                            const float* __restrict__ W1,
                                            const float* __restrict__ b1,
                                            float* __restrict__ up, float* __restrict__ vv) {
    __shared__ float xs[PTS][NC];
    int t = threadIdx.x;
    int p0 = blockIdx.x * PTS;
    for (int i = t; i < PTS * NC; i += 192) {
        int pt = i / NC, cc = i % NC;
        xs[pt][cc] = nodes[(size_t)(p0 + pt) * NC + cc];
    }
    __syncthreads();
    float accU[PTS] = {}, accV[PTS] = {};
    for (int c4 = 0; c4 < NC; c4 += 4) {
        float wa[4], wb[4];
        #pragma unroll
        for (int i = 0; i < 4; ++i) {
            wa[i] = W1[(size_t)(c4 + i) * NC + t];
            wb[i] = W1[(size_t)(c4 + i + NC) * NC + t];
        }
        #pragma unroll
        for (int pt = 0; pt < PTS; ++pt) {
            float4 xv = *reinterpret_cast<const float4*>(&xs[pt][c4]);
            accU[pt] += xv.x * wa[0] + xv.y * wa[1] + xv.z * wa[2] + xv.w * wa[3];
            accV[pt] += xv.x * wb[0] + xv.y * wb[1] + xv.z * wb[2] + xv.w * wb[3];
        }
    }
    float bb = b1[t];
    #pragma unroll
    for (int pt = 0; pt < PTS; ++pt) {
        up[(size_t)(p0 + pt) * NC + t] = accU[pt] - accV[pt] + bb;
        vv[(size_t)(p0 + pt) * NC + t] = accV[pt];
    }
}

// ---------------- prep: W2T bf16 [n][k] from W2 f32 [k][n] --------------------
__global__ void __launch_bounds__(256) k_w2t(const float* __restrict__ W2,
                                             ushort* __restrict__ w2t) {
    int idx = blockIdx.x * 256 + threadIdx.x;
    if (idx >= NC * NC) return;
    int n = idx / NC, k = idx % NC;
    w2t[(size_t)n * NC + k] = f2bf(W2[(size_t)k * NC + n]);
}

// ---- kernel 5: barrier-free edge MLP: per-lane A-gather from global, W2 in LDS
// Block = 512 thr (8 waves), 16 points. Wave owns 2 whole points (acc[2][12]).
// A-frag gathered straight from up/vv (L2) -> lrelu -> cvt_pk bf16. One barrier
// total (W2 stage); epilogue uses wave-private LDS + lgkmcnt only.
__device__ __forceinline__ bf16x8 make_h(const float* __restrict__ u,
                                         const float* __restrict__ v) {
    float4 ua = *reinterpret_cast<const float4*>(u);
    float4 ub = *reinterpret_cast<const float4*>(u + 4);
    float4 va = *reinterpret_cast<const float4*>(v);
    float4 vb = *reinterpret_cast<const float4*>(v + 4);
    union { bf16x8 v8; __hip_bfloat162 h2[4]; } r;
    r.h2[0] = __float22bfloat162_rn(make_float2(lrelu(ua.x + va.x), lrelu(ua.y + va.y)));
    r.h2[1] = __float22bfloat162_rn(make_float2(lrelu(ua.z + va.z), lrelu(ua.w + va.w)));
    r.h2[2] = __float22bfloat162_rn(make_float2(lrelu(ub.x + vb.x), lrelu(ub.y + vb.y)));
    r.h2[3] = __float22bfloat162_rn(make_float2(lrelu(ub.z + vb.z), lrelu(ub.w + vb.w)));
    return r.v8;
}

#define EW 8    // waves/block
#define EPW 2   // points/wave
__global__ void __launch_bounds__(512, 2) k_edge3(const float* __restrict__ up,
                                                  const float* __restrict__ vv,
                                                  const int* __restrict__ knn,
                                                  const ushort* __restrict__ w2t,
                                                  const float* __restrict__ b2,
                                                  const float* __restrict__ gamma,
                                                  const float* __restrict__ beta,
                                                  float* __restrict__ out) {
    __shared__ ushort w2s[NC][200];          // 76800 B; stride 400B -> 8-phase-min b128
    __shared__ float aggs[EW][EPW][NC];      // 12288 B, wave-private slices
    int t = threadIdx.x;
    int wv = t >> 6, l = t & 63;
    int lg = l >> 4, lr = l & 15;

    for (int i = t; i < NC * 24; i += 512) {
        int r_ = i / 24, c_ = i % 24;
        *reinterpret_cast<bf16x8*>(&w2s[r_][c_ * 8]) =
            *reinterpret_cast<const bf16x8*>(&w2t[(size_t)r_ * NC + c_ * 8]);
    }
    __syncthreads();   // only block-wide barrier

    int pt0 = blockIdx.x * (EW * EPW) + wv * EPW;
    int b = pt0 / NP;
    const float* vb = vv + (size_t)b * NP * NC;
    int lre = lr < KNN ? lr : KNN - 1;       // dummy rows 12-15 reuse edge 11 (masked later)
    int q0 = knn[(size_t)(pt0 + 0) * KNN + lre];
    int q1 = knn[(size_t)(pt0 + 1) * KNN + lre];
    const float* u0p = up + (size_t)(pt0 + 0) * NC + 8 * lg;
    const float* u1p = up + (size_t)(pt0 + 1) * NC + 8 * lg;
    const float* v0p = vb + (size_t)q0 * NC + 8 * lg;
    const float* v1p = vb + (size_t)q1 * NC + 8 * lg;

    f32x4 acc[EPW][12];
    #pragma unroll
    for (int pt = 0; pt < EPW; ++pt)
        #pragma unroll
        for (int nt = 0; nt < 12; ++nt)
            acc[pt][nt] = (f32x4){0.f, 0.f, 0.f, 0.f};

    #pragma unroll
    for (int ks = 0; ks < 6; ++ks) {
        bf16x8 a0 = make_h(u0p + ks * 32, v0p + ks * 32);
        bf16x8 a1 = make_h(u1p + ks * 32, v1p + ks * 32);
        #pragma unroll
        for (int nt = 0; nt < 12; ++nt) {
            bf16x8 bfr = *reinterpret_cast<const bf16x8*>(&w2s[nt * 16 + lr][ks * 32 + lg * 8]);
            acc[0][nt] = __builtin_amdgcn_mfma_f32_16x16x32_bf16(a0, bfr, acc[0][nt], 0, 0, 0);
            acc[1][nt] = __builtin_amdgcn_mfma_f32_16x16x32_bf16(a1, bfr, acc[1][nt], 0, 0, 0);
        }
    }

    // epilogue: lrelu(+b2), mean over 12 real edge-rows (rows = lg*4+j; lg==3 dummy)
    #pragma unroll
    for (int pt = 0; pt < EPW; ++pt) {
        #pragma unroll
        for (int nt = 0; nt < 12; ++nt) {
            float bb = b2[nt * 16 + lr];
            float s = 0.f;
            if (lg < 3) {
                #pragma unroll
                for (int j = 0; j < 4; ++j) s += lrelu(acc[pt][nt][j] + bb);
            }
            s += __shfl_xor(s, 16, 64);
            s += __shfl_xor(s, 32, 64);
            if (lg == 0) aggs[wv][pt][nt * 16 + lr] = s * (1.0f / KNN);
        }
    }
    asm volatile("s_waitcnt lgkmcnt(0)" ::: "memory");   // same-wave LDS RAW

    #pragma unroll
    for (int pt = 0; pt < EPW; ++pt) {
        float a0 = aggs[wv][pt][l], a1 = aggs[wv][pt][l + 64], a2 = aggs[wv][pt][l + 128];
        float s = a0 + a1 + a2;
        #pragma unroll
        for (int off = 32; off; off >>= 1) s += __shfl_xor(s, off, 64);
        float mu = s / (float)NC;
        float d0 = a0 - mu, d1 = a1 - mu, d2 = a2 - mu;
        float vs = d0 * d0 + d1 * d1 + d2 * d2;
        #pragma unroll
        for (int off = 32; off; off >>= 1) vs += __shfl_xor(vs, off, 64);
        float rstd = 1.0f / sqrtf(vs / (float)NC + 1e-5f);
        float* o = out + (size_t)(pt0 + pt) * NC;
        o[l]       = d0 * rstd * gamma[l]       + beta[l];
        o[l + 64]  = d1 * rstd * gamma[l + 64]  + beta[l + 64];
        o[l + 128] = d2 * rstd * gamma[l + 128] + beta[l + 128];
    }
}

extern "C" void kernel_launch(void* const* d_in, const int* in_sizes, int n_in,
                              void* d_out, int out_size, void* d_ws, size_t ws_size,
                              hipStream_t stream) {
    const float* nodes = (const float*)d_in[0];
    const float* W1    = (const float*)d_in[1];
    const float* b1    = (const float*)d_in[2];
    const float* W2    = (const float*)d_in[3];
    const float* b2    = (const float*)d_in[4];
    const float* gamma = (const float*)d_in[5];
    const float* beta  = (const float*)d_in[6];
    float* out = (float*)d_out;

    const size_t BPC = (size_t)NB * NP * NC;
    float*  xn  = (float*)d_ws;                        // B*P*C f32
    float*  up  = xn + BPC;                            // B*P*C f32
    float*  vv  = up + BPC;                            // B*P*C f32
    ushort* xh  = (ushort*)(vv + BPC);                 // B*P*C bf16
    int*    knn = (int*)(xh + BPC);                    // B*P*K
    ushort* w2t = (ushort*)(knn + (size_t)NB * NP * KNN); // C*C bf16
    float*  sim = (float*)((char*)(w2t + (size_t)NC * NC) + 8);
    sim = (float*)(((uintptr_t)sim + 15) & ~(uintptr_t)15);

    size_t fixed_bytes = (size_t)((char*)sim - (char*)d_ws);
    bool full = ws_size >= fixed_bytes + (size_t)NB * NP * NP * 4;

    k_normalize<<<NB * NP / 4, 256, 0, stream>>>(nodes, xn, xh);
    k_uv<<<NB * NP / PTS, 192, 0, stream>>>(nodes, W1, b1, up, vv);
    k_w2t<<<(NC * NC + 255) / 256, 256, 0, stream>>>(W2, w2t);
    if (full) {
        k_sim3<<<dim3(NP / 128, NP / 128, NB), 256, 0, stream>>>(xh, sim,
                                                                 (size_t)NP * NC, (size_t)NP * NP);
        k_topk4<<<NB * NP / 4, 256, 0, stream>>>(sim, xn, knn,
                                                 (size_t)NP * NP, (size_t)NP * NC);
    } else {
        for (int b = 0; b < NB; ++b) {
            k_sim3<<<dim3(NP / 128, NP / 128, 1), 256, 0, stream>>>(xh + (size_t)b * NP * NC, sim, 0, 0);
            k_topk4<<<NP / 4, 256, 0, stream>>>(sim, xn + (size_t)b * NP * NC,
                                                knn + (size_t)b * NP * KNN, 0, 0);
        }
    }
    k_edge3<<<NB * NP / (EW * EPW), 512, 0, stream>>>(up, vv, knn, w2t, b2, gamma, beta, out);
}

// Round 7
// 134.792 us; speedup vs baseline: 2.3593x; 1.0201x over previous
//
#include <hip/hip_runtime.h>
#include <hip/hip_bf16.h>
#include <math.h>

#define NB 4
#define NP 2048
#define NC 192
#define KNN 12
#define KSEL 16
#define NEG_SLOPE 0.2f

typedef __attribute__((ext_vector_type(8))) short bf16x8;
typedef __attribute__((ext_vector_type(4))) float f32x4;

__device__ __forceinline__ float lrelu(float x) { return x >= 0.0f ? x : NEG_SLOPE * x; }

__device__ __forceinline__ ushort f2bf(float x) {
    unsigned u = __float_as_uint(x);
    unsigned r = (u + 0x7FFFu + ((u >> 16) & 1u)) >> 16;   // RNE
    return (ushort)r;
}

// -- kernel 1: L2-normalize; out: xn f32 (rescore), xh bf16 (sim), xb bf16 (UV)
__global__ void __launch_bounds__(256) k_normalize(const float* __restrict__ nodes,
                                                   float* __restrict__ xn,
                                                   ushort* __restrict__ xh,
                                                   ushort* __restrict__ xb) {
    int wave = threadIdx.x >> 6;
    int lane = threadIdx.x & 63;
    size_t pt = (size_t)blockIdx.x * 4 + wave;
    const float* x = nodes + pt * NC;
    float v0 = x[lane], v1 = x[lane + 64], v2 = x[lane + 128];
    float s = v0 * v0 + v1 * v1 + v2 * v2;
    #pragma unroll
    for (int off = 32; off; off >>= 1) s += __shfl_xor(s, off, 64);
    float inv = 1.0f / fmaxf(sqrtf(s), 1e-12f);
    float f0 = v0 * inv, f1 = v1 * inv, f2 = v2 * inv;
    float* o = xn + pt * NC;
    o[lane] = f0; o[lane + 64] = f1; o[lane + 128] = f2;
    ushort* oh = xh + pt * NC;
    oh[lane] = f2bf(f0); oh[lane + 64] = f2bf(f1); oh[lane + 128] = f2bf(f2);
    ushort* ob = xb + pt * NC;
    ob[lane] = f2bf(v0); ob[lane + 64] = f2bf(v1); ob[lane + 128] = f2bf(v2);
}

// ------- kernel 2: sim = Xh * Xh^T via bf16 MFMA (approximate, f32 out) -------
__global__ void __launch_bounds__(256) k_sim3(const ushort* __restrict__ xh,
                                              float* __restrict__ sim,
                                              size_t xstride, size_t simstride) {
    __shared__ ushort Ah[128][72];
    __shared__ ushort Bh[128][72];
    const ushort* XbH = xh + (size_t)blockIdx.z * xstride;
    float* sb = sim + (size_t)blockIdx.z * simstride;
    int t = threadIdx.x;
    int w = t >> 6, l = t & 63;
    int wm = w >> 1, wn = w & 1;
    int lg = l >> 4, lr = l & 15;
    int m0 = blockIdx.y * 128, n0 = blockIdx.x * 128;

    f32x4 acc[4][4];
    #pragma unroll
    for (int mi = 0; mi < 4; ++mi)
        #pragma unroll
        for (int ni = 0; ni < 4; ++ni)
            acc[mi][ni] = (f32x4){0.f, 0.f, 0.f, 0.f};

    int r = t >> 3, c = (t & 7) * 8;
    for (int ks = 0; ks < 3; ++ks) {
        int kb = ks * 64;
        #pragma unroll
        for (int i = 0; i < 4; ++i) {
            int row = r + 32 * i;
            *reinterpret_cast<bf16x8*>(&Ah[row][c]) =
                *reinterpret_cast<const bf16x8*>(&XbH[(size_t)(m0 + row) * NC + kb + c]);
            *reinterpret_cast<bf16x8*>(&Bh[row][c]) =
                *reinterpret_cast<const bf16x8*>(&XbH[(size_t)(n0 + row) * NC + kb + c]);
        }
        __syncthreads();
        #pragma unroll
        for (int ksub = 0; ksub < 2; ++ksub) {
            int ko = ksub * 32 + 8 * lg;
            bf16x8 af[4], bf[4];
            #pragma unroll
            for (int f = 0; f < 4; ++f) {
                af[f] = *reinterpret_cast<const bf16x8*>(&Ah[wm * 64 + f * 16 + lr][ko]);
                bf[f] = *reinterpret_cast<const bf16x8*>(&Bh[wn * 64 + f * 16 + lr][ko]);
            }
            #pragma unroll
            for (int mi = 0; mi < 4; ++mi)
                #pragma unroll
                for (int ni = 0; ni < 4; ++ni)
                    acc[mi][ni] = __builtin_amdgcn_mfma_f32_16x16x32_bf16(af[mi], bf[ni], acc[mi][ni], 0, 0, 0);
        }
        __syncthreads();
    }
    #pragma unroll
    for (int mi = 0; mi < 4; ++mi)
        #pragma unroll
        for (int j = 0; j < 4; ++j) {
            int row = m0 + wm * 64 + mi * 16 + lg * 4 + j;
            #pragma unroll
            for (int ni = 0; ni < 4; ++ni)
                sb[(size_t)row * NP + n0 + wn * 64 + ni * 16 + lr] = acc[mi][ni][j];
        }
}

// ------- kernel 3: threshold+compact+bitonic top-16, exact rescore -> 12-set --
__global__ void __launch_bounds__(256) k_topk4(const float* __restrict__ sim,
                                               const float* __restrict__ xn,
                                               int* __restrict__ knn,
                                               size_t simstride, size_t xstride) {
    __shared__ float cvs[4][64];
    __shared__ int   cis[4][64];
    int wv = threadIdx.x >> 6, lane = threadIdx.x & 63;
    int row = blockIdx.x * 4 + wv;
    int batch = row / NP, p = row % NP;
    const float* sr = sim + (size_t)batch * simstride + (size_t)p * NP;

    float4 v4[8];
    #pragma unroll
    for (int i = 0; i < 8; ++i)
        v4[i] = *reinterpret_cast<const float4*>(sr + lane * 4 + i * 256);

    #pragma unroll
    for (int i = 0; i < 8; ++i) {
        int base = lane * 4 + i * 256;
        v4[i].x = (base + 0 == p) ? -INFINITY : v4[i].x;
        v4[i].y = (base + 1 == p) ? -INFINITY : v4[i].y;
        v4[i].z = (base + 2 == p) ? -INFINITY : v4[i].z;
        v4[i].w = (base + 3 == p) ? -INFINITY : v4[i].w;
    }

    float lmax = -INFINITY;
    #pragma unroll
    for (int i = 0; i < 8; ++i) {
        lmax = fmaxf(lmax, fmaxf(fmaxf(v4[i].x, v4[i].y), fmaxf(v4[i].z, v4[i].w)));
    }

    float sm = lmax;
    #pragma unroll
    for (int k = 2; k <= 64; k <<= 1) {
        #pragma unroll
        for (int j = k >> 1; j >= 1; j >>= 1) {
            float ov = __shfl_xor(sm, j, 64);
            bool lower = (lane & j) == 0;
            bool up = (lane & k) != 0;
            float lo = fminf(sm, ov), hi = fmaxf(sm, ov);
            sm = (up == lower) ? lo : hi;
        }
    }
    float theta = __shfl(sm, 16, 64);

    int cnt = 0;
    #pragma unroll
    for (int i = 0; i < 8; ++i) {
        cnt += (v4[i].x > theta) + (v4[i].y > theta) + (v4[i].z > theta) + (v4[i].w > theta);
    }
    int x = cnt;
    #pragma unroll
    for (int off = 1; off < 64; off <<= 1) {
        int y = __shfl_up(x, off, 64);
        if (lane >= off) x += y;
    }
    int excl = x - cnt;
    int total = __shfl(x, 63, 64);

    int my_q = 0;
    bool fb = (total < KSEL) || (total > 64);
    if (!fb) {
        cvs[wv][lane] = -INFINITY;
        cis[wv][lane] = 0;
        asm volatile("s_waitcnt lgkmcnt(0)" ::: "memory");
        int pos = excl;
        #pragma unroll
        for (int i = 0; i < 8; ++i) {
            int base = lane * 4 + i * 256;
            float vs[4] = {v4[i].x, v4[i].y, v4[i].z, v4[i].w};
            #pragma unroll
            for (int j = 0; j < 4; ++j) {
                if (vs[j] > theta) {
                    cvs[wv][pos] = vs[j];
                    cis[wv][pos] = base + j;
                    ++pos;
                }
            }
        }
        asm volatile("s_waitcnt lgkmcnt(0)" ::: "memory");
        float v = cvs[wv][lane];
        int   idx = cis[wv][lane];
        #pragma unroll
        for (int k = 2; k <= 64; k <<= 1) {
            #pragma unroll
            for (int j = k >> 1; j >= 1; j >>= 1) {
                float ov = __shfl_xor(v, j, 64);
                int   oi = __shfl_xor(idx, j, 64);
                bool lower = (lane & j) == 0;
                bool up = (lane & k) != 0;
                bool ogt = (ov > v);
                float hv = ogt ? ov : v;  int hid = ogt ? oi : idx;
                float lv = ogt ? v : ov;  int lid = ogt ? idx : oi;
                bool keep_lo = (up == lower);
                v   = keep_lo ? lv : hv;
                idx = keep_lo ? lid : hid;
            }
        }
        my_q = __shfl(idx, lane >> 2, 64);
    } else {
        float tv[KSEL]; int ti[KSEL];
        #pragma unroll
        for (int q = 0; q < KSEL; ++q) { tv[q] = -INFINITY; ti[q] = 0x7FFFFFFF; }
        #pragma unroll
        for (int i = 0; i < 8; ++i) {
            int base = lane * 4 + i * 256;
            float vs[4] = {v4[i].x, v4[i].y, v4[i].z, v4[i].w};
            #pragma unroll
            for (int j = 0; j < 4; ++j) {
                float v = vs[j];
                int idx = base + j;
                if (v > tv[0]) {
                    bool cg[KSEL];
                    #pragma unroll
                    for (int q = 0; q < KSEL; ++q) cg[q] = v > tv[q];
                    #pragma unroll
                    for (int q = 0; q < KSEL - 1; ++q) {
                        tv[q] = cg[q + 1] ? tv[q + 1] : (cg[q] ? v : tv[q]);
                        ti[q] = cg[q + 1] ? ti[q + 1] : (cg[q] ? idx : ti[q]);
                    }
                    tv[KSEL - 1] = cg[KSEL - 1] ? v : tv[KSEL - 1];
                    ti[KSEL - 1] = cg[KSEL - 1] ? idx : ti[KSEL - 1];
                }
            }
        }
        #pragma unroll
        for (int rr = 0; rr < KSEL; ++rr) {
            float bv = tv[KSEL - 1]; int bi = ti[KSEL - 1];
            #pragma unroll
            for (int off = 1; off < 64; off <<= 1) {
                float ov = __shfl_xor(bv, off, 64);
                int   oi = __shfl_xor(bi, off, 64);
                if (ov > bv || (ov == bv && oi < bi)) { bv = ov; bi = oi; }
            }
            if ((lane >> 2) == rr) my_q = bi;
            if (bv == tv[KSEL - 1] && bi == ti[KSEL - 1]) {
                #pragma unroll
                for (int s = KSEL - 1; s > 0; --s) { tv[s] = tv[s - 1]; ti[s] = ti[s - 1]; }
                tv[0] = -INFINITY; ti[0] = 0x7FFFFFFF;
            }
        }
    }

    const float* xb = xn + (size_t)batch * xstride;
    const float* cp = xb + (size_t)p * NC + (lane & 3) * 48;
    const float* cq = xb + (size_t)my_q * NC + (lane & 3) * 48;
    float dot = 0.f;
    #pragma unroll
    for (int i = 0; i < 12; ++i) {
        float4 a = *reinterpret_cast<const float4*>(cp + i * 4);
        float4 bq = *reinterpret_cast<const float4*>(cq + i * 4);
        dot += a.x * bq.x + a.y * bq.y + a.z * bq.z + a.w * bq.w;
    }
    dot += __shfl_xor(dot, 1, 64);
    dot += __shfl_xor(dot, 2, 64);
    int g = lane >> 2;
    int rank = 0;
    #pragma unroll
    for (int j = 0; j < KSEL; ++j) {
        float vj = __shfl(dot, j * 4, 64);
        int   qj = __shfl(my_q, j * 4, 64);
        if (j != g && (vj > dot || (vj == dot && qj < my_q))) ++rank;
    }
    bool keep = ((lane & 3) == 0) && (rank < KNN);
    unsigned long long mask = __ballot(keep);
    int pos = __popcll(mask & ((1ull << lane) - 1));
    if (keep) knn[(size_t)row * KNN + pos] = my_q;
}

// ---- prep: w1t[384][192] bf16 = [(W1a - W1b)^T ; W1b^T] ----------------------
__global__ void __launch_bounds__(256) k_w1t(const float* __restrict__ W1,
                                             ushort* __restrict__ w1t) {
    int idx = blockIdx.x * 256 + threadIdx.x;
    if (idx >= 2 * NC * NC) return;
    int n = idx / NC, k = idx % NC;
    float v;
    if (n < NC) v = W1[(size_t)k * NC + n] - W1[(size_t)(k + NC) * NC + n];
    else        v = W1[(size_t)(k + NC) * NC + (n - NC)];
    w1t[idx] = f2bf(v);
}

// ---- prep: W2T bf16 [n][k] from W2 f32 [k][n] --------------------------------
__global__ void __launch_bounds__(256) k_w2t(const float* __restrict__ W2,
                                             ushort* __restrict__ w2t) {
    int idx = blockIdx.x * 256 + threadIdx.x;
    if (idx >= NC * NC) return;
    int n = idx / NC, k = idx % NC;
    w2t[(size_t)n * NC + k] = f2bf(W2[(size_t)k * NC + n]);
}

// ---- kernel 4: [U'|V] = Xb @ w1t^T via MFMA; bias fused into U' --------------
// 32 points/block, 256 thr (4 waves); wave w owns 96 output cols (of 384).
#define UVM 32
__global__ void __launch_bounds__(256) k_uv2(const ushort* __restrict__ xb,
                                             const ushort* __restrict__ w1t,
                                             const float* __restrict__ b1,
                                             float* __restrict__ up,
                                             float* __restrict__ vv) {
    __shared__ ushort xs[UVM][200];   // 12.8 KB, stride 400B -> uniform quads
    int t = threadIdx.x;
    int w = t >> 6, l = t & 63;
    int lg = l >> 4, lr = l & 15;
    int p0 = blockIdx.x * UVM;
    for (int i = t; i < UVM * 24; i += 256) {
        int row = i / 24, c = (i % 24) * 8;
        *reinterpret_cast<bf16x8*>(&xs[row][c]) =
            *reinterpret_cast<const bf16x8*>(&xb[(size_t)(p0 + row) * NC + c]);
    }
    __syncthreads();
    int n0 = w * 96;
    f32x4 acc[2][6];
    #pragma unroll
    for (int mt = 0; mt < 2; ++mt)
        #pragma unroll
        for (int nt = 0; nt < 6; ++nt)
            acc[mt][nt] = (f32x4){0.f, 0.f, 0.f, 0.f};
    #pragma unroll
    for (int ks = 0; ks < 6; ++ks) {
        bf16x8 bfr[6];
        #pragma unroll
        for (int nt = 0; nt < 6; ++nt)
            bfr[nt] = *reinterpret_cast<const bf16x8*>(
                &w1t[(size_t)(n0 + nt * 16 + lr) * NC + ks * 32 + lg * 8]);
        bf16x8 a0 = *reinterpret_cast<const bf16x8*>(&xs[lr][ks * 32 + lg * 8]);
        bf16x8 a1 = *reinterpret_cast<const bf16x8*>(&xs[16 + lr][ks * 32 + lg * 8]);
        #pragma unroll
        for (int nt = 0; nt < 6; ++nt) {
            acc[0][nt] = __builtin_amdgcn_mfma_f32_16x16x32_bf16(a0, bfr[nt], acc[0][nt], 0, 0, 0);
            acc[1][nt] = __builtin_amdgcn_mfma_f32_16x16x32_bf16(a1, bfr[nt], acc[1][nt], 0, 0, 0);
        }
    }
    bool isU = (n0 < NC);   // wave-uniform
    #pragma unroll
    for (int nt = 0; nt < 6; ++nt) {
        int col = n0 + nt * 16 + lr;
        float bb = isU ? b1[col] : 0.f;
        int ocol = isU ? col : col - NC;
        float* dst = isU ? up : vv;
        #pragma unroll
        for (int mt = 0; mt < 2; ++mt)
            #pragma unroll
            for (int j = 0; j < 4; ++j) {
                int pt = p0 + mt * 16 + lg * 4 + j;
                dst[(size_t)pt * NC + ocol] = acc[mt][nt][j] + bb;
            }
    }
}

// ---- kernel 5: edge MLP, 16 waves/block (32 pts), W2 in LDS, gather from L2 --
__device__ __forceinline__ bf16x8 make_h(const float* __restrict__ u,
                                         const float* __restrict__ v) {
    float4 ua = *reinterpret_cast<const float4*>(u);
    float4 ub = *reinterpret_cast<const float4*>(u + 4);
    float4 va = *reinterpret_cast<const float4*>(v);
    float4 vb = *reinterpret_cast<const float4*>(v + 4);
    union { bf16x8 v8; __hip_bfloat162 h2[4]; } r;
    r.h2[0] = __float22bfloat162_rn(make_float2(lrelu(ua.x + va.x), lrelu(ua.y + va.y)));
    r.h2[1] = __float22bfloat162_rn(make_float2(lrelu(ua.z + va.z), lrelu(ua.w + va.w)));
    r.h2[2] = __float22bfloat162_rn(make_float2(lrelu(ub.x + vb.x), lrelu(ub.y + vb.y)));
    r.h2[3] = __float22bfloat162_rn(make_float2(lrelu(ub.z + vb.z), lrelu(ub.w + vb.w)));
    return r.v8;
}

#define EW 16   // waves/block
#define EPW 2   // points/wave
__global__ void __launch_bounds__(1024, 1) k_edge4(const float* __restrict__ up,
                                                   const float* __restrict__ vv,
                                                   const int* __restrict__ knn,
                                                   const ushort* __restrict__ w2t,
                                                   const float* __restrict__ b2,
                                                   const float* __restrict__ gamma,
                                                   const float* __restrict__ beta,
                                                   float* __restrict__ out) {
    __shared__ ushort w2s[NC][200];          // 76.8 KB
    __shared__ float aggs[EW][EPW][NC];      // 24.6 KB
    int t = threadIdx.x;
    int wv = t >> 6, l = t & 63;
    int lg = l >> 4, lr = l & 15;

    for (int i = t; i < NC * 24; i += 1024) {
        int r_ = i / 24, c_ = i % 24;
        *reinterpret_cast<bf16x8*>(&w2s[r_][c_ * 8]) =
            *reinterpret_cast<const bf16x8*>(&w2t[(size_t)r_ * NC + c_ * 8]);
    }
    __syncthreads();   // only block-wide barrier

    int pt0 = blockIdx.x * (EW * EPW) + wv * EPW;
    int b = pt0 / NP;
    const float* vb = vv + (size_t)b * NP * NC;
    int lre = lr < KNN ? lr : KNN - 1;
    int q0 = knn[(size_t)(pt0 + 0) * KNN + lre];
    int q1 = knn[(size_t)(pt0 + 1) * KNN + lre];
    const float* u0p = up + (size_t)(pt0 + 0) * NC + 8 * lg;
    const float* u1p = up + (size_t)(pt0 + 1) * NC + 8 * lg;
    const float* v0p = vb + (size_t)q0 * NC + 8 * lg;
    const float* v1p = vb + (size_t)q1 * NC + 8 * lg;

    f32x4 acc[EPW][12];
    #pragma unroll
    for (int pt = 0; pt < EPW; ++pt)
        #pragma unroll
        for (int nt = 0; nt < 12; ++nt)
            acc[pt][nt] = (f32x4){0.f, 0.f, 0.f, 0.f};

    #pragma unroll
    for (int ks = 0; ks < 6; ++ks) {
        bf16x8 a0 = make_h(u0p + ks * 32, v0p + ks * 32);
        bf16x8 a1 = make_h(u1p + ks * 32, v1p + ks * 32);
        #pragma unroll
        for (int nt = 0; nt < 12; ++nt) {
            bf16x8 bfr = *reinterpret_cast<const bf16x8*>(&w2s[nt * 16 + lr][ks * 32 + lg * 8]);
            acc[0][nt] = __builtin_amdgcn_mfma_f32_16x16x32_bf16(a0, bfr, acc[0][nt], 0, 0, 0);
            acc[1][nt] = __builtin_amdgcn_mfma_f32_16x16x32_bf16(a1, bfr, acc[1][nt], 0, 0, 0);
        }
    }

    #pragma unroll
    for (int pt = 0; pt < EPW; ++pt) {
        #pragma unroll
        for (int nt = 0; nt < 12; ++nt) {
            float bb = b2[nt * 16 + lr];
            float s = 0.f;
            if (lg < 3) {
                #pragma unroll
                for (int j = 0; j < 4; ++j) s += lrelu(acc[pt][nt][j] + bb);
            }
            s += __shfl_xor(s, 16, 64);
            s += __shfl_xor(s, 32, 64);
            if (lg == 0) aggs[wv][pt][nt * 16 + lr] = s * (1.0f / KNN);
        }
    }
    asm volatile("s_waitcnt lgkmcnt(0)" ::: "memory");   // same-wave LDS RAW

    #pragma unroll
    for (int pt = 0; pt < EPW; ++pt) {
        float a0 = aggs[wv][pt][l], a1 = aggs[wv][pt][l + 64], a2 = aggs[wv][pt][l + 128];
        float s = a0 + a1 + a2;
        #pragma unroll
        for (int off = 32; off; off >>= 1) s += __shfl_xor(s, off, 64);
        float mu = s / (float)NC;
        float d0 = a0 - mu, d1 = a1 - mu, d2 = a2 - mu;
        float vs = d0 * d0 + d1 * d1 + d2 * d2;
        #pragma unroll
        for (int off = 32; off; off >>= 1) vs += __shfl_xor(vs, off, 64);
        float rstd = 1.0f / sqrtf(vs / (float)NC + 1e-5f);
        float* o = out + (size_t)(pt0 + pt) * NC;
        o[l]       = d0 * rstd * gamma[l]       + beta[l];
        o[l + 64]  = d1 * rstd * gamma[l + 64]  + beta[l + 64];
        o[l + 128] = d2 * rstd * gamma[l + 128] + beta[l + 128];
    }
}

extern "C" void kernel_launch(void* const* d_in, const int* in_sizes, int n_in,
                              void* d_out, int out_size, void* d_ws, size_t ws_size,
                              hipStream_t stream) {
    const float* nodes = (const float*)d_in[0];
    const float* W1    = (const float*)d_in[1];
    const float* b1    = (const float*)d_in[2];
    const float* W2    = (const float*)d_in[3];
    const float* b2    = (const float*)d_in[4];
    const float* gamma = (const float*)d_in[5];
    const float* beta  = (const float*)d_in[6];
    float* out = (float*)d_out;

    const size_t BPC = (size_t)NB * NP * NC;
    float*  xn  = (float*)d_ws;                        // B*P*C f32
    float*  up  = xn + BPC;                            // B*P*C f32
    float*  vv  = up + BPC;                            // B*P*C f32
    ushort* xh  = (ushort*)(vv + BPC);                 // B*P*C bf16 (normalized)
    ushort* xb  = xh + BPC;                            // B*P*C bf16 (raw)
    int*    knn = (int*)(xb + BPC);                    // B*P*K
    ushort* w2t = (ushort*)(knn + (size_t)NB * NP * KNN); // C*C bf16
    ushort* w1t = w2t + (size_t)NC * NC;               // 2C*C bf16
    float*  sim = (float*)((char*)(w1t + (size_t)2 * NC * NC) + 8);
    sim = (float*)(((uintptr_t)sim + 15) & ~(uintptr_t)15);

    size_t fixed_bytes = (size_t)((char*)sim - (char*)d_ws);
    bool full = ws_size >= fixed_bytes + (size_t)NB * NP * NP * 4;

    k_normalize<<<NB * NP / 4, 256, 0, stream>>>(nodes, xn, xh, xb);
    k_w1t<<<(2 * NC * NC + 255) / 256, 256, 0, stream>>>(W1, w1t);
    k_w2t<<<(NC * NC + 255) / 256, 256, 0, stream>>>(W2, w2t);
    k_uv2<<<NB * NP / UVM, 256, 0, stream>>>(xb, w1t, b1, up, vv);
    if (full) {
        k_sim3<<<dim3(NP / 128, NP / 128, NB), 256, 0, stream>>>(xh, sim,
                                                                 (size_t)NP * NC, (size_t)NP * NP);
        k_topk4<<<NB * NP / 4, 256, 0, stream>>>(sim, xn, knn,
                                                 (size_t)NP * NP, (size_t)NP * NC);
    } else {
        for (int b = 0; b < NB; ++b) {
            k_sim3<<<dim3(NP / 128, NP / 128, 1), 256, 0, stream>>>(xh + (size_t)b * NP * NC, sim, 0, 0);
            k_topk4<<<NP / 4, 256, 0, stream>>>(sim, xn + (size_t)b * NP * NC,
                                                knn + (size_t)b * NP * KNN, 0, 0);
        }
    }
    k_edge4<<<NB * NP / (EW * EPW), 1024, 0, stream>>>(up, vv, knn, w2t, b2, gamma, beta, out);
}

// Round 8
// 131.369 us; speedup vs baseline: 2.4208x; 1.0261x over previous
//
#include <hip/hip_runtime.h>
#include <hip/hip_bf16.h>
#include <math.h>

#define NB 4
#define NP 2048
#define NC 192
#define KNN 12
#define KSEL 16
#define NEG_SLOPE 0.2f

typedef __attribute__((ext_vector_type(8))) short bf16x8;
typedef __attribute__((ext_vector_type(4))) float f32x4;

__device__ __forceinline__ float lrelu(float x) { return x >= 0.0f ? x : NEG_SLOPE * x; }

__device__ __forceinline__ ushort f2bf(float x) {
    unsigned u = __float_as_uint(x);
    unsigned r = (u + 0x7FFFu + ((u >> 16) & 1u)) >> 16;   // RNE
    return (ushort)r;
}

// -- kernel 1: L2-normalize; out: xn f32 (rescore), xh bf16 (sim), xb bf16 (UV)
__global__ void __launch_bounds__(256) k_normalize(const float* __restrict__ nodes,
                                                   float* __restrict__ xn,
                                                   ushort* __restrict__ xh,
                                                   ushort* __restrict__ xb) {
    int wave = threadIdx.x >> 6;
    int lane = threadIdx.x & 63;
    size_t pt = (size_t)blockIdx.x * 4 + wave;
    const float* x = nodes + pt * NC;
    float v0 = x[lane], v1 = x[lane + 64], v2 = x[lane + 128];
    float s = v0 * v0 + v1 * v1 + v2 * v2;
    #pragma unroll
    for (int off = 32; off; off >>= 1) s += __shfl_xor(s, off, 64);
    float inv = 1.0f / fmaxf(sqrtf(s), 1e-12f);
    float f0 = v0 * inv, f1 = v1 * inv, f2 = v2 * inv;
    float* o = xn + pt * NC;
    o[lane] = f0; o[lane + 64] = f1; o[lane + 128] = f2;
    ushort* oh = xh + pt * NC;
    oh[lane] = f2bf(f0); oh[lane + 64] = f2bf(f1); oh[lane + 128] = f2bf(f2);
    ushort* ob = xb + pt * NC;
    ob[lane] = f2bf(v0); ob[lane + 64] = f2bf(v1); ob[lane + 128] = f2bf(v2);
}

// ------- kernel 2: sim = Xh * Xh^T via bf16 MFMA (approximate, f32 out) -------
__global__ void __launch_bounds__(256) k_sim3(const ushort* __restrict__ xh,
                                              float* __restrict__ sim,
                                              size_t xstride, size_t simstride) {
    __shared__ ushort Ah[128][72];
    __shared__ ushort Bh[128][72];
    const ushort* XbH = xh + (size_t)blockIdx.z * xstride;
    float* sb = sim + (size_t)blockIdx.z * simstride;
    int t = threadIdx.x;
    int w = t >> 6, l = t & 63;
    int wm = w >> 1, wn = w & 1;
    int lg = l >> 4, lr = l & 15;
    int m0 = blockIdx.y * 128, n0 = blockIdx.x * 128;

    f32x4 acc[4][4];
    #pragma unroll
    for (int mi = 0; mi < 4; ++mi)
        #pragma unroll
        for (int ni = 0; ni < 4; ++ni)
            acc[mi][ni] = (f32x4){0.f, 0.f, 0.f, 0.f};

    int r = t >> 3, c = (t & 7) * 8;
    for (int ks = 0; ks < 3; ++ks) {
        int kb = ks * 64;
        #pragma unroll
        for (int i = 0; i < 4; ++i) {
            int row = r + 32 * i;
            *reinterpret_cast<bf16x8*>(&Ah[row][c]) =
                *reinterpret_cast<const bf16x8*>(&XbH[(size_t)(m0 + row) * NC + kb + c]);
            *reinterpret_cast<bf16x8*>(&Bh[row][c]) =
                *reinterpret_cast<const bf16x8*>(&XbH[(size_t)(n0 + row) * NC + kb + c]);
        }
        __syncthreads();
        #pragma unroll
        for (int ksub = 0; ksub < 2; ++ksub) {
            int ko = ksub * 32 + 8 * lg;
            bf16x8 af[4], bf[4];
            #pragma unroll
            for (int f = 0; f < 4; ++f) {
                af[f] = *reinterpret_cast<const bf16x8*>(&Ah[wm * 64 + f * 16 + lr][ko]);
                bf[f] = *reinterpret_cast<const bf16x8*>(&Bh[wn * 64 + f * 16 + lr][ko]);
            }
            #pragma unroll
            for (int mi = 0; mi < 4; ++mi)
                #pragma unroll
                for (int ni = 0; ni < 4; ++ni)
                    acc[mi][ni] = __builtin_amdgcn_mfma_f32_16x16x32_bf16(af[mi], bf[ni], acc[mi][ni], 0, 0, 0);
        }
        __syncthreads();
    }
    #pragma unroll
    for (int mi = 0; mi < 4; ++mi)
        #pragma unroll
        for (int j = 0; j < 4; ++j) {
            int row = m0 + wm * 64 + mi * 16 + lg * 4 + j;
            #pragma unroll
            for (int ni = 0; ni < 4; ++ni)
                sb[(size_t)row * NP + n0 + wn * 64 + ni * 16 + lr] = acc[mi][ni][j];
        }
}

// ------- kernel 3: threshold+compact+bitonic top-16, exact rescore -> 12-set --
__global__ void __launch_bounds__(256) k_topk4(const float* __restrict__ sim,
                                               const float* __restrict__ xn,
                                               int* __restrict__ knn,
                                               size_t simstride, size_t xstride) {
    __shared__ float cvs[4][64];
    __shared__ int   cis[4][64];
    int wv = threadIdx.x >> 6, lane = threadIdx.x & 63;
    int row = blockIdx.x * 4 + wv;
    int batch = row / NP, p = row % NP;
    const float* sr = sim + (size_t)batch * simstride + (size_t)p * NP;

    float4 v4[8];
    #pragma unroll
    for (int i = 0; i < 8; ++i)
        v4[i] = *reinterpret_cast<const float4*>(sr + lane * 4 + i * 256);

    #pragma unroll
    for (int i = 0; i < 8; ++i) {
        int base = lane * 4 + i * 256;
        v4[i].x = (base + 0 == p) ? -INFINITY : v4[i].x;
        v4[i].y = (base + 1 == p) ? -INFINITY : v4[i].y;
        v4[i].z = (base + 2 == p) ? -INFINITY : v4[i].z;
        v4[i].w = (base + 3 == p) ? -INFINITY : v4[i].w;
    }

    float lmax = -INFINITY;
    #pragma unroll
    for (int i = 0; i < 8; ++i) {
        lmax = fmaxf(lmax, fmaxf(fmaxf(v4[i].x, v4[i].y), fmaxf(v4[i].z, v4[i].w)));
    }

    float sm = lmax;
    #pragma unroll
    for (int k = 2; k <= 64; k <<= 1) {
        #pragma unroll
        for (int j = k >> 1; j >= 1; j >>= 1) {
            float ov = __shfl_xor(sm, j, 64);
            bool lower = (lane & j) == 0;
            bool up = (lane & k) != 0;
            float lo = fminf(sm, ov), hi = fmaxf(sm, ov);
            sm = (up == lower) ? lo : hi;
        }
    }
    float theta = __shfl(sm, 16, 64);

    int cnt = 0;
    #pragma unroll
    for (int i = 0; i < 8; ++i) {
        cnt += (v4[i].x > theta) + (v4[i].y > theta) + (v4[i].z > theta) + (v4[i].w > theta);
    }
    int x = cnt;
    #pragma unroll
    for (int off = 1; off < 64; off <<= 1) {
        int y = __shfl_up(x, off, 64);
        if (lane >= off) x += y;
    }
    int excl = x - cnt;
    int total = __shfl(x, 63, 64);

    int my_q = 0;
    bool fb = (total < KSEL) || (total > 64);
    if (!fb) {
        cvs[wv][lane] = -INFINITY;
        cis[wv][lane] = 0;
        asm volatile("s_waitcnt lgkmcnt(0)" ::: "memory");
        int pos = excl;
        #pragma unroll
        for (int i = 0; i < 8; ++i) {
            int base = lane * 4 + i * 256;
            float vs[4] = {v4[i].x, v4[i].y, v4[i].z, v4[i].w};
            #pragma unroll
            for (int j = 0; j < 4; ++j) {
                if (vs[j] > theta) {
                    cvs[wv][pos] = vs[j];
                    cis[wv][pos] = base + j;
                    ++pos;
                }
            }
        }
        asm volatile("s_waitcnt lgkmcnt(0)" ::: "memory");
        float v = cvs[wv][lane];
        int   idx = cis[wv][lane];
        #pragma unroll
        for (int k = 2; k <= 64; k <<= 1) {
            #pragma unroll
            for (int j = k >> 1; j >= 1; j >>= 1) {
                float ov = __shfl_xor(v, j, 64);
                int   oi = __shfl_xor(idx, j, 64);
                bool lower = (lane & j) == 0;
                bool up = (lane & k) != 0;
                bool ogt = (ov > v);
                float hv = ogt ? ov : v;  int hid = ogt ? oi : idx;
                float lv = ogt ? v : ov;  int lid = ogt ? idx : oi;
                bool keep_lo = (up == lower);
                v   = keep_lo ? lv : hv;
                idx = keep_lo ? lid : hid;
            }
        }
        my_q = __shfl(idx, lane >> 2, 64);
    } else {
        float tv[KSEL]; int ti[KSEL];
        #pragma unroll
        for (int q = 0; q < KSEL; ++q) { tv[q] = -INFINITY; ti[q] = 0x7FFFFFFF; }
        #pragma unroll
        for (int i = 0; i < 8; ++i) {
            int base = lane * 4 + i * 256;
            float vs[4] = {v4[i].x, v4[i].y, v4[i].z, v4[i].w};
            #pragma unroll
            for (int j = 0; j < 4; ++j) {
                float v = vs[j];
                int idx = base + j;
                if (v > tv[0]) {
                    bool cg[KSEL];
                    #pragma unroll
                    for (int q = 0; q < KSEL; ++q) cg[q] = v > tv[q];
                    #pragma unroll
                    for (int q = 0; q < KSEL - 1; ++q) {
                        tv[q] = cg[q + 1] ? tv[q + 1] : (cg[q] ? v : tv[q]);
                        ti[q] = cg[q + 1] ? ti[q + 1] : (cg[q] ? idx : ti[q]);
                    }
                    tv[KSEL - 1] = cg[KSEL - 1] ? v : tv[KSEL - 1];
                    ti[KSEL - 1] = cg[KSEL - 1] ? idx : ti[KSEL - 1];
                }
            }
        }
        #pragma unroll
        for (int rr = 0; rr < KSEL; ++rr) {
            float bv = tv[KSEL - 1]; int bi = ti[KSEL - 1];
            #pragma unroll
            for (int off = 1; off < 64; off <<= 1) {
                float ov = __shfl_xor(bv, off, 64);
                int   oi = __shfl_xor(bi, off, 64);
                if (ov > bv || (ov == bv && oi < bi)) { bv = ov; bi = oi; }
            }
            if ((lane >> 2) == rr) my_q = bi;
            if (bv == tv[KSEL - 1] && bi == ti[KSEL - 1]) {
                #pragma unroll
                for (int s = KSEL - 1; s > 0; --s) { tv[s] = tv[s - 1]; ti[s] = ti[s - 1]; }
                tv[0] = -INFINITY; ti[0] = 0x7FFFFFFF;
            }
        }
    }

    const float* xb = xn + (size_t)batch * xstride;
    const float* cp = xb + (size_t)p * NC + (lane & 3) * 48;
    const float* cq = xb + (size_t)my_q * NC + (lane & 3) * 48;
    float dot = 0.f;
    #pragma unroll
    for (int i = 0; i < 12; ++i) {
        float4 a = *reinterpret_cast<const float4*>(cp + i * 4);
        float4 bq = *reinterpret_cast<const float4*>(cq + i * 4);
        dot += a.x * bq.x + a.y * bq.y + a.z * bq.z + a.w * bq.w;
    }
    dot += __shfl_xor(dot, 1, 64);
    dot += __shfl_xor(dot, 2, 64);
    int g = lane >> 2;
    int rank = 0;
    #pragma unroll
    for (int j = 0; j < KSEL; ++j) {
        float vj = __shfl(dot, j * 4, 64);
        int   qj = __shfl(my_q, j * 4, 64);
        if (j != g && (vj > dot || (vj == dot && qj < my_q))) ++rank;
    }
    bool keep = ((lane & 3) == 0) && (rank < KNN);
    unsigned long long mask = __ballot(keep);
    int pos = __popcll(mask & ((1ull << lane) - 1));
    if (keep) knn[(size_t)row * KNN + pos] = my_q;
}

// ---- prep: w1t[384][192] bf16 = [(W1a - W1b)^T ; W1b^T] ----------------------
__global__ void __launch_bounds__(256) k_w1t(const float* __restrict__ W1,
                                             ushort* __restrict__ w1t) {
    int idx = blockIdx.x * 256 + threadIdx.x;
    if (idx >= 2 * NC * NC) return;
    int n = idx / NC, k = idx % NC;
    float v;
    if (n < NC) v = W1[(size_t)k * NC + n] - W1[(size_t)(k + NC) * NC + n];
    else        v = W1[(size_t)(k + NC) * NC + (n - NC)];
    w1t[idx] = f2bf(v);
}

// ---- prep: W2T bf16 [n][k] from W2 f32 [k][n] --------------------------------
__global__ void __launch_bounds__(256) k_w2t(const float* __restrict__ W2,
                                             ushort* __restrict__ w2t) {
    int idx = blockIdx.x * 256 + threadIdx.x;
    if (idx >= NC * NC) return;
    int n = idx / NC, k = idx % NC;
    w2t[(size_t)n * NC + k] = f2bf(W2[(size_t)k * NC + n]);
}

// ---- kernel 4: [U'|V] = Xb @ w1t^T via MFMA; bias fused into U' --------------
#define UVM 32
__global__ void __launch_bounds__(256) k_uv2(const ushort* __restrict__ xb,
                                             const ushort* __restrict__ w1t,
                                             const float* __restrict__ b1,
                                             float* __restrict__ up,
                                             float* __restrict__ vv) {
    __shared__ ushort xs[UVM][200];
    int t = threadIdx.x;
    int w = t >> 6, l = t & 63;
    int lg = l >> 4, lr = l & 15;
    int p0 = blockIdx.x * UVM;
    for (int i = t; i < UVM * 24; i += 256) {
        int row = i / 24, c = (i % 24) * 8;
        *reinterpret_cast<bf16x8*>(&xs[row][c]) =
            *reinterpret_cast<const bf16x8*>(&xb[(size_t)(p0 + row) * NC + c]);
    }
    __syncthreads();
    int n0 = w * 96;
    f32x4 acc[2][6];
    #pragma unroll
    for (int mt = 0; mt < 2; ++mt)
        #pragma unroll
        for (int nt = 0; nt < 6; ++nt)
            acc[mt][nt] = (f32x4){0.f, 0.f, 0.f, 0.f};
    #pragma unroll
    for (int ks = 0; ks < 6; ++ks) {
        bf16x8 bfr[6];
        #pragma unroll
        for (int nt = 0; nt < 6; ++nt)
            bfr[nt] = *reinterpret_cast<const bf16x8*>(
                &w1t[(size_t)(n0 + nt * 16 + lr) * NC + ks * 32 + lg * 8]);
        bf16x8 a0 = *reinterpret_cast<const bf16x8*>(&xs[lr][ks * 32 + lg * 8]);
        bf16x8 a1 = *reinterpret_cast<const bf16x8*>(&xs[16 + lr][ks * 32 + lg * 8]);
        #pragma unroll
        for (int nt = 0; nt < 6; ++nt) {
            acc[0][nt] = __builtin_amdgcn_mfma_f32_16x16x32_bf16(a0, bfr[nt], acc[0][nt], 0, 0, 0);
            acc[1][nt] = __builtin_amdgcn_mfma_f32_16x16x32_bf16(a1, bfr[nt], acc[1][nt], 0, 0, 0);
        }
    }
    bool isU = (n0 < NC);
    #pragma unroll
    for (int nt = 0; nt < 6; ++nt) {
        int col = n0 + nt * 16 + lr;
        float bb = isU ? b1[col] : 0.f;
        int ocol = isU ? col : col - NC;
        float* dst = isU ? up : vv;
        #pragma unroll
        for (int mt = 0; mt < 2; ++mt)
            #pragma unroll
            for (int j = 0; j < 4; ++j) {
                int pt = p0 + mt * 16 + lg * 4 + j;
                dst[(size_t)pt * NC + ocol] = acc[mt][nt][j] + bb;
            }
    }
}

// ---- kernel 5: edge MLP; XCD batch-affinity swizzle + double-buffered gather -
__device__ __forceinline__ bf16x8 packh(float4 ua, float4 ub, float4 va, float4 vb) {
    union { bf16x8 v8; __hip_bfloat162 h2[4]; } r;
    r.h2[0] = __float22bfloat162_rn(make_float2(lrelu(ua.x + va.x), lrelu(ua.y + va.y)));
    r.h2[1] = __float22bfloat162_rn(make_float2(lrelu(ua.z + va.z), lrelu(ua.w + va.w)));
    r.h2[2] = __float22bfloat162_rn(make_float2(lrelu(ub.x + vb.x), lrelu(ub.y + vb.y)));
    r.h2[3] = __float22bfloat162_rn(make_float2(lrelu(ub.z + vb.z), lrelu(ub.w + vb.w)));
    return r.v8;
}

#define EW 16   // waves/block
#define EPW 2   // points/wave
__global__ void __launch_bounds__(1024, 1) k_edge5(const float* __restrict__ up,
                                                   const float* __restrict__ vv,
                                                   const int* __restrict__ knn,
                                                   const ushort* __restrict__ w2t,
                                                   const float* __restrict__ b2,
                                                   const float* __restrict__ gamma,
                                                   const float* __restrict__ beta,
                                                   float* __restrict__ out) {
    __shared__ ushort w2s[NC][200];          // 76.8 KB
    __shared__ float aggs[EW][EPW][NC];      // 24.6 KB
    int t = threadIdx.x;
    int wv = t >> 6, l = t & 63;
    int lg = l >> 4, lr = l & 15;

    // XCD batch-affinity swizzle: grid=256, 8 XCDs x 32 CUs. Work chunk per XCD
    // is contiguous (covers half a batch) -> per-XCD L2 gather working set
    // = one batch's vv slice (1.57 MB), fits the 4 MB XCD L2.
    int bid = blockIdx.x;
    int wrk = (bid & 7) * 32 + (bid >> 3);

    for (int i = t; i < NC * 24; i += 1024) {
        int r_ = i / 24, c_ = i % 24;
        *reinterpret_cast<bf16x8*>(&w2s[r_][c_ * 8]) =
            *reinterpret_cast<const bf16x8*>(&w2t[(size_t)r_ * NC + c_ * 8]);
    }
    __syncthreads();   // only block-wide barrier

    int pt0 = wrk * (EW * EPW) + wv * EPW;
    int b = pt0 / NP;
    const float* vb = vv + (size_t)b * NP * NC;
    int lre = lr < KNN ? lr : KNN - 1;
    int q0 = knn[(size_t)(pt0 + 0) * KNN + lre];
    int q1 = knn[(size_t)(pt0 + 1) * KNN + lre];
    const float* u0p = up + (size_t)(pt0 + 0) * NC + 8 * lg;
    const float* u1p = up + (size_t)(pt0 + 1) * NC + 8 * lg;
    const float* v0p = vb + (size_t)q0 * NC + 8 * lg;
    const float* v1p = vb + (size_t)q1 * NC + 8 * lg;

    f32x4 acc[EPW][12];
    #pragma unroll
    for (int pt = 0; pt < EPW; ++pt)
        #pragma unroll
        for (int nt = 0; nt < 12; ++nt)
            acc[pt][nt] = (f32x4){0.f, 0.f, 0.f, 0.f};

    // double-buffered gather: issue ks+1 loads before ks's MFMA block
    float4 sU0a[2], sU0b[2], sV0a[2], sV0b[2];
    float4 sU1a[2], sU1b[2], sV1a[2], sV1b[2];
#define LDST(ph, ks) do { \
        sU0a[ph] = *reinterpret_cast<const float4*>(u0p + (ks) * 32);     \
        sU0b[ph] = *reinterpret_cast<const float4*>(u0p + (ks) * 32 + 4); \
        sV0a[ph] = *reinterpret_cast<const float4*>(v0p + (ks) * 32);     \
        sV0b[ph] = *reinterpret_cast<const float4*>(v0p + (ks) * 32 + 4); \
        sU1a[ph] = *reinterpret_cast<const float4*>(u1p + (ks) * 32);     \
        sU1b[ph] = *reinterpret_cast<const float4*>(u1p + (ks) * 32 + 4); \
        sV1a[ph] = *reinterpret_cast<const float4*>(v1p + (ks) * 32);     \
        sV1b[ph] = *reinterpret_cast<const float4*>(v1p + (ks) * 32 + 4); \
    } while (0)

    LDST(0, 0);
    #pragma unroll
    for (int ks = 0; ks < 6; ++ks) {
        int ph = ks & 1;
        if (ks < 5) LDST(ph ^ 1, ks + 1);
        bf16x8 a0 = packh(sU0a[ph], sU0b[ph], sV0a[ph], sV0b[ph]);
        bf16x8 a1 = packh(sU1a[ph], sU1b[ph], sV1a[ph], sV1b[ph]);
        #pragma unroll
        for (int nt = 0; nt < 12; ++nt) {
            bf16x8 bfr = *reinterpret_cast<const bf16x8*>(&w2s[nt * 16 + lr][ks * 32 + lg * 8]);
            acc[0][nt] = __builtin_amdgcn_mfma_f32_16x16x32_bf16(a0, bfr, acc[0][nt], 0, 0, 0);
            acc[1][nt] = __builtin_amdgcn_mfma_f32_16x16x32_bf16(a1, bfr, acc[1][nt], 0, 0, 0);
        }
    }
#undef LDST

    #pragma unroll
    for (int pt = 0; pt < EPW; ++pt) {
        #pragma unroll
        for (int nt = 0; nt < 12; ++nt) {
            float bb = b2[nt * 16 + lr];
            float s = 0.f;
            if (lg < 3) {
                #pragma unroll
                for (int j = 0; j < 4; ++j) s += lrelu(acc[pt][nt][j] + bb);
            }
            s += __shfl_xor(s, 16, 64);
            s += __shfl_xor(s, 32, 64);
            if (lg == 0) aggs[wv][pt][nt * 16 + lr] = s * (1.0f / KNN);
        }
    }
    asm volatile("s_waitcnt lgkmcnt(0)" ::: "memory");   // same-wave LDS RAW

    #pragma unroll
    for (int pt = 0; pt < EPW; ++pt) {
        float a0 = aggs[wv][pt][l], a1 = aggs[wv][pt][l + 64], a2 = aggs[wv][pt][l + 128];
        float s = a0 + a1 + a2;
        #pragma unroll
        for (int off = 32; off; off >>= 1) s += __shfl_xor(s, off, 64);
        float mu = s / (float)NC;
        float d0 = a0 - mu, d1 = a1 - mu, d2 = a2 - mu;
        float vs = d0 * d0 + d1 * d1 + d2 * d2;
        #pragma unroll
        for (int off = 32; off; off >>= 1) vs += __shfl_xor(vs, off, 64);
        float rstd = 1.0f / sqrtf(vs / (float)NC + 1e-5f);
        float* o = out + (size_t)(pt0 + pt) * NC;
        o[l]       = d0 * rstd * gamma[l]       + beta[l];
        o[l + 64]  = d1 * rstd * gamma[l + 64]  + beta[l + 64];
        o[l + 128] = d2 * rstd * gamma[l + 128] + beta[l + 128];
    }
}

extern "C" void kernel_launch(void* const* d_in, const int* in_sizes, int n_in,
                              void* d_out, int out_size, void* d_ws, size_t ws_size,
                              hipStream_t stream) {
    const float* nodes = (const float*)d_in[0];
    const float* W1    = (const float*)d_in[1];
    const float* b1    = (const float*)d_in[2];
    const float* W2    = (const float*)d_in[3];
    const float* b2    = (const float*)d_in[4];
    const float* gamma = (const float*)d_in[5];
    const float* beta  = (const float*)d_in[6];
    float* out = (float*)d_out;

    const size_t BPC = (size_t)NB * NP * NC;
    float*  xn  = (float*)d_ws;                        // B*P*C f32
    float*  up  = xn + BPC;                            // B*P*C f32
    float*  vv  = up + BPC;                            // B*P*C f32
    ushort* xh  = (ushort*)(vv + BPC);                 // B*P*C bf16 (normalized)
    ushort* xb  = xh + BPC;                            // B*P*C bf16 (raw)
    int*    knn = (int*)(xb + BPC);                    // B*P*K
    ushort* w2t = (ushort*)(knn + (size_t)NB * NP * KNN); // C*C bf16
    ushort* w1t = w2t + (size_t)NC * NC;               // 2C*C bf16
    float*  sim = (float*)((char*)(w1t + (size_t)2 * NC * NC) + 8);
    sim = (float*)(((uintptr_t)sim + 15) & ~(uintptr_t)15);

    size_t fixed_bytes = (size_t)((char*)sim - (char*)d_ws);
    bool full = ws_size >= fixed_bytes + (size_t)NB * NP * NP * 4;

    k_normalize<<<NB * NP / 4, 256, 0, stream>>>(nodes, xn, xh, xb);
    k_w1t<<<(2 * NC * NC + 255) / 256, 256, 0, stream>>>(W1, w1t);
    k_w2t<<<(NC * NC + 255) / 256, 256, 0, stream>>>(W2, w2t);
    k_uv2<<<NB * NP / UVM, 256, 0, stream>>>(xb, w1t, b1, up, vv);
    if (full) {
        k_sim3<<<dim3(NP / 128, NP / 128, NB), 256, 0, stream>>>(xh, sim,
                                                                 (size_t)NP * NC, (size_t)NP * NP);
        k_topk4<<<NB * NP / 4, 256, 0, stream>>>(sim, xn, knn,
                                                 (size_t)NP * NP, (size_t)NP * NC);
    } else {
        for (int b = 0; b < NB; ++b) {
            k_sim3<<<dim3(NP / 128, NP / 128, 1), 256, 0, stream>>>(xh + (size_t)b * NP * NC, sim, 0, 0);
            k_topk4<<<NP / 4, 256, 0, stream>>>(sim, xn + (size_t)b * NP * NC,
                                                knn + (size_t)b * NP * KNN, 0, 0);
        }
    }
    k_edge5<<<NB * NP / (EW * EPW), 1024, 0, stream>>>(up, vv, knn, w2t, b2, gamma, beta, out);
}

// Round 9
// 118.234 us; speedup vs baseline: 2.6897x; 1.1111x over previous
//
#include <hip/hip_runtime.h>
#include <hip/hip_bf16.h>
#include <math.h>

#define NB 4
#define NP 2048
#define NC 192
#define KNN 12
#define KSEL 16
#define NEG_SLOPE 0.2f

typedef __attribute__((ext_vector_type(8))) short bf16x8;
typedef __attribute__((ext_vector_type(4))) float f32x4;

__device__ __forceinline__ float lrelu(float x) { return x >= 0.0f ? x : NEG_SLOPE * x; }

__device__ __forceinline__ ushort f2bf(float x) {
    unsigned u = __float_as_uint(x);
    unsigned r = (u + 0x7FFFu + ((u >> 16) & 1u)) >> 16;   // RNE
    return (ushort)r;
}

// -- kernel 1: L2-normalize; out: xn f32 (rescore), xh bf16 (sim), xb bf16 (UV)
__global__ void __launch_bounds__(256) k_normalize(const float* __restrict__ nodes,
                                                   float* __restrict__ xn,
                                                   ushort* __restrict__ xh,
                                                   ushort* __restrict__ xb) {
    int wave = threadIdx.x >> 6;
    int lane = threadIdx.x & 63;
    size_t pt = (size_t)blockIdx.x * 4 + wave;
    const float* x = nodes + pt * NC;
    float v0 = x[lane], v1 = x[lane + 64], v2 = x[lane + 128];
    float s = v0 * v0 + v1 * v1 + v2 * v2;
    #pragma unroll
    for (int off = 32; off; off >>= 1) s += __shfl_xor(s, off, 64);
    float inv = 1.0f / fmaxf(sqrtf(s), 1e-12f);
    float f0 = v0 * inv, f1 = v1 * inv, f2 = v2 * inv;
    float* o = xn + pt * NC;
    o[lane] = f0; o[lane + 64] = f1; o[lane + 128] = f2;
    ushort* oh = xh + pt * NC;
    oh[lane] = f2bf(f0); oh[lane + 64] = f2bf(f1); oh[lane + 128] = f2bf(f2);
    ushort* ob = xb + pt * NC;
    ob[lane] = f2bf(v0); ob[lane + 64] = f2bf(v1); ob[lane + 128] = f2bf(v2);
}

// ------- kernel 2: sim = Xh * Xh^T via bf16 MFMA (approximate, f32 out) -------
__global__ void __launch_bounds__(256) k_sim3(const ushort* __restrict__ xh,
                                              float* __restrict__ sim,
                                              size_t xstride, size_t simstride) {
    __shared__ ushort Ah[128][72];
    __shared__ ushort Bh[128][72];
    const ushort* XbH = xh + (size_t)blockIdx.z * xstride;
    float* sb = sim + (size_t)blockIdx.z * simstride;
    int t = threadIdx.x;
    int w = t >> 6, l = t & 63;
    int wm = w >> 1, wn = w & 1;
    int lg = l >> 4, lr = l & 15;
    int m0 = blockIdx.y * 128, n0 = blockIdx.x * 128;

    f32x4 acc[4][4];
    #pragma unroll
    for (int mi = 0; mi < 4; ++mi)
        #pragma unroll
        for (int ni = 0; ni < 4; ++ni)
            acc[mi][ni] = (f32x4){0.f, 0.f, 0.f, 0.f};

    int r = t >> 3, c = (t & 7) * 8;
    for (int ks = 0; ks < 3; ++ks) {
        int kb = ks * 64;
        #pragma unroll
        for (int i = 0; i < 4; ++i) {
            int row = r + 32 * i;
            *reinterpret_cast<bf16x8*>(&Ah[row][c]) =
                *reinterpret_cast<const bf16x8*>(&XbH[(size_t)(m0 + row) * NC + kb + c]);
            *reinterpret_cast<bf16x8*>(&Bh[row][c]) =
                *reinterpret_cast<const bf16x8*>(&XbH[(size_t)(n0 + row) * NC + kb + c]);
        }
        __syncthreads();
        #pragma unroll
        for (int ksub = 0; ksub < 2; ++ksub) {
            int ko = ksub * 32 + 8 * lg;
            bf16x8 af[4], bf[4];
            #pragma unroll
            for (int f = 0; f < 4; ++f) {
                af[f] = *reinterpret_cast<const bf16x8*>(&Ah[wm * 64 + f * 16 + lr][ko]);
                bf[f] = *reinterpret_cast<const bf16x8*>(&Bh[wn * 64 + f * 16 + lr][ko]);
            }
            #pragma unroll
            for (int mi = 0; mi < 4; ++mi)
                #pragma unroll
                for (int ni = 0; ni < 4; ++ni)
                    acc[mi][ni] = __builtin_amdgcn_mfma_f32_16x16x32_bf16(af[mi], bf[ni], acc[mi][ni], 0, 0, 0);
        }
        __syncthreads();
    }
    #pragma unroll
    for (int mi = 0; mi < 4; ++mi)
        #pragma unroll
        for (int j = 0; j < 4; ++j) {
            int row = m0 + wm * 64 + mi * 16 + lg * 4 + j;
            #pragma unroll
            for (int ni = 0; ni < 4; ++ni)
                sb[(size_t)row * NP + n0 + wn * 64 + ni * 16 + lr] = acc[mi][ni][j];
        }
}

// ------- kernel 3: threshold+compact+bitonic top-16, exact rescore -> 12-set --
__global__ void __launch_bounds__(256) k_topk4(const float* __restrict__ sim,
                                               const float* __restrict__ xn,
                                               int* __restrict__ knn,
                                               size_t simstride, size_t xstride) {
    __shared__ float cvs[4][64];
    __shared__ int   cis[4][64];
    int wv = threadIdx.x >> 6, lane = threadIdx.x & 63;
    int row = blockIdx.x * 4 + wv;
    int batch = row / NP, p = row % NP;
    const float* sr = sim + (size_t)batch * simstride + (size_t)p * NP;

    float4 v4[8];
    #pragma unroll
    for (int i = 0; i < 8; ++i)
        v4[i] = *reinterpret_cast<const float4*>(sr + lane * 4 + i * 256);

    #pragma unroll
    for (int i = 0; i < 8; ++i) {
        int base = lane * 4 + i * 256;
        v4[i].x = (base + 0 == p) ? -INFINITY : v4[i].x;
        v4[i].y = (base + 1 == p) ? -INFINITY : v4[i].y;
        v4[i].z = (base + 2 == p) ? -INFINITY : v4[i].z;
        v4[i].w = (base + 3 == p) ? -INFINITY : v4[i].w;
    }

    float lmax = -INFINITY;
    #pragma unroll
    for (int i = 0; i < 8; ++i) {
        lmax = fmaxf(lmax, fmaxf(fmaxf(v4[i].x, v4[i].y), fmaxf(v4[i].z, v4[i].w)));
    }

    float sm = lmax;
    #pragma unroll
    for (int k = 2; k <= 64; k <<= 1) {
        #pragma unroll
        for (int j = k >> 1; j >= 1; j >>= 1) {
            float ov = __shfl_xor(sm, j, 64);
            bool lower = (lane & j) == 0;
            bool up = (lane & k) != 0;
            float lo = fminf(sm, ov), hi = fmaxf(sm, ov);
            sm = (up == lower) ? lo : hi;
        }
    }
    float theta = __shfl(sm, 16, 64);

    int cnt = 0;
    #pragma unroll
    for (int i = 0; i < 8; ++i) {
        cnt += (v4[i].x > theta) + (v4[i].y > theta) + (v4[i].z > theta) + (v4[i].w > theta);
    }
    int x = cnt;
    #pragma unroll
    for (int off = 1; off < 64; off <<= 1) {
        int y = __shfl_up(x, off, 64);
        if (lane >= off) x += y;
    }
    int excl = x - cnt;
    int total = __shfl(x, 63, 64);

    int my_q = 0;
    bool fb = (total < KSEL) || (total > 64);
    if (!fb) {
        cvs[wv][lane] = -INFINITY;
        cis[wv][lane] = 0;
        asm volatile("s_waitcnt lgkmcnt(0)" ::: "memory");
        int pos = excl;
        #pragma unroll
        for (int i = 0; i < 8; ++i) {
            int base = lane * 4 + i * 256;
            float vs[4] = {v4[i].x, v4[i].y, v4[i].z, v4[i].w};
            #pragma unroll
            for (int j = 0; j < 4; ++j) {
                if (vs[j] > theta) {
                    cvs[wv][pos] = vs[j];
                    cis[wv][pos] = base + j;
                    ++pos;
                }
            }
        }
        asm volatile("s_waitcnt lgkmcnt(0)" ::: "memory");
        float v = cvs[wv][lane];
        int   idx = cis[wv][lane];
        #pragma unroll
        for (int k = 2; k <= 64; k <<= 1) {
            #pragma unroll
            for (int j = k >> 1; j >= 1; j >>= 1) {
                float ov = __shfl_xor(v, j, 64);
                int   oi = __shfl_xor(idx, j, 64);
                bool lower = (lane & j) == 0;
                bool up = (lane & k) != 0;
                bool ogt = (ov > v);
                float hv = ogt ? ov : v;  int hid = ogt ? oi : idx;
                float lv = ogt ? v : ov;  int lid = ogt ? idx : oi;
                bool keep_lo = (up == lower);
                v   = keep_lo ? lv : hv;
                idx = keep_lo ? lid : hid;
            }
        }
        my_q = __shfl(idx, lane >> 2, 64);
    } else {
        float tv[KSEL]; int ti[KSEL];
        #pragma unroll
        for (int q = 0; q < KSEL; ++q) { tv[q] = -INFINITY; ti[q] = 0x7FFFFFFF; }
        #pragma unroll
        for (int i = 0; i < 8; ++i) {
            int base = lane * 4 + i * 256;
            float vs[4] = {v4[i].x, v4[i].y, v4[i].z, v4[i].w};
            #pragma unroll
            for (int j = 0; j < 4; ++j) {
                float v = vs[j];
                int idx = base + j;
                if (v > tv[0]) {
                    bool cg[KSEL];
                    #pragma unroll
                    for (int q = 0; q < KSEL; ++q) cg[q] = v > tv[q];
                    #pragma unroll
                    for (int q = 0; q < KSEL - 1; ++q) {
                        tv[q] = cg[q + 1] ? tv[q + 1] : (cg[q] ? v : tv[q]);
                        ti[q] = cg[q + 1] ? ti[q + 1] : (cg[q] ? idx : ti[q]);
                    }
                    tv[KSEL - 1] = cg[KSEL - 1] ? v : tv[KSEL - 1];
                    ti[KSEL - 1] = cg[KSEL - 1] ? idx : ti[KSEL - 1];
                }
            }
        }
        #pragma unroll
        for (int rr = 0; rr < KSEL; ++rr) {
            float bv = tv[KSEL - 1]; int bi = ti[KSEL - 1];
            #pragma unroll
            for (int off = 1; off < 64; off <<= 1) {
                float ov = __shfl_xor(bv, off, 64);
                int   oi = __shfl_xor(bi, off, 64);
                if (ov > bv || (ov == bv && oi < bi)) { bv = ov; bi = oi; }
            }
            if ((lane >> 2) == rr) my_q = bi;
            if (bv == tv[KSEL - 1] && bi == ti[KSEL - 1]) {
                #pragma unroll
                for (int s = KSEL - 1; s > 0; --s) { tv[s] = tv[s - 1]; ti[s] = ti[s - 1]; }
                tv[0] = -INFINITY; ti[0] = 0x7FFFFFFF;
            }
        }
    }

    const float* xb = xn + (size_t)batch * xstride;
    const float* cp = xb + (size_t)p * NC + (lane & 3) * 48;
    const float* cq = xb + (size_t)my_q * NC + (lane & 3) * 48;
    float dot = 0.f;
    #pragma unroll
    for (int i = 0; i < 12; ++i) {
        float4 a = *reinterpret_cast<const float4*>(cp + i * 4);
        float4 bq = *reinterpret_cast<const float4*>(cq + i * 4);
        dot += a.x * bq.x + a.y * bq.y + a.z * bq.z + a.w * bq.w;
    }
    dot += __shfl_xor(dot, 1, 64);
    dot += __shfl_xor(dot, 2, 64);
    int g = lane >> 2;
    int rank = 0;
    #pragma unroll
    for (int j = 0; j < KSEL; ++j) {
        float vj = __shfl(dot, j * 4, 64);
        int   qj = __shfl(my_q, j * 4, 64);
        if (j != g && (vj > dot || (vj == dot && qj < my_q))) ++rank;
    }
    bool keep = ((lane & 3) == 0) && (rank < KNN);
    unsigned long long mask = __ballot(keep);
    int pos = __popcll(mask & ((1ull << lane) - 1));
    if (keep) knn[(size_t)row * KNN + pos] = my_q;
}

// ---- prep: w1t[384][192] bf16 = [(W1a - W1b)^T ; W1b^T] ----------------------
__global__ void __launch_bounds__(256) k_w1t(const float* __restrict__ W1,
                                             ushort* __restrict__ w1t) {
    int idx = blockIdx.x * 256 + threadIdx.x;
    if (idx >= 2 * NC * NC) return;
    int n = idx / NC, k = idx % NC;
    float v;
    if (n < NC) v = W1[(size_t)k * NC + n] - W1[(size_t)(k + NC) * NC + n];
    else        v = W1[(size_t)(k + NC) * NC + (n - NC)];
    w1t[idx] = f2bf(v);
}

// ---- prep: W2T bf16 [n][k] from W2 f32 [k][n] --------------------------------
__global__ void __launch_bounds__(256) k_w2t(const float* __restrict__ W2,
                                             ushort* __restrict__ w2t) {
    int idx = blockIdx.x * 256 + threadIdx.x;
    if (idx >= NC * NC) return;
    int n = idx / NC, k = idx % NC;
    w2t[(size_t)n * NC + k] = f2bf(W2[(size_t)k * NC + n]);
}

// ---- kernel 4: [U'|V] = Xb @ w1t^T via MFMA; bias fused into U' --------------
#define UVM 32
__global__ void __launch_bounds__(256) k_uv2(const ushort* __restrict__ xb,
                                             const ushort* __restrict__ w1t,
                                             const float* __restrict__ b1,
                                             float* __restrict__ up,
                                             float* __restrict__ vv) {
    __shared__ ushort xs[UVM][200];
    int t = threadIdx.x;
    int w = t >> 6, l = t & 63;
    int lg = l >> 4, lr = l & 15;
    int p0 = blockIdx.x * UVM;
    for (int i = t; i < UVM * 24; i += 256) {
        int row = i / 24, c = (i % 24) * 8;
        *reinterpret_cast<bf16x8*>(&xs[row][c]) =
            *reinterpret_cast<const bf16x8*>(&xb[(size_t)(p0 + row) * NC + c]);
    }
    __syncthreads();
    int n0 = w * 96;
    f32x4 acc[2][6];
    #pragma unroll
    for (int mt = 0; mt < 2; ++mt)
        #pragma unroll
        for (int nt = 0; nt < 6; ++nt)
            acc[mt][nt] = (f32x4){0.f, 0.f, 0.f, 0.f};
    #pragma unroll
    for (int ks = 0; ks < 6; ++ks) {
        bf16x8 bfr[6];
        #pragma unroll
        for (int nt = 0; nt < 6; ++nt)
            bfr[nt] = *reinterpret_cast<const bf16x8*>(
                &w1t[(size_t)(n0 + nt * 16 + lr) * NC + ks * 32 + lg * 8]);
        bf16x8 a0 = *reinterpret_cast<const bf16x8*>(&xs[lr][ks * 32 + lg * 8]);
        bf16x8 a1 = *reinterpret_cast<const bf16x8*>(&xs[16 + lr][ks * 32 + lg * 8]);
        #pragma unroll
        for (int nt = 0; nt < 6; ++nt) {
            acc[0][nt] = __builtin_amdgcn_mfma_f32_16x16x32_bf16(a0, bfr[nt], acc[0][nt], 0, 0, 0);
            acc[1][nt] = __builtin_amdgcn_mfma_f32_16x16x32_bf16(a1, bfr[nt], acc[1][nt], 0, 0, 0);
        }
    }
    bool isU = (n0 < NC);
    #pragma unroll
    for (int nt = 0; nt < 6; ++nt) {
        int col = n0 + nt * 16 + lr;
        float bb = isU ? b1[col] : 0.f;
        int ocol = isU ? col : col - NC;
        float* dst = isU ? up : vv;
        #pragma unroll
        for (int mt = 0; mt < 2; ++mt)
            #pragma unroll
            for (int j = 0; j < 4; ++j) {
                int pt = p0 + mt * 16 + lg * 4 + j;
                dst[(size_t)pt * NC + ocol] = acc[mt][nt][j] + bb;
            }
    }
}

// ---- kernel 5: edge MLP; 12 waves/block (3/SIMD), no spill, EPW=2 ------------
__device__ __forceinline__ bf16x8 make_h(const float* __restrict__ u,
                                         const float* __restrict__ v) {
    float4 ua = *reinterpret_cast<const float4*>(u);
    float4 ub = *reinterpret_cast<const float4*>(u + 4);
    float4 va = *reinterpret_cast<const float4*>(v);
    float4 vb = *reinterpret_cast<const float4*>(v + 4);
    union { bf16x8 v8; __hip_bfloat162 h2[4]; } r;
    r.h2[0] = __float22bfloat162_rn(make_float2(lrelu(ua.x + va.x), lrelu(ua.y + va.y)));
    r.h2[1] = __float22bfloat162_rn(make_float2(lrelu(ua.z + va.z), lrelu(ua.w + va.w)));
    r.h2[2] = __float22bfloat162_rn(make_float2(lrelu(ub.x + vb.x), lrelu(ub.y + vb.y)));
    r.h2[3] = __float22bfloat162_rn(make_float2(lrelu(ub.z + vb.z), lrelu(ub.w + vb.w)));
    return r.v8;
}

#define EW 12   // waves/block
#define EPW 2   // points/wave
__global__ void __launch_bounds__(768, 3) k_edge6(const float* __restrict__ up,
                                                  const float* __restrict__ vv,
                                                  const int* __restrict__ knn,
                                                  const ushort* __restrict__ w2t,
                                                  const float* __restrict__ b2,
                                                  const float* __restrict__ gamma,
                                                  const float* __restrict__ beta,
                                                  float* __restrict__ out) {
    __shared__ ushort w2s[NC][200];          // 76.8 KB
    __shared__ float aggs[EW][EPW][NC];      // 18.4 KB  -> 95.2 KB total
    int t = threadIdx.x;
    int wv = t >> 6, l = t & 63;
    int lg = l >> 4, lr = l & 15;

    int pt0 = blockIdx.x * (EW * EPW) + wv * EPW;
    bool valid = pt0 < NB * NP;

    // prefetch q indices before the barrier (independent of LDS)
    int q0 = 0, q1 = 0;
    int lre = lr < KNN ? lr : KNN - 1;
    if (valid) {
        q0 = knn[(size_t)(pt0 + 0) * KNN + lre];
        q1 = knn[(size_t)(pt0 + 1) * KNN + lre];
    }

    for (int i = t; i < NC * 24; i += 768) {
        int r_ = i / 24, c_ = i % 24;
        *reinterpret_cast<bf16x8*>(&w2s[r_][c_ * 8]) =
            *reinterpret_cast<const bf16x8*>(&w2t[(size_t)r_ * NC + c_ * 8]);
    }
    __syncthreads();   // only block-wide barrier; tail waves exit after
    if (!valid) return;

    int b = pt0 / NP;
    const float* vb = vv + (size_t)b * NP * NC;
    const float* u0p = up + (size_t)(pt0 + 0) * NC + 8 * lg;
    const float* u1p = up + (size_t)(pt0 + 1) * NC + 8 * lg;
    const float* v0p = vb + (size_t)q0 * NC + 8 * lg;
    const float* v1p = vb + (size_t)q1 * NC + 8 * lg;

    f32x4 acc[EPW][12];
    #pragma unroll
    for (int pt = 0; pt < EPW; ++pt)
        #pragma unroll
        for (int nt = 0; nt < 12; ++nt)
            acc[pt][nt] = (f32x4){0.f, 0.f, 0.f, 0.f};

    #pragma unroll
    for (int ks = 0; ks < 6; ++ks) {
        bf16x8 a0 = make_h(u0p + ks * 32, v0p + ks * 32);
        bf16x8 a1 = make_h(u1p + ks * 32, v1p + ks * 32);
        #pragma unroll
        for (int nt = 0; nt < 12; ++nt) {
            bf16x8 bfr = *reinterpret_cast<const bf16x8*>(&w2s[nt * 16 + lr][ks * 32 + lg * 8]);
            acc[0][nt] = __builtin_amdgcn_mfma_f32_16x16x32_bf16(a0, bfr, acc[0][nt], 0, 0, 0);
            acc[1][nt] = __builtin_amdgcn_mfma_f32_16x16x32_bf16(a1, bfr, acc[1][nt], 0, 0, 0);
        }
    }

    #pragma unroll
    for (int pt = 0; pt < EPW; ++pt) {
        #pragma unroll
        for (int nt = 0; nt < 12; ++nt) {
            float bb = b2[nt * 16 + lr];
            float s = 0.f;
            if (lg < 3) {
                #pragma unroll
                for (int j = 0; j < 4; ++j) s += lrelu(acc[pt][nt][j] + bb);
            }
            s += __shfl_xor(s, 16, 64);
            s += __shfl_xor(s, 32, 64);
            if (lg == 0) aggs[wv][pt][nt * 16 + lr] = s * (1.0f / KNN);
        }
    }
    asm volatile("s_waitcnt lgkmcnt(0)" ::: "memory");   // same-wave LDS RAW

    #pragma unroll
    for (int pt = 0; pt < EPW; ++pt) {
        float a0 = aggs[wv][pt][l], a1 = aggs[wv][pt][l + 64], a2 = aggs[wv][pt][l + 128];
        float s = a0 + a1 + a2;
        #pragma unroll
        for (int off = 32; off; off >>= 1) s += __shfl_xor(s, off, 64);
        float mu = s / (float)NC;
        float d0 = a0 - mu, d1 = a1 - mu, d2 = a2 - mu;
        float vs = d0 * d0 + d1 * d1 + d2 * d2;
        #pragma unroll
        for (int off = 32; off; off >>= 1) vs += __shfl_xor(vs, off, 64);
        float rstd = 1.0f / sqrtf(vs / (float)NC + 1e-5f);
        float* o = out + (size_t)(pt0 + pt) * NC;
        o[l]       = d0 * rstd * gamma[l]       + beta[l];
        o[l + 64]  = d1 * rstd * gamma[l + 64]  + beta[l + 64];
        o[l + 128] = d2 * rstd * gamma[l + 128] + beta[l + 128];
    }
}

extern "C" void kernel_launch(void* const* d_in, const int* in_sizes, int n_in,
                              void* d_out, int out_size, void* d_ws, size_t ws_size,
                              hipStream_t stream) {
    const float* nodes = (const float*)d_in[0];
    const float* W1    = (const float*)d_in[1];
    const float* b1    = (const float*)d_in[2];
    const float* W2    = (const float*)d_in[3];
    const float* b2    = (const float*)d_in[4];
    const float* gamma = (const float*)d_in[5];
    const float* beta  = (const float*)d_in[6];
    float* out = (float*)d_out;

    const size_t BPC = (size_t)NB * NP * NC;
    float*  xn  = (float*)d_ws;                        // B*P*C f32
    float*  up  = xn + BPC;                            // B*P*C f32
    float*  vv  = up + BPC;                            // B*P*C f32
    ushort* xh  = (ushort*)(vv + BPC);                 // B*P*C bf16 (normalized)
    ushort* xb  = xh + BPC;                            // B*P*C bf16 (raw)
    int*    knn = (int*)(xb + BPC);                    // B*P*K
    ushort* w2t = (ushort*)(knn + (size_t)NB * NP * KNN); // C*C bf16
    ushort* w1t = w2t + (size_t)NC * NC;               // 2C*C bf16
    float*  sim = (float*)((char*)(w1t + (size_t)2 * NC * NC) + 8);
    sim = (float*)(((uintptr_t)sim + 15) & ~(uintptr_t)15);

    size_t fixed_bytes = (size_t)((char*)sim - (char*)d_ws);
    bool full = ws_size >= fixed_bytes + (size_t)NB * NP * NP * 4;

    k_normalize<<<NB * NP / 4, 256, 0, stream>>>(nodes, xn, xh, xb);
    k_w1t<<<(2 * NC * NC + 255) / 256, 256, 0, stream>>>(W1, w1t);
    k_w2t<<<(NC * NC + 255) / 256, 256, 0, stream>>>(W2, w2t);
    k_uv2<<<NB * NP / UVM, 256, 0, stream>>>(xb, w1t, b1, up, vv);
    if (full) {
        k_sim3<<<dim3(NP / 128, NP / 128, NB), 256, 0, stream>>>(xh, sim,
                                                                 (size_t)NP * NC, (size_t)NP * NP);
        k_topk4<<<NB * NP / 4, 256, 0, stream>>>(sim, xn, knn,
                                                 (size_t)NP * NP, (size_t)NP * NC);
    } else {
        for (int b = 0; b < NB; ++b) {
            k_sim3<<<dim3(NP / 128, NP / 128, 1), 256, 0, stream>>>(xh + (size_t)b * NP * NC, sim, 0, 0);
            k_topk4<<<NP / 4, 256, 0, stream>>>(sim, xn + (size_t)b * NP * NC,
                                                knn + (size_t)b * NP * KNN, 0, 0);
        }
    }
    int egrid = (NB * NP + EW * EPW - 1) / (EW * EPW);
    k_edge6<<<egrid, 768, 0, stream>>>(up, vv, knn, w2t, b2, gamma, beta, out);
}

// Round 10
// 108.275 us; speedup vs baseline: 2.9371x; 1.0920x over previous
//
#include <hip/hip_runtime.h>
#include <hip/hip_bf16.h>
#include <math.h>

#define NB 4
#define NP 2048
#define NC 192
#define KNN 12
#define KSEL 16
#define NEG_SLOPE 0.2f

typedef __attribute__((ext_vector_type(8))) short bf16x8;
typedef __attribute__((ext_vector_type(4))) float f32x4;

__device__ __forceinline__ float lrelu(float x) { return x >= 0.0f ? x : NEG_SLOPE * x; }

__device__ __forceinline__ ushort f2bf(float x) {
    unsigned u = __float_as_uint(x);
    unsigned r = (u + 0x7FFFu + ((u >> 16) & 1u)) >> 16;   // RNE
    return (ushort)r;
}

// -- kernel 1: L2-normalize; out: xn f32 (rescore), xh bf16 (sim), xb bf16 (UV)
__global__ void __launch_bounds__(256) k_normalize(const float* __restrict__ nodes,
                                                   float* __restrict__ xn,
                                                   ushort* __restrict__ xh,
                                                   ushort* __restrict__ xb) {
    int wave = threadIdx.x >> 6;
    int lane = threadIdx.x & 63;
    size_t pt = (size_t)blockIdx.x * 4 + wave;
    const float* x = nodes + pt * NC;
    float v0 = x[lane], v1 = x[lane + 64], v2 = x[lane + 128];
    float s = v0 * v0 + v1 * v1 + v2 * v2;
    #pragma unroll
    for (int off = 32; off; off >>= 1) s += __shfl_xor(s, off, 64);
    float inv = 1.0f / fmaxf(sqrtf(s), 1e-12f);
    float f0 = v0 * inv, f1 = v1 * inv, f2 = v2 * inv;
    float* o = xn + pt * NC;
    o[lane] = f0; o[lane + 64] = f1; o[lane + 128] = f2;
    ushort* oh = xh + pt * NC;
    oh[lane] = f2bf(f0); oh[lane + 64] = f2bf(f1); oh[lane + 128] = f2bf(f2);
    ushort* ob = xb + pt * NC;
    ob[lane] = f2bf(v0); ob[lane + 64] = f2bf(v1); ob[lane + 128] = f2bf(v2);
}

// ------- kernel 2: sim = Xh * Xh^T via bf16 MFMA (approximate, f32 out) -------
__global__ void __launch_bounds__(256) k_sim3(const ushort* __restrict__ xh,
                                              float* __restrict__ sim,
                                              size_t xstride, size_t simstride) {
    __shared__ ushort Ah[128][72];
    __shared__ ushort Bh[128][72];
    const ushort* XbH = xh + (size_t)blockIdx.z * xstride;
    float* sb = sim + (size_t)blockIdx.z * simstride;
    int t = threadIdx.x;
    int w = t >> 6, l = t & 63;
    int wm = w >> 1, wn = w & 1;
    int lg = l >> 4, lr = l & 15;
    int m0 = blockIdx.y * 128, n0 = blockIdx.x * 128;

    f32x4 acc[4][4];
    #pragma unroll
    for (int mi = 0; mi < 4; ++mi)
        #pragma unroll
        for (int ni = 0; ni < 4; ++ni)
            acc[mi][ni] = (f32x4){0.f, 0.f, 0.f, 0.f};

    int r = t >> 3, c = (t & 7) * 8;
    for (int ks = 0; ks < 3; ++ks) {
        int kb = ks * 64;
        #pragma unroll
        for (int i = 0; i < 4; ++i) {
            int row = r + 32 * i;
            *reinterpret_cast<bf16x8*>(&Ah[row][c]) =
                *reinterpret_cast<const bf16x8*>(&XbH[(size_t)(m0 + row) * NC + kb + c]);
            *reinterpret_cast<bf16x8*>(&Bh[row][c]) =
                *reinterpret_cast<const bf16x8*>(&XbH[(size_t)(n0 + row) * NC + kb + c]);
        }
        __syncthreads();
        #pragma unroll
        for (int ksub = 0; ksub < 2; ++ksub) {
            int ko = ksub * 32 + 8 * lg;
            bf16x8 af[4], bf[4];
            #pragma unroll
            for (int f = 0; f < 4; ++f) {
                af[f] = *reinterpret_cast<const bf16x8*>(&Ah[wm * 64 + f * 16 + lr][ko]);
                bf[f] = *reinterpret_cast<const bf16x8*>(&Bh[wn * 64 + f * 16 + lr][ko]);
            }
            #pragma unroll
            for (int mi = 0; mi < 4; ++mi)
                #pragma unroll
                for (int ni = 0; ni < 4; ++ni)
                    acc[mi][ni] = __builtin_amdgcn_mfma_f32_16x16x32_bf16(af[mi], bf[ni], acc[mi][ni], 0, 0, 0);
        }
        __syncthreads();
    }
    #pragma unroll
    for (int mi = 0; mi < 4; ++mi)
        #pragma unroll
        for (int j = 0; j < 4; ++j) {
            int row = m0 + wm * 64 + mi * 16 + lg * 4 + j;
            #pragma unroll
            for (int ni = 0; ni < 4; ++ni)
                sb[(size_t)row * NP + n0 + wn * 64 + ni * 16 + lr] = acc[mi][ni][j];
        }
}

// ------- kernel 3: threshold+compact+bitonic top-16, exact rescore -> 12-set --
__global__ void __launch_bounds__(256) k_topk4(const float* __restrict__ sim,
                                               const float* __restrict__ xn,
                                               int* __restrict__ knn,
                                               size_t simstride, size_t xstride) {
    __shared__ float cvs[4][64];
    __shared__ int   cis[4][64];
    int wv = threadIdx.x >> 6, lane = threadIdx.x & 63;
    int row = blockIdx.x * 4 + wv;
    int batch = row / NP, p = row % NP;
    const float* sr = sim + (size_t)batch * simstride + (size_t)p * NP;

    float4 v4[8];
    #pragma unroll
    for (int i = 0; i < 8; ++i)
        v4[i] = *reinterpret_cast<const float4*>(sr + lane * 4 + i * 256);

    #pragma unroll
    for (int i = 0; i < 8; ++i) {
        int base = lane * 4 + i * 256;
        v4[i].x = (base + 0 == p) ? -INFINITY : v4[i].x;
        v4[i].y = (base + 1 == p) ? -INFINITY : v4[i].y;
        v4[i].z = (base + 2 == p) ? -INFINITY : v4[i].z;
        v4[i].w = (base + 3 == p) ? -INFINITY : v4[i].w;
    }

    float lmax = -INFINITY;
    #pragma unroll
    for (int i = 0; i < 8; ++i) {
        lmax = fmaxf(lmax, fmaxf(fmaxf(v4[i].x, v4[i].y), fmaxf(v4[i].z, v4[i].w)));
    }

    float sm = lmax;
    #pragma unroll
    for (int k = 2; k <= 64; k <<= 1) {
        #pragma unroll
        for (int j = k >> 1; j >= 1; j >>= 1) {
            float ov = __shfl_xor(sm, j, 64);
            bool lower = (lane & j) == 0;
            bool up = (lane & k) != 0;
            float lo = fminf(sm, ov), hi = fmaxf(sm, ov);
            sm = (up == lower) ? lo : hi;
        }
    }
    float theta = __shfl(sm, 16, 64);

    int cnt = 0;
    #pragma unroll
    for (int i = 0; i < 8; ++i) {
        cnt += (v4[i].x > theta) + (v4[i].y > theta) + (v4[i].z > theta) + (v4[i].w > theta);
    }
    int x = cnt;
    #pragma unroll
    for (int off = 1; off < 64; off <<= 1) {
        int y = __shfl_up(x, off, 64);
        if (lane >= off) x += y;
    }
    int excl = x - cnt;
    int total = __shfl(x, 63, 64);

    int my_q = 0;
    bool fb = (total < KSEL) || (total > 64);
    if (!fb) {
        cvs[wv][lane] = -INFINITY;
        cis[wv][lane] = 0;
        asm volatile("s_waitcnt lgkmcnt(0)" ::: "memory");
        int pos = excl;
        #pragma unroll
        for (int i = 0; i < 8; ++i) {
            int base = lane * 4 + i * 256;
            float vs[4] = {v4[i].x, v4[i].y, v4[i].z, v4[i].w};
            #pragma unroll
            for (int j = 0; j < 4; ++j) {
                if (vs[j] > theta) {
                    cvs[wv][pos] = vs[j];
                    cis[wv][pos] = base + j;
                    ++pos;
                }
            }
        }
        asm volatile("s_waitcnt lgkmcnt(0)" ::: "memory");
        float v = cvs[wv][lane];
        int   idx = cis[wv][lane];
        #pragma unroll
        for (int k = 2; k <= 64; k <<= 1) {
            #pragma unroll
            for (int j = k >> 1; j >= 1; j >>= 1) {
                float ov = __shfl_xor(v, j, 64);
                int   oi = __shfl_xor(idx, j, 64);
                bool lower = (lane & j) == 0;
                bool up = (lane & k) != 0;
                bool ogt = (ov > v);
                float hv = ogt ? ov : v;  int hid = ogt ? oi : idx;
                float lv = ogt ? v : ov;  int lid = ogt ? idx : oi;
                bool keep_lo = (up == lower);
                v   = keep_lo ? lv : hv;
                idx = keep_lo ? lid : hid;
            }
        }
        my_q = __shfl(idx, lane >> 2, 64);
    } else {
        float tv[KSEL]; int ti[KSEL];
        #pragma unroll
        for (int q = 0; q < KSEL; ++q) { tv[q] = -INFINITY; ti[q] = 0x7FFFFFFF; }
        #pragma unroll
        for (int i = 0; i < 8; ++i) {
            int base = lane * 4 + i * 256;
            float vs[4] = {v4[i].x, v4[i].y, v4[i].z, v4[i].w};
            #pragma unroll
            for (int j = 0; j < 4; ++j) {
                float v = vs[j];
                int idx = base + j;
                if (v > tv[0]) {
                    bool cg[KSEL];
                    #pragma unroll
                    for (int q = 0; q < KSEL; ++q) cg[q] = v > tv[q];
                    #pragma unroll
                    for (int q = 0; q < KSEL - 1; ++q) {
                        tv[q] = cg[q + 1] ? tv[q + 1] : (cg[q] ? v : tv[q]);
                        ti[q] = cg[q + 1] ? ti[q + 1] : (cg[q] ? idx : ti[q]);
                    }
                    tv[KSEL - 1] = cg[KSEL - 1] ? v : tv[KSEL - 1];
                    ti[KSEL - 1] = cg[KSEL - 1] ? idx : ti[KSEL - 1];
                }
            }
        }
        #pragma unroll
        for (int rr = 0; rr < KSEL; ++rr) {
            float bv = tv[KSEL - 1]; int bi = ti[KSEL - 1];
            #pragma unroll
            for (int off = 1; off < 64; off <<= 1) {
                float ov = __shfl_xor(bv, off, 64);
                int   oi = __shfl_xor(bi, off, 64);
                if (ov > bv || (ov == bv && oi < bi)) { bv = ov; bi = oi; }
            }
            if ((lane >> 2) == rr) my_q = bi;
            if (bv == tv[KSEL - 1] && bi == ti[KSEL - 1]) {
                #pragma unroll
                for (int s = KSEL - 1; s > 0; --s) { tv[s] = tv[s - 1]; ti[s] = ti[s - 1]; }
                tv[0] = -INFINITY; ti[0] = 0x7FFFFFFF;
            }
        }
    }

    const float* xb = xn + (size_t)batch * xstride;
    const float* cp = xb + (size_t)p * NC + (lane & 3) * 48;
    const float* cq = xb + (size_t)my_q * NC + (lane & 3) * 48;
    float dot = 0.f;
    #pragma unroll
    for (int i = 0; i < 12; ++i) {
        float4 a = *reinterpret_cast<const float4*>(cp + i * 4);
        float4 bq = *reinterpret_cast<const float4*>(cq + i * 4);
        dot += a.x * bq.x + a.y * bq.y + a.z * bq.z + a.w * bq.w;
    }
    dot += __shfl_xor(dot, 1, 64);
    dot += __shfl_xor(dot, 2, 64);
    int g = lane >> 2;
    int rank = 0;
    #pragma unroll
    for (int j = 0; j < KSEL; ++j) {
        float vj = __shfl(dot, j * 4, 64);
        int   qj = __shfl(my_q, j * 4, 64);
        if (j != g && (vj > dot || (vj == dot && qj < my_q))) ++rank;
    }
    bool keep = ((lane & 3) == 0) && (rank < KNN);
    unsigned long long mask = __ballot(keep);
    int pos = __popcll(mask & ((1ull << lane) - 1));
    if (keep) knn[(size_t)row * KNN + pos] = my_q;
}

// ---- prep: w1t[384][192] bf16 = [(W1a - W1b)^T ; W1b^T] ----------------------
__global__ void __launch_bounds__(256) k_w1t(const float* __restrict__ W1,
                                             ushort* __restrict__ w1t) {
    int idx = blockIdx.x * 256 + threadIdx.x;
    if (idx >= 2 * NC * NC) return;
    int n = idx / NC, k = idx % NC;
    float v;
    if (n < NC) v = W1[(size_t)k * NC + n] - W1[(size_t)(k + NC) * NC + n];
    else        v = W1[(size_t)(k + NC) * NC + (n - NC)];
    w1t[idx] = f2bf(v);
}

// ---- prep: W2T bf16 [n][k] from W2 f32 [k][n] --------------------------------
__global__ void __launch_bounds__(256) k_w2t(const float* __restrict__ W2,
                                             ushort* __restrict__ w2t) {
    int idx = blockIdx.x * 256 + threadIdx.x;
    if (idx >= NC * NC) return;
    int n = idx / NC, k = idx % NC;
    w2t[(size_t)n * NC + k] = f2bf(W2[(size_t)k * NC + n]);
}

// ---- kernel 4: [U'|V] = Xb @ w1t^T via MFMA; bias fused into U' --------------
#define UVM 32
__global__ void __launch_bounds__(256) k_uv2(const ushort* __restrict__ xb,
                                             const ushort* __restrict__ w1t,
                                             const float* __restrict__ b1,
                                             float* __restrict__ up,
                                             float* __restrict__ vv) {
    __shared__ ushort xs[UVM][200];
    int t = threadIdx.x;
    int w = t >> 6, l = t & 63;
    int lg = l >> 4, lr = l & 15;
    int p0 = blockIdx.x * UVM;
    for (int i = t; i < UVM * 24; i += 256) {
        int row = i / 24, c = (i % 24) * 8;
        *reinterpret_cast<bf16x8*>(&xs[row][c]) =
            *reinterpret_cast<const bf16x8*>(&xb[(size_t)(p0 + row) * NC + c]);
    }
    __syncthreads();
    int n0 = w * 96;
    f32x4 acc[2][6];
    #pragma unroll
    for (int mt = 0; mt < 2; ++mt)
        #pragma unroll
        for (int nt = 0; nt < 6; ++nt)
            acc[mt][nt] = (f32x4){0.f, 0.f, 0.f, 0.f};
    #pragma unroll
    for (int ks = 0; ks < 6; ++ks) {
        bf16x8 bfr[6];
        #pragma unroll
        for (int nt = 0; nt < 6; ++nt)
            bfr[nt] = *reinterpret_cast<const bf16x8*>(
                &w1t[(size_t)(n0 + nt * 16 + lr) * NC + ks * 32 + lg * 8]);
        bf16x8 a0 = *reinterpret_cast<const bf16x8*>(&xs[lr][ks * 32 + lg * 8]);
        bf16x8 a1 = *reinterpret_cast<const bf16x8*>(&xs[16 + lr][ks * 32 + lg * 8]);
        #pragma unroll
        for (int nt = 0; nt < 6; ++nt) {
            acc[0][nt] = __builtin_amdgcn_mfma_f32_16x16x32_bf16(a0, bfr[nt], acc[0][nt], 0, 0, 0);
            acc[1][nt] = __builtin_amdgcn_mfma_f32_16x16x32_bf16(a1, bfr[nt], acc[1][nt], 0, 0, 0);
        }
    }
    bool isU = (n0 < NC);
    #pragma unroll
    for (int nt = 0; nt < 6; ++nt) {
        int col = n0 + nt * 16 + lr;
        float bb = isU ? b1[col] : 0.f;
        int ocol = isU ? col : col - NC;
        float* dst = isU ? up : vv;
        #pragma unroll
        for (int mt = 0; mt < 2; ++mt)
            #pragma unroll
            for (int j = 0; j < 4; ++j) {
                int pt = p0 + mt * 16 + lg * 4 + j;
                dst[(size_t)pt * NC + ocol] = acc[mt][nt][j] + bb;
            }
    }
}

// ---- kernel 5: edge MLP; EPW=1 (48 AGPR acc), 16 waves/block, 4 waves/SIMD ---
__device__ __forceinline__ bf16x8 packh(float4 ua, float4 ub, float4 va, float4 vb) {
    union { bf16x8 v8; __hip_bfloat162 h2[4]; } r;
    r.h2[0] = __float22bfloat162_rn(make_float2(lrelu(ua.x + va.x), lrelu(ua.y + va.y)));
    r.h2[1] = __float22bfloat162_rn(make_float2(lrelu(ua.z + va.z), lrelu(ua.w + va.w)));
    r.h2[2] = __float22bfloat162_rn(make_float2(lrelu(ub.x + vb.x), lrelu(ub.y + vb.y)));
    r.h2[3] = __float22bfloat162_rn(make_float2(lrelu(ub.z + vb.z), lrelu(ub.w + vb.w)));
    return r.v8;
}

#define EW 16   // waves/block, 1 point each
__global__ void __launch_bounds__(1024, 4) k_edge7(const float* __restrict__ up,
                                                   const float* __restrict__ vv,
                                                   const int* __restrict__ knn,
                                                   const ushort* __restrict__ w2t,
                                                   const float* __restrict__ b2,
                                                   const float* __restrict__ gamma,
                                                   const float* __restrict__ beta,
                                                   float* __restrict__ out) {
    __shared__ ushort w2s[NC][200];   // 76.8 KB
    __shared__ float aggs[EW][NC];    // 12.3 KB -> 89.1 KB total, 1 block/CU
    int t = threadIdx.x;
    int wv = t >> 6, l = t & 63;
    int lg = l >> 4, lr = l & 15;

    int pt0 = blockIdx.x * EW + wv;   // grid 512 x 16 waves = 8192, no tail
    int lre = lr < KNN ? lr : KNN - 1;
    int q0 = knn[(size_t)pt0 * KNN + lre];   // prefetch before barrier

    for (int i = t; i < NC * 24; i += 1024) {
        int r_ = i / 24, c_ = i % 24;
        *reinterpret_cast<bf16x8*>(&w2s[r_][c_ * 8]) =
            *reinterpret_cast<const bf16x8*>(&w2t[(size_t)r_ * NC + c_ * 8]);
    }
    __syncthreads();   // only block-wide barrier

    int b = pt0 / NP;
    const float* u0p = up + (size_t)pt0 * NC + 8 * lg;
    const float* v0p = vv + ((size_t)b * NP + q0) * NC + 8 * lg;

    f32x4 acc[12];
    #pragma unroll
    for (int nt = 0; nt < 12; ++nt) acc[nt] = (f32x4){0.f, 0.f, 0.f, 0.f};

    // double-buffered gather: prefetch ks+1 before ks's MFMA chain
    float4 sUa[2], sUb[2], sVa[2], sVb[2];
#define LDST(ph, ks) do { \
        sUa[ph] = *reinterpret_cast<const float4*>(u0p + (ks) * 32);     \
        sUb[ph] = *reinterpret_cast<const float4*>(u0p + (ks) * 32 + 4); \
        sVa[ph] = *reinterpret_cast<const float4*>(v0p + (ks) * 32);     \
        sVb[ph] = *reinterpret_cast<const float4*>(v0p + (ks) * 32 + 4); \
    } while (0)

    LDST(0, 0);
    #pragma unroll
    for (int ks = 0; ks < 6; ++ks) {
        int ph = ks & 1;
        if (ks < 5) LDST(ph ^ 1, ks + 1);
        bf16x8 a0 = packh(sUa[ph], sUb[ph], sVa[ph], sVb[ph]);
        #pragma unroll
        for (int nt = 0; nt < 12; ++nt) {
            bf16x8 bfr = *reinterpret_cast<const bf16x8*>(&w2s[nt * 16 + lr][ks * 32 + lg * 8]);
            acc[nt] = __builtin_amdgcn_mfma_f32_16x16x32_bf16(a0, bfr, acc[nt], 0, 0, 0);
        }
    }
#undef LDST

    // epilogue: lrelu(+b2), mean over 12 real edge-rows
    #pragma unroll
    for (int nt = 0; nt < 12; ++nt) {
        float bb = b2[nt * 16 + lr];
        float s = 0.f;
        if (lg < 3) {
            #pragma unroll
            for (int j = 0; j < 4; ++j) s += lrelu(acc[nt][j] + bb);
        }
        s += __shfl_xor(s, 16, 64);
        s += __shfl_xor(s, 32, 64);
        if (lg == 0) aggs[wv][nt * 16 + lr] = s * (1.0f / KNN);
    }
    asm volatile("s_waitcnt lgkmcnt(0)" ::: "memory");   // same-wave LDS RAW

    float a0 = aggs[wv][l], a1 = aggs[wv][l + 64], a2 = aggs[wv][l + 128];
    float s = a0 + a1 + a2;
    #pragma unroll
    for (int off = 32; off; off >>= 1) s += __shfl_xor(s, off, 64);
    float mu = s / (float)NC;
    float d0 = a0 - mu, d1 = a1 - mu, d2 = a2 - mu;
    float vs = d0 * d0 + d1 * d1 + d2 * d2;
    #pragma unroll
    for (int off = 32; off; off >>= 1) vs += __shfl_xor(vs, off, 64);
    float rstd = 1.0f / sqrtf(vs / (float)NC + 1e-5f);
    float* o = out + (size_t)pt0 * NC;
    o[l]       = d0 * rstd * gamma[l]       + beta[l];
    o[l + 64]  = d1 * rstd * gamma[l + 64]  + beta[l + 64];
    o[l + 128] = d2 * rstd * gamma[l + 128] + beta[l + 128];
}

extern "C" void kernel_launch(void* const* d_in, const int* in_sizes, int n_in,
                              void* d_out, int out_size, void* d_ws, size_t ws_size,
                              hipStream_t stream) {
    const float* nodes = (const float*)d_in[0];
    const float* W1    = (const float*)d_in[1];
    const float* b1    = (const float*)d_in[2];
    const float* W2    = (const float*)d_in[3];
    const float* b2    = (const float*)d_in[4];
    const float* gamma = (const float*)d_in[5];
    const float* beta  = (const float*)d_in[6];
    float* out = (float*)d_out;

    const size_t BPC = (size_t)NB * NP * NC;
    float*  xn  = (float*)d_ws;                        // B*P*C f32
    float*  up  = xn + BPC;                            // B*P*C f32
    float*  vv  = up + BPC;                            // B*P*C f32
    ushort* xh  = (ushort*)(vv + BPC);                 // B*P*C bf16 (normalized)
    ushort* xb  = xh + BPC;                            // B*P*C bf16 (raw)
    int*    knn = (int*)(xb + BPC);                    // B*P*K
    ushort* w2t = (ushort*)(knn + (size_t)NB * NP * KNN); // C*C bf16
    ushort* w1t = w2t + (size_t)NC * NC;               // 2C*C bf16
    float*  sim = (float*)((char*)(w1t + (size_t)2 * NC * NC) + 8);
    sim = (float*)(((uintptr_t)sim + 15) & ~(uintptr_t)15);

    size_t fixed_bytes = (size_t)((char*)sim - (char*)d_ws);
    bool full = ws_size >= fixed_bytes + (size_t)NB * NP * NP * 4;

    k_normalize<<<NB * NP / 4, 256, 0, stream>>>(nodes, xn, xh, xb);
    k_w1t<<<(2 * NC * NC + 255) / 256, 256, 0, stream>>>(W1, w1t);
    k_w2t<<<(NC * NC + 255) / 256, 256, 0, stream>>>(W2, w2t);
    k_uv2<<<NB * NP / UVM, 256, 0, stream>>>(xb, w1t, b1, up, vv);
    if (full) {
        k_sim3<<<dim3(NP / 128, NP / 128, NB), 256, 0, stream>>>(xh, sim,
                                                                 (size_t)NP * NC, (size_t)NP * NP);
        k_topk4<<<NB * NP / 4, 256, 0, stream>>>(sim, xn, knn,
                                                 (size_t)NP * NP, (size_t)NP * NC);
    } else {
        for (int b = 0; b < NB; ++b) {
            k_sim3<<<dim3(NP / 128, NP / 128, 1), 256, 0, stream>>>(xh + (size_t)b * NP * NC, sim, 0, 0);
            k_topk4<<<NP / 4, 256, 0, stream>>>(sim, xn + (size_t)b * NP * NC,
                                                knn + (size_t)b * NP * KNN, 0, 0);
        }
    }
    k_edge7<<<NB * NP / EW, 1024, 0, stream>>>(up, vv, knn, w2t, b2, gamma, beta, out);
}